// Round 3
// baseline (3502.815 us; speedup 1.0000x reference)
//
#include <hip/hip_runtime.h>

typedef _Float16 h4 __attribute__((ext_vector_type(4)));
typedef _Float16 half8 __attribute__((ext_vector_type(8)));
typedef float f32x4 __attribute__((ext_vector_type(4)));

#define NBLK 250

// ---------------- Kernel 1: spatial MLP -> X[:, 0:2000, :] ----------------
__global__ __launch_bounds__(256) void k_spatial(
    const float* __restrict__ x, const float* __restrict__ sp_emb,
    const float* __restrict__ W1, const float* __restrict__ b1,
    const float* __restrict__ W2, const float* __restrict__ b2,
    float* __restrict__ X) {
  __shared__ float W1s[128 * 32];
  __shared__ float W2s[32 * 32];
  __shared__ float b1s[32], b2s[32];
  int tid = threadIdx.x;
  for (int i = tid; i < 128 * 32; i += 256) W1s[i] = W1[i];
  for (int i = tid; i < 32 * 32; i += 256) W2s[i] = W2[i];
  if (tid < 32) { b1s[tid] = b1[tid]; b2s[tid] = b2[tid]; }
  __syncthreads();
  int gidx = blockIdx.x * 256 + tid;
  if (gidx >= 8 * 2000) return;
  int b = gidx / 2000, n = gidx % 2000;
  float h1[32];
#pragma unroll
  for (int l = 0; l < 32; l++) h1[l] = b1s[l];
  for (int k = 0; k < 96; k++) {
    float xv = x[((size_t)b * 96 + k) * 2000 + n];
#pragma unroll
    for (int l = 0; l < 32; l++) h1[l] = fmaf(xv, W1s[k * 32 + l], h1[l]);
  }
  for (int e4 = 0; e4 < 8; e4++) {
    float4 ev = *reinterpret_cast<const float4*>(&sp_emb[(size_t)n * 32 + e4 * 4]);
    float evs[4] = {ev.x, ev.y, ev.z, ev.w};
#pragma unroll
    for (int q = 0; q < 4; q++) {
      int e = e4 * 4 + q;
#pragma unroll
      for (int l = 0; l < 32; l++) h1[l] = fmaf(evs[q], W1s[(96 + e) * 32 + l], h1[l]);
    }
  }
  float out[32];
#pragma unroll
  for (int j = 0; j < 32; j++) out[j] = b2s[j];
  for (int l = 0; l < 32; l++) {
    float a = h1[l] > 0.0f ? h1[l] : (__expf(h1[l]) - 1.0f);
#pragma unroll
    for (int j = 0; j < 32; j++) out[j] = fmaf(a, W2s[l * 32 + j], out[j]);
  }
  float* dst = X + ((size_t)b * 2096 + n) * 32;
#pragma unroll
  for (int j = 0; j < 32; j++) dst[j] = out[j];
}

// ---------------- Kernel 2: temporal GRU input gates precompute ----------------
__global__ __launch_bounds__(256) void k_tgi(
    const float* __restrict__ x, const float* __restrict__ x_mark,
    const float* __restrict__ t_emb, const float* __restrict__ Wih,
    const float* __restrict__ bih, float* __restrict__ gi) {
  __shared__ float xs[8][2036];
  int tid = threadIdx.x;
  int row0 = blockIdx.x * 8;
  for (int rr = 0; rr < 8; rr++) {
    int row = row0 + rr;
    int b = row / 96, t = row % 96;
    for (int k = tid; k < 2036; k += 256) {
      float v;
      if (k < 2000) v = x[((size_t)b * 96 + t) * 2000 + k];
      else if (k < 2004) v = x_mark[((size_t)b * 96 + t) * 4 + (k - 2000)];
      else v = t_emb[(size_t)t * 32 + (k - 2004)];
      xs[rr][k] = v;
    }
  }
  __syncthreads();
  for (int oi = tid; oi < 8 * 96; oi += 256) {
    int rr = oi / 96, g = oi % 96;
    const float* w = Wih + (size_t)g * 2036;
    float acc = bih[g];
    for (int k = 0; k < 2036; k += 4) {
      float4 wv = *reinterpret_cast<const float4*>(w + k);
      acc = fmaf(xs[rr][k + 0], wv.x, acc);
      acc = fmaf(xs[rr][k + 1], wv.y, acc);
      acc = fmaf(xs[rr][k + 2], wv.z, acc);
      acc = fmaf(xs[rr][k + 3], wv.w, acc);
    }
    gi[(size_t)(row0 + rr) * 96 + g] = acc;
  }
}

// ---------------- Kernel 3: temporal GRU scan (hidden=32) ----------------
__global__ __launch_bounds__(256) void k_tgru(
    const float* __restrict__ gi, const float* __restrict__ Whh,
    const float* __restrict__ bhh, float* __restrict__ X) {
  __shared__ float Whs[96][33];
  __shared__ float hs[8][33];
  int tid = threadIdx.x;
  for (int i = tid; i < 96 * 32; i += 256) Whs[i / 32][i % 32] = Whh[i];
  int b = tid >> 5, j = tid & 31;
  hs[b][j] = 0.0f;
  __syncthreads();
  for (int t = 0; t < 96; t++) {
    float gr = bhh[j], gz = bhh[32 + j], gn = bhh[64 + j];
#pragma unroll 8
    for (int k = 0; k < 32; k++) {
      float hv = hs[b][k];
      gr = fmaf(hv, Whs[j][k], gr);
      gz = fmaf(hv, Whs[32 + j][k], gz);
      gn = fmaf(hv, Whs[64 + j][k], gn);
    }
    const float* g = gi + ((size_t)b * 96 + t) * 96;
    float ir = g[j], iz = g[32 + j], inn = g[64 + j];
    float r = 1.0f / (1.0f + __expf(-(ir + gr)));
    float z = 1.0f / (1.0f + __expf(-(iz + gz)));
    float n = tanhf(inn + r * gn);
    float hn = (1.0f - z) * n + z * hs[b][j];
    __syncthreads();
    hs[b][j] = hn;
    X[((size_t)b * 2096 + 2000 + t) * 32 + j] = hn;
    __syncthreads();
  }
}

// ---------------- Kernel 4: fused GNN pass ----------------
__global__ __launch_bounds__(256) void k_gnn(
    const float* __restrict__ Xa, const float* __restrict__ Xin,
    float* __restrict__ Xout, const float* __restrict__ W,
    const float* __restrict__ bias) {
  __shared__ float XaR[32][36];
  __shared__ float Xm[64][36];
  __shared__ float Xi[64][36];
  __shared__ float At[32][68];
  __shared__ float Ws[32][36];
  __shared__ float bs[32];
  int tid = threadIdx.x;
  int b = blockIdx.y;
  int r0 = blockIdx.x * 32;
  const float* Xab = Xa + (size_t)b * 2096 * 32;
  const float* Xib = Xin + (size_t)b * 2096 * 32;
  for (int i = tid; i < 32 * 32; i += 256) {
    int r = i >> 5, k = i & 31;
    XaR[r][k] = (r0 + r < 2096) ? Xab[(size_t)(r0 + r) * 32 + k] : 0.0f;
    Ws[r][k] = W[i];
  }
  if (tid < 32) bs[tid] = bias[tid];
  float acc[4] = {0.f, 0.f, 0.f, 0.f};
  int sm = tid & 63, rq = tid >> 6;
  int ar = tid & 31, fg = tid >> 5;
  for (int mt = 0; mt < 33; mt++) {
    int m0 = mt * 64;
    __syncthreads();
    for (int i = tid; i < 64 * 32; i += 256) {
      int m = i >> 5, k = i & 31;
      int gm = m0 + m;
      bool ok = gm < 2096;
      Xm[m][k] = ok ? Xab[(size_t)gm * 32 + k] : 0.0f;
      Xi[m][k] = ok ? Xib[(size_t)gm * 32 + k] : 0.0f;
    }
    __syncthreads();
    float xm[32];
#pragma unroll
    for (int k4 = 0; k4 < 8; k4++) {
      float4 v = *reinterpret_cast<const float4*>(&Xm[sm][k4 * 4]);
      xm[k4 * 4 + 0] = v.x; xm[k4 * 4 + 1] = v.y;
      xm[k4 * 4 + 2] = v.z; xm[k4 * 4 + 3] = v.w;
    }
#pragma unroll
    for (int i = 0; i < 8; i++) {
      int r = rq * 8 + i;
      float s = 0.0f;
#pragma unroll
      for (int k4 = 0; k4 < 8; k4++) {
        float4 xa = *reinterpret_cast<const float4*>(&XaR[r][k4 * 4]);
        s = fmaf(xa.x, xm[k4 * 4 + 0], s);
        s = fmaf(xa.y, xm[k4 * 4 + 1], s);
        s = fmaf(xa.z, xm[k4 * 4 + 2], s);
        s = fmaf(xa.w, xm[k4 * 4 + 3], s);
      }
      float e = __expf(-2.0f * fmaxf(s, 0.0f));
      At[r][sm] = (1.0f - e) / (1.0f + e);
    }
    __syncthreads();
    int f0 = fg * 4;
#pragma unroll
    for (int m = 0; m < 64; m += 4) {
      float4 av = *reinterpret_cast<const float4*>(&At[ar][m]);
      float4 x0 = *reinterpret_cast<const float4*>(&Xi[m + 0][f0]);
      float4 x1 = *reinterpret_cast<const float4*>(&Xi[m + 1][f0]);
      float4 x2 = *reinterpret_cast<const float4*>(&Xi[m + 2][f0]);
      float4 x3 = *reinterpret_cast<const float4*>(&Xi[m + 3][f0]);
      acc[0] = fmaf(av.x, x0.x, acc[0]); acc[1] = fmaf(av.x, x0.y, acc[1]);
      acc[2] = fmaf(av.x, x0.z, acc[2]); acc[3] = fmaf(av.x, x0.w, acc[3]);
      acc[0] = fmaf(av.y, x1.x, acc[0]); acc[1] = fmaf(av.y, x1.y, acc[1]);
      acc[2] = fmaf(av.y, x1.z, acc[2]); acc[3] = fmaf(av.y, x1.w, acc[3]);
      acc[0] = fmaf(av.z, x2.x, acc[0]); acc[1] = fmaf(av.z, x2.y, acc[1]);
      acc[2] = fmaf(av.z, x2.z, acc[2]); acc[3] = fmaf(av.z, x2.w, acc[3]);
      acc[0] = fmaf(av.w, x3.x, acc[0]); acc[1] = fmaf(av.w, x3.y, acc[1]);
      acc[2] = fmaf(av.w, x3.z, acc[2]); acc[3] = fmaf(av.w, x3.w, acc[3]);
    }
  }
  __syncthreads();
  {
    int f0 = fg * 4;
    Xm[ar][f0 + 0] = acc[0]; Xm[ar][f0 + 1] = acc[1];
    Xm[ar][f0 + 2] = acc[2]; Xm[ar][f0 + 3] = acc[3];
  }
  __syncthreads();
  int f0 = fg * 4;
  float o[4];
#pragma unroll
  for (int j = 0; j < 4; j++) o[j] = bs[f0 + j];
#pragma unroll
  for (int k = 0; k < 32; k++) {
    float mv = Xm[ar][k];
    float4 wv = *reinterpret_cast<const float4*>(&Ws[k][f0]);
    o[0] = fmaf(mv, wv.x, o[0]);
    o[1] = fmaf(mv, wv.y, o[1]);
    o[2] = fmaf(mv, wv.z, o[2]);
    o[3] = fmaf(mv, wv.w, o[3]);
  }
  int grr = r0 + ar;
  if (grr < 2096) {
    float* dst = Xout + ((size_t)b * 2096 + grr) * 32 + f0;
#pragma unroll
    for (int j = 0; j < 4; j++) {
      float v = o[j];
      dst[j] = v > 0.0f ? v : (__expf(v) - 1.0f);
    }
  }
}

// ---------------- Kernel 5: spatial readout MLP rs ----------------
__global__ __launch_bounds__(256) void k_rs(
    const float* __restrict__ X, const float* __restrict__ W1,
    const float* __restrict__ b1, const float* __restrict__ W2,
    const float* __restrict__ b2, float* __restrict__ rs) {
  __shared__ float Xt[32][33];
  __shared__ float W2s[96][100];
  __shared__ float Hl[32][100];
  __shared__ float b1s[96], b2s[96];
  int tid = threadIdx.x;
  int b = blockIdx.y;
  int n0 = blockIdx.x * 32;
  for (int i = tid; i < 96 * 96; i += 256) W2s[i / 96][i % 96] = W2[i];
  if (tid < 96) { b1s[tid] = b1[tid]; b2s[tid] = b2[tid]; }
  for (int i = tid; i < 32 * 32; i += 256) {
    int r = i >> 5, k = i & 31;
    Xt[r][k] = (n0 + r < 2000) ? X[((size_t)b * 2096 + n0 + r) * 32 + k] : 0.0f;
  }
  __syncthreads();
  int r = tid & 31, cg = tid >> 5;
#pragma unroll
  for (int i = 0; i < 12; i++) {
    int c = cg * 12 + i;
    float a = b1s[c];
    for (int k = 0; k < 32; k++) a = fmaf(Xt[r][k], W1[k * 96 + c], a);
    Hl[r][c] = a > 0.0f ? a : (__expf(a) - 1.0f);
  }
  __syncthreads();
  float o[12];
#pragma unroll
  for (int i = 0; i < 12; i++) o[i] = b2s[cg * 12 + i];
  for (int k = 0; k < 96; k++) {
    float hv = Hl[r][k];
#pragma unroll
    for (int i = 0; i < 12; i++) o[i] = fmaf(hv, W2s[k][cg * 12 + i], o[i]);
  }
  if (n0 + r < 2000) {
    float* dst = rs + ((size_t)b * 2000 + n0 + r) * 96 + cg * 12;
#pragma unroll
    for (int i = 0; i < 12; i++) dst[i] = o[i];
  }
}

// ---------------- Kernel 6: tr-GRU input gates precompute ----------------
__global__ __launch_bounds__(256) void k_trgi(
    const float* __restrict__ X, const float* __restrict__ Wih,
    const float* __restrict__ bih, float* __restrict__ gi) {
  __shared__ float Xs[96][33];
  __shared__ float Wsh[384][33];
  int tid = threadIdx.x;
  int b = blockIdx.y;
  int g0 = blockIdx.x * 384;
  for (int i = tid; i < 96 * 32; i += 256) {
    int t = i >> 5, k = i & 31;
    Xs[t][k] = X[((size_t)b * 2096 + 2000 + t) * 32 + k];
  }
  for (int i = tid; i < 384 * 32; i += 256) {
    int g = i >> 5, k = i & 31;
    Wsh[g][k] = (g0 + g < 6000) ? Wih[(size_t)(g0 + g) * 32 + k] : 0.0f;
  }
  __syncthreads();
  for (int oi = tid; oi < 96 * 384; oi += 256) {
    int t = oi / 384, g = oi % 384;
    if (g0 + g >= 6000) continue;
    float a = bih[g0 + g];
#pragma unroll
    for (int k = 0; k < 32; k++) a = fmaf(Xs[t][k], Wsh[g][k], a);
    gi[((size_t)b * 96 + t) * 6000 + g0 + g] = a;
  }
}

// ---------------- Kernel 6b: init counters + zero h ----------------
__global__ __launch_bounds__(256) void k_init(int* __restrict__ cnt,
                                              _Float16* __restrict__ hA) {
  int i = blockIdx.x * 256 + threadIdx.x;
  if (i < 128) cnt[i] = 0;
  if (i < 16000) hA[i] = (_Float16)0.0f;
}

// ---------------- Kernel 7: tr-GRU scan, persistent, MFMA 16x16x32 f16 ----------------
// Per block-step: C[24 rows][8 b] = W[24][2048] * h[2048][8] via 2 M-tiles x 64 K-chunks,
// K split across 16 waves, cross-wave reduce through LDS parts.
__global__ __launch_bounds__(1024) void k_trgru(
    const float* __restrict__ gi, const float* __restrict__ whh,
    const float* __restrict__ bhh, _Float16* __restrict__ hA,
    _Float16* __restrict__ hB, float* __restrict__ rt,
    int* __restrict__ cnt) {
  __shared__ _Float16 wf0[32768];  // tile0 (rows 0-15): 64 chunks x 64 lanes x 8 f16, lane-linear
  __shared__ _Float16 wf1[16384];  // tile1 (rows 16-23): 64 chunks x 32 slots x 8 f16
  __shared__ _Float16 hf[16384];   // B-frags: 64 chunks x (4 kblk x 8 b) x 8 f16
  __shared__ float pt[4096];       // parts: [w 16][tile 2][lb 4][b 8][reg 4]
  int tid = threadIdx.x;
  int blk = blockIdx.x;
  int l = tid & 63, w = tid >> 6;

  // zero wf/hf (covers K-pad 2000..2047 and pad rows)
  {
    half8 z = {(_Float16)0, (_Float16)0, (_Float16)0, (_Float16)0,
               (_Float16)0, (_Float16)0, (_Float16)0, (_Float16)0};
    for (int i = tid; i < 8192; i += 1024) {
      if (i < 4096) ((half8*)wf0)[i] = z;
      else if (i < 6144) ((half8*)wf1)[i - 4096] = z;
      else ((half8*)hf)[i - 6144] = z;
    }
  }
  __syncthreads();
  // fill W fragments (one-time), f32 -> f16
  for (int i = tid; i < 6144; i += 1024) {
    if (i < 4096) {
      int c = i >> 6, ll = i & 63;
      int row = ll & 15, g = row >> 3, lj = row & 7;
      int kb = c * 32 + ((ll >> 4) << 3);
      if (kb <= 1992) {
        const float* src = whh + ((size_t)(g * 2000 + blk * 8 + lj)) * 2000 + kb;
        float4 v0 = *reinterpret_cast<const float4*>(src);
        float4 v1 = *reinterpret_cast<const float4*>(src + 4);
        half8 o = {(_Float16)v0.x, (_Float16)v0.y, (_Float16)v0.z, (_Float16)v0.w,
                   (_Float16)v1.x, (_Float16)v1.y, (_Float16)v1.z, (_Float16)v1.w};
        ((half8*)wf0)[i] = o;
      }
    } else {
      int idx = i - 4096;
      int c = idx >> 5, s = idx & 31;
      int lj = s & 7;
      int kb = c * 32 + ((s >> 3) << 3);
      if (kb <= 1992) {
        const float* src = whh + ((size_t)(2 * 2000 + blk * 8 + lj)) * 2000 + kb;
        float4 v0 = *reinterpret_cast<const float4*>(src);
        float4 v1 = *reinterpret_cast<const float4*>(src + 4);
        half8 o = {(_Float16)v0.x, (_Float16)v0.y, (_Float16)v0.z, (_Float16)v0.w,
                   (_Float16)v1.x, (_Float16)v1.y, (_Float16)v1.z, (_Float16)v1.w};
        ((half8*)wf1)[idx] = o;
      }
    }
  }

  // combine-thread state (tid < 64): (lj, cb)
  int lj = (tid >> 3) & 7, cb = tid & 7;
  int jg = blk * 8 + lj;
  float hold = 0.0f, bR = 0.f, bZ = 0.f, bN = 0.f;
  if (tid < 64) {
    bR = bhh[jg]; bZ = bhh[2000 + jg]; bN = bhh[4000 + jg];
  }
  int bslot = ((l >> 4) * 8 + (l & 7)) * 8;  // f16 offset within chunk (wf1 / hf)
  __syncthreads();

  for (int t = 0; t < 96; t++) {
    const _Float16* hc = (t & 1) ? hB : hA;
    _Float16* hn = (t & 1) ? hA : hB;
    // prefetch gi for combine
    float gir = 0.f, giz = 0.f, gin = 0.f;
    if (tid < 64) {
      const float* gp = gi + ((size_t)cb * 96 + t) * 6000;
      gir = gp[jg]; giz = gp[2000 + jg]; gin = gp[4000 + jg];
    }
    // stage h -> B fragments
    for (int i = tid; i < 2048; i += 1024) {
      int b = i & 7, k8 = i >> 3;
      if (k8 < 250) {
        half8 v = *reinterpret_cast<const half8*>(hc + b * 2000 + k8 * 8);
        *reinterpret_cast<half8*>(hf + ((k8 >> 2) * 256 + (k8 & 3) * 64 + b * 8)) = v;
      }
    }
    __syncthreads();
    // MFMA phase: wave w handles k-chunks 4w .. 4w+3
    f32x4 c0 = {0.f, 0.f, 0.f, 0.f}, c1 = {0.f, 0.f, 0.f, 0.f};
#pragma unroll
    for (int i = 0; i < 4; i++) {
      int c = w * 4 + i;
      half8 bv = *reinterpret_cast<const half8*>(hf + c * 256 + bslot);
      half8 a0 = *reinterpret_cast<const half8*>(wf0 + c * 512 + l * 8);
      half8 a1 = *reinterpret_cast<const half8*>(wf1 + c * 256 + bslot);
      c0 = __builtin_amdgcn_mfma_f32_16x16x32_f16(a0, bv, c0, 0, 0, 0);
      c1 = __builtin_amdgcn_mfma_f32_16x16x32_f16(a1, bv, c1, 0, 0, 0);
    }
    {
      int bcol = l & 15;
      if (bcol < 8) {
        int lb = l >> 4;
        *reinterpret_cast<f32x4*>(pt + w * 256 + ((0 * 4 + lb) * 8 + bcol) * 4) = c0;
        *reinterpret_cast<f32x4*>(pt + w * 256 + ((1 * 4 + lb) * 8 + bcol) * 4) = c1;
      }
    }
    __syncthreads();
    // combine (wave 0): reduce 16 wave-partials, GRU pointwise, write h / rt
    if (tid < 64) {
      float s[3];
#pragma unroll
      for (int g = 0; g < 3; g++) {
        int row = g * 8 + lj;
        int tile = row >> 4, rr = row & 15;
        int base = ((tile * 4 + (rr >> 2)) * 8 + cb) * 4 + (rr & 3);
        float acc = 0.f;
#pragma unroll
        for (int w2 = 0; w2 < 16; w2++) acc += pt[w2 * 256 + base];
        s[g] = acc;
      }
      float r_ = 1.0f / (1.0f + __expf(-(gir + s[0] + bR)));
      float z_ = 1.0f / (1.0f + __expf(-(giz + s[1] + bZ)));
      float n_ = tanhf(gin + r_ * (s[2] + bN));
      hold = (1.0f - z_) * n_ + z_ * hold;
      hn[cb * 2000 + jg] = (_Float16)hold;
      rt[((size_t)cb * 96 + t) * 2000 + jg] = hold;
    }
    // release (after this wave's global writes), then global barrier
    if (tid == 0) {
      __hip_atomic_fetch_add(&cnt[t + 1], 1, __ATOMIC_RELEASE, __HIP_MEMORY_SCOPE_AGENT);
    }
    if (tid == 64) {
      while (__hip_atomic_load(&cnt[t + 1], __ATOMIC_ACQUIRE, __HIP_MEMORY_SCOPE_AGENT) < NBLK) {
        __builtin_amdgcn_s_sleep(1);
      }
    }
    __syncthreads();
  }
}

// ---------------- Kernel 8: final combine + out matmul ----------------
__global__ __launch_bounds__(256) void k_final(
    const float* __restrict__ rs, const float* __restrict__ rt,
    const float* __restrict__ outW, const float* __restrict__ outb,
    float* __restrict__ out) {
  __shared__ float w[96];
  __shared__ float ob;
  int tid = threadIdx.x;
  if (tid < 96) w[tid] = outW[tid];
  if (tid == 0) ob = outb[0];
  __syncthreads();
  int gidx = blockIdx.x * 256 + tid;
  if (gidx >= 16000) return;
  int b = gidx / 2000, n = gidx % 2000;
  const float* rsp = rs + (size_t)gidx * 96;
  float acc = ob;
  for (int t4 = 0; t4 < 24; t4++) {
    float4 rv = *reinterpret_cast<const float4*>(rsp + t4 * 4);
    int t = t4 * 4;
    acc = fmaf(rv.x + rt[((size_t)b * 96 + t + 0) * 2000 + n], w[t + 0], acc);
    acc = fmaf(rv.y + rt[((size_t)b * 96 + t + 1) * 2000 + n], w[t + 1], acc);
    acc = fmaf(rv.z + rt[((size_t)b * 96 + t + 2) * 2000 + n], w[t + 2], acc);
    acc = fmaf(rv.w + rt[((size_t)b * 96 + t + 3) * 2000 + n], w[t + 3], acc);
  }
  out[gidx] = acc;
}

extern "C" void kernel_launch(void* const* d_in, const int* in_sizes, int n_in,
                              void* d_out, int out_size, void* d_ws, size_t ws_size,
                              hipStream_t stream) {
  const float* x      = (const float*)d_in[0];
  const float* x_mark = (const float*)d_in[1];
  const float* sp_emb = (const float*)d_in[2];
  const float* sp_W1  = (const float*)d_in[3];
  const float* sp_b1  = (const float*)d_in[4];
  const float* sp_W2  = (const float*)d_in[5];
  const float* sp_b2  = (const float*)d_in[6];
  const float* t_emb  = (const float*)d_in[7];
  const float* t_Wih  = (const float*)d_in[8];
  const float* t_Whh  = (const float*)d_in[9];
  const float* t_bih  = (const float*)d_in[10];
  const float* t_bhh  = (const float*)d_in[11];
  const float* gcn_W  = (const float*)d_in[12];
  const float* gcn_b  = (const float*)d_in[13];
  const float* fr_W1  = (const float*)d_in[14];
  const float* fr_b1  = (const float*)d_in[15];
  const float* fr_W2  = (const float*)d_in[16];
  const float* fr_b2  = (const float*)d_in[17];
  const float* tr_Wih = (const float*)d_in[18];
  const float* tr_Whh = (const float*)d_in[19];
  const float* tr_bih = (const float*)d_in[20];
  const float* tr_bhh = (const float*)d_in[21];
  const float* out_W  = (const float*)d_in[22];
  const float* out_b  = (const float*)d_in[23];
  (void)in_sizes; (void)n_in; (void)out_size; (void)ws_size;

  float* ws = (float*)d_ws;
  float* X0   = ws;                    // 8*2096*32 = 536576
  float* X1   = X0 + 536576;
  float* X2   = X1 + 536576;
  float* tgi  = X2 + 536576;           // 768*96 = 73728
  float* trgi = tgi + 73728;           // 8*96*6000 = 4608000
  float* hsl  = trgi + 4608000;        // 16000 f32 slot -> hA/hB (f16, 16000 each)
  float* cns  = hsl + 16000;           // 16000 f32 slot -> cnt
  float* rt   = cns + 16000;           // 8*96*2000 = 1536000
  float* rs   = rt + 1536000;          // 8*2000*96 = 1536000

  _Float16* hA = (_Float16*)hsl;
  _Float16* hB = hA + 16000;
  int* cnt = (int*)cns;

  k_init<<<63, 256, 0, stream>>>(cnt, hA);
  k_spatial<<<63, 256, 0, stream>>>(x, sp_emb, sp_W1, sp_b1, sp_W2, sp_b2, X0);
  k_tgi<<<96, 256, 0, stream>>>(x, x_mark, t_emb, t_Wih, t_bih, tgi);
  k_tgru<<<1, 256, 0, stream>>>(tgi, t_Whh, t_bhh, X0);

  dim3 gg(66, 8);
  k_gnn<<<gg, 256, 0, stream>>>(X0, X0, X1, gcn_W + 0 * 1024, gcn_b + 0 * 32);
  k_gnn<<<gg, 256, 0, stream>>>(X0, X1, X2, gcn_W + 1 * 1024, gcn_b + 1 * 32);
  k_gnn<<<gg, 256, 0, stream>>>(X2, X2, X0, gcn_W + 2 * 1024, gcn_b + 2 * 32);
  k_gnn<<<gg, 256, 0, stream>>>(X2, X0, X1, gcn_W + 3 * 1024, gcn_b + 3 * 32);

  k_rs<<<dim3(63, 8), 256, 0, stream>>>(X1, fr_W1, fr_b1, fr_W2, fr_b2, rs);
  k_trgi<<<dim3(16, 8), 256, 0, stream>>>(X1, tr_Wih, tr_bih, trgi);

  {
    const float* a0 = trgi;
    const float* a1 = tr_Whh;
    const float* a2 = tr_bhh;
    _Float16* a3 = hA;
    _Float16* a4 = hB;
    float* a5 = rt;
    int* a6 = cnt;
    void* cargs[] = {&a0, &a1, &a2, &a3, &a4, &a5, &a6};
    hipLaunchCooperativeKernel((const void*)k_trgru, dim3(NBLK), dim3(1024), cargs, 0, stream);
  }

  k_final<<<63, 256, 0, stream>>>(rs, rt, out_W, out_b, (float*)d_out);
}

// Round 4
// 3351.130 us; speedup vs baseline: 1.0453x; 1.0453x over previous
//
#include <hip/hip_runtime.h>

typedef _Float16 h4 __attribute__((ext_vector_type(4)));
typedef _Float16 half8 __attribute__((ext_vector_type(8)));
typedef float f32x4 __attribute__((ext_vector_type(4)));

#define NBLK 250
#define NGRP 16
#define BAR_INTS (96 * NGRP * 32 + 96 * 32)

// ---------------- Kernel 1: spatial MLP -> X[:, 0:2000, :] ----------------
__global__ __launch_bounds__(256) void k_spatial(
    const float* __restrict__ x, const float* __restrict__ sp_emb,
    const float* __restrict__ W1, const float* __restrict__ b1,
    const float* __restrict__ W2, const float* __restrict__ b2,
    float* __restrict__ X) {
  __shared__ float W1s[128 * 32];
  __shared__ float W2s[32 * 32];
  __shared__ float b1s[32], b2s[32];
  int tid = threadIdx.x;
  for (int i = tid; i < 128 * 32; i += 256) W1s[i] = W1[i];
  for (int i = tid; i < 32 * 32; i += 256) W2s[i] = W2[i];
  if (tid < 32) { b1s[tid] = b1[tid]; b2s[tid] = b2[tid]; }
  __syncthreads();
  int gidx = blockIdx.x * 256 + tid;
  if (gidx >= 8 * 2000) return;
  int b = gidx / 2000, n = gidx % 2000;
  float h1[32];
#pragma unroll
  for (int l = 0; l < 32; l++) h1[l] = b1s[l];
  for (int k = 0; k < 96; k++) {
    float xv = x[((size_t)b * 96 + k) * 2000 + n];
#pragma unroll
    for (int l = 0; l < 32; l++) h1[l] = fmaf(xv, W1s[k * 32 + l], h1[l]);
  }
  for (int e4 = 0; e4 < 8; e4++) {
    float4 ev = *reinterpret_cast<const float4*>(&sp_emb[(size_t)n * 32 + e4 * 4]);
    float evs[4] = {ev.x, ev.y, ev.z, ev.w};
#pragma unroll
    for (int q = 0; q < 4; q++) {
      int e = e4 * 4 + q;
#pragma unroll
      for (int l = 0; l < 32; l++) h1[l] = fmaf(evs[q], W1s[(96 + e) * 32 + l], h1[l]);
    }
  }
  float out[32];
#pragma unroll
  for (int j = 0; j < 32; j++) out[j] = b2s[j];
  for (int l = 0; l < 32; l++) {
    float a = h1[l] > 0.0f ? h1[l] : (__expf(h1[l]) - 1.0f);
#pragma unroll
    for (int j = 0; j < 32; j++) out[j] = fmaf(a, W2s[l * 32 + j], out[j]);
  }
  float* dst = X + ((size_t)b * 2096 + n) * 32;
#pragma unroll
  for (int j = 0; j < 32; j++) dst[j] = out[j];
}

// ---------------- Kernel 2: temporal GRU input gates precompute ----------------
__global__ __launch_bounds__(256) void k_tgi(
    const float* __restrict__ x, const float* __restrict__ x_mark,
    const float* __restrict__ t_emb, const float* __restrict__ Wih,
    const float* __restrict__ bih, float* __restrict__ gi) {
  __shared__ float xs[8][2036];
  int tid = threadIdx.x;
  int row0 = blockIdx.x * 8;
  for (int rr = 0; rr < 8; rr++) {
    int row = row0 + rr;
    int b = row / 96, t = row % 96;
    for (int k = tid; k < 2036; k += 256) {
      float v;
      if (k < 2000) v = x[((size_t)b * 96 + t) * 2000 + k];
      else if (k < 2004) v = x_mark[((size_t)b * 96 + t) * 4 + (k - 2000)];
      else v = t_emb[(size_t)t * 32 + (k - 2004)];
      xs[rr][k] = v;
    }
  }
  __syncthreads();
  for (int oi = tid; oi < 8 * 96; oi += 256) {
    int rr = oi / 96, g = oi % 96;
    const float* w = Wih + (size_t)g * 2036;
    float acc = bih[g];
    for (int k = 0; k < 2036; k += 4) {
      float4 wv = *reinterpret_cast<const float4*>(w + k);
      acc = fmaf(xs[rr][k + 0], wv.x, acc);
      acc = fmaf(xs[rr][k + 1], wv.y, acc);
      acc = fmaf(xs[rr][k + 2], wv.z, acc);
      acc = fmaf(xs[rr][k + 3], wv.w, acc);
    }
    gi[(size_t)(row0 + rr) * 96 + g] = acc;
  }
}

// ---------------- Kernel 3: temporal GRU scan (hidden=32) ----------------
__global__ __launch_bounds__(256) void k_tgru(
    const float* __restrict__ gi, const float* __restrict__ Whh,
    const float* __restrict__ bhh, float* __restrict__ X) {
  __shared__ float Whs[96][33];
  __shared__ float hs[8][33];
  int tid = threadIdx.x;
  for (int i = tid; i < 96 * 32; i += 256) Whs[i / 32][i % 32] = Whh[i];
  int b = tid >> 5, j = tid & 31;
  hs[b][j] = 0.0f;
  __syncthreads();
  for (int t = 0; t < 96; t++) {
    float gr = bhh[j], gz = bhh[32 + j], gn = bhh[64 + j];
#pragma unroll 8
    for (int k = 0; k < 32; k++) {
      float hv = hs[b][k];
      gr = fmaf(hv, Whs[j][k], gr);
      gz = fmaf(hv, Whs[32 + j][k], gz);
      gn = fmaf(hv, Whs[64 + j][k], gn);
    }
    const float* g = gi + ((size_t)b * 96 + t) * 96;
    float ir = g[j], iz = g[32 + j], inn = g[64 + j];
    float r = 1.0f / (1.0f + __expf(-(ir + gr)));
    float z = 1.0f / (1.0f + __expf(-(iz + gz)));
    float n = tanhf(inn + r * gn);
    float hn = (1.0f - z) * n + z * hs[b][j];
    __syncthreads();
    hs[b][j] = hn;
    X[((size_t)b * 2096 + 2000 + t) * 32 + j] = hn;
    __syncthreads();
  }
}

// ---------------- Kernel 4: fused GNN pass ----------------
__global__ __launch_bounds__(256) void k_gnn(
    const float* __restrict__ Xa, const float* __restrict__ Xin,
    float* __restrict__ Xout, const float* __restrict__ W,
    const float* __restrict__ bias) {
  __shared__ float XaR[32][36];
  __shared__ float Xm[64][36];
  __shared__ float Xi[64][36];
  __shared__ float At[32][68];
  __shared__ float Ws[32][36];
  __shared__ float bs[32];
  int tid = threadIdx.x;
  int b = blockIdx.y;
  int r0 = blockIdx.x * 32;
  const float* Xab = Xa + (size_t)b * 2096 * 32;
  const float* Xib = Xin + (size_t)b * 2096 * 32;
  for (int i = tid; i < 32 * 32; i += 256) {
    int r = i >> 5, k = i & 31;
    XaR[r][k] = (r0 + r < 2096) ? Xab[(size_t)(r0 + r) * 32 + k] : 0.0f;
    Ws[r][k] = W[i];
  }
  if (tid < 32) bs[tid] = bias[tid];
  float acc[4] = {0.f, 0.f, 0.f, 0.f};
  int sm = tid & 63, rq = tid >> 6;
  int ar = tid & 31, fg = tid >> 5;
  for (int mt = 0; mt < 33; mt++) {
    int m0 = mt * 64;
    __syncthreads();
    for (int i = tid; i < 64 * 32; i += 256) {
      int m = i >> 5, k = i & 31;
      int gm = m0 + m;
      bool ok = gm < 2096;
      Xm[m][k] = ok ? Xab[(size_t)gm * 32 + k] : 0.0f;
      Xi[m][k] = ok ? Xib[(size_t)gm * 32 + k] : 0.0f;
    }
    __syncthreads();
    float xm[32];
#pragma unroll
    for (int k4 = 0; k4 < 8; k4++) {
      float4 v = *reinterpret_cast<const float4*>(&Xm[sm][k4 * 4]);
      xm[k4 * 4 + 0] = v.x; xm[k4 * 4 + 1] = v.y;
      xm[k4 * 4 + 2] = v.z; xm[k4 * 4 + 3] = v.w;
    }
#pragma unroll
    for (int i = 0; i < 8; i++) {
      int r = rq * 8 + i;
      float s = 0.0f;
#pragma unroll
      for (int k4 = 0; k4 < 8; k4++) {
        float4 xa = *reinterpret_cast<const float4*>(&XaR[r][k4 * 4]);
        s = fmaf(xa.x, xm[k4 * 4 + 0], s);
        s = fmaf(xa.y, xm[k4 * 4 + 1], s);
        s = fmaf(xa.z, xm[k4 * 4 + 2], s);
        s = fmaf(xa.w, xm[k4 * 4 + 3], s);
      }
      float e = __expf(-2.0f * fmaxf(s, 0.0f));
      At[r][sm] = (1.0f - e) / (1.0f + e);
    }
    __syncthreads();
    int f0 = fg * 4;
#pragma unroll
    for (int m = 0; m < 64; m += 4) {
      float4 av = *reinterpret_cast<const float4*>(&At[ar][m]);
      float4 x0 = *reinterpret_cast<const float4*>(&Xi[m + 0][f0]);
      float4 x1 = *reinterpret_cast<const float4*>(&Xi[m + 1][f0]);
      float4 x2 = *reinterpret_cast<const float4*>(&Xi[m + 2][f0]);
      float4 x3 = *reinterpret_cast<const float4*>(&Xi[m + 3][f0]);
      acc[0] = fmaf(av.x, x0.x, acc[0]); acc[1] = fmaf(av.x, x0.y, acc[1]);
      acc[2] = fmaf(av.x, x0.z, acc[2]); acc[3] = fmaf(av.x, x0.w, acc[3]);
      acc[0] = fmaf(av.y, x1.x, acc[0]); acc[1] = fmaf(av.y, x1.y, acc[1]);
      acc[2] = fmaf(av.y, x1.z, acc[2]); acc[3] = fmaf(av.y, x1.w, acc[3]);
      acc[0] = fmaf(av.z, x2.x, acc[0]); acc[1] = fmaf(av.z, x2.y, acc[1]);
      acc[2] = fmaf(av.z, x2.z, acc[2]); acc[3] = fmaf(av.z, x2.w, acc[3]);
      acc[0] = fmaf(av.w, x3.x, acc[0]); acc[1] = fmaf(av.w, x3.y, acc[1]);
      acc[2] = fmaf(av.w, x3.z, acc[2]); acc[3] = fmaf(av.w, x3.w, acc[3]);
    }
  }
  __syncthreads();
  {
    int f0 = fg * 4;
    Xm[ar][f0 + 0] = acc[0]; Xm[ar][f0 + 1] = acc[1];
    Xm[ar][f0 + 2] = acc[2]; Xm[ar][f0 + 3] = acc[3];
  }
  __syncthreads();
  int f0 = fg * 4;
  float o[4];
#pragma unroll
  for (int j = 0; j < 4; j++) o[j] = bs[f0 + j];
#pragma unroll
  for (int k = 0; k < 32; k++) {
    float mv = Xm[ar][k];
    float4 wv = *reinterpret_cast<const float4*>(&Ws[k][f0]);
    o[0] = fmaf(mv, wv.x, o[0]);
    o[1] = fmaf(mv, wv.y, o[1]);
    o[2] = fmaf(mv, wv.z, o[2]);
    o[3] = fmaf(mv, wv.w, o[3]);
  }
  int grr = r0 + ar;
  if (grr < 2096) {
    float* dst = Xout + ((size_t)b * 2096 + grr) * 32 + f0;
#pragma unroll
    for (int j = 0; j < 4; j++) {
      float v = o[j];
      dst[j] = v > 0.0f ? v : (__expf(v) - 1.0f);
    }
  }
}

// ---------------- Kernel 5: spatial readout MLP rs ----------------
__global__ __launch_bounds__(256) void k_rs(
    const float* __restrict__ X, const float* __restrict__ W1,
    const float* __restrict__ b1, const float* __restrict__ W2,
    const float* __restrict__ b2, float* __restrict__ rs) {
  __shared__ float Xt[32][33];
  __shared__ float W2s[96][100];
  __shared__ float Hl[32][100];
  __shared__ float b1s[96], b2s[96];
  int tid = threadIdx.x;
  int b = blockIdx.y;
  int n0 = blockIdx.x * 32;
  for (int i = tid; i < 96 * 96; i += 256) W2s[i / 96][i % 96] = W2[i];
  if (tid < 96) { b1s[tid] = b1[tid]; b2s[tid] = b2[tid]; }
  for (int i = tid; i < 32 * 32; i += 256) {
    int r = i >> 5, k = i & 31;
    Xt[r][k] = (n0 + r < 2000) ? X[((size_t)b * 2096 + n0 + r) * 32 + k] : 0.0f;
  }
  __syncthreads();
  int r = tid & 31, cg = tid >> 5;
#pragma unroll
  for (int i = 0; i < 12; i++) {
    int c = cg * 12 + i;
    float a = b1s[c];
    for (int k = 0; k < 32; k++) a = fmaf(Xt[r][k], W1[k * 96 + c], a);
    Hl[r][c] = a > 0.0f ? a : (__expf(a) - 1.0f);
  }
  __syncthreads();
  float o[12];
#pragma unroll
  for (int i = 0; i < 12; i++) o[i] = b2s[cg * 12 + i];
  for (int k = 0; k < 96; k++) {
    float hv = Hl[r][k];
#pragma unroll
    for (int i = 0; i < 12; i++) o[i] = fmaf(hv, W2s[k][cg * 12 + i], o[i]);
  }
  if (n0 + r < 2000) {
    float* dst = rs + ((size_t)b * 2000 + n0 + r) * 96 + cg * 12;
#pragma unroll
    for (int i = 0; i < 12; i++) dst[i] = o[i];
  }
}

// ---------------- Kernel 6: tr-GRU input gates precompute ----------------
__global__ __launch_bounds__(256) void k_trgi(
    const float* __restrict__ X, const float* __restrict__ Wih,
    const float* __restrict__ bih, float* __restrict__ gi) {
  __shared__ float Xs[96][33];
  __shared__ float Wsh[384][33];
  int tid = threadIdx.x;
  int b = blockIdx.y;
  int g0 = blockIdx.x * 384;
  for (int i = tid; i < 96 * 32; i += 256) {
    int t = i >> 5, k = i & 31;
    Xs[t][k] = X[((size_t)b * 2096 + 2000 + t) * 32 + k];
  }
  for (int i = tid; i < 384 * 32; i += 256) {
    int g = i >> 5, k = i & 31;
    Wsh[g][k] = (g0 + g < 6000) ? Wih[(size_t)(g0 + g) * 32 + k] : 0.0f;
  }
  __syncthreads();
  for (int oi = tid; oi < 96 * 384; oi += 256) {
    int t = oi / 384, g = oi % 384;
    if (g0 + g >= 6000) continue;
    float a = bih[g0 + g];
#pragma unroll
    for (int k = 0; k < 32; k++) a = fmaf(Xs[t][k], Wsh[g][k], a);
    gi[((size_t)b * 96 + t) * 6000 + g0 + g] = a;
  }
}

// ---------------- Kernel 6b: init barrier counters + zero h ----------------
__global__ __launch_bounds__(256) void k_init(int* __restrict__ bar,
                                              _Float16* __restrict__ hA) {
  int i = blockIdx.x * 256 + threadIdx.x;
  for (int j = i; j < BAR_INTS; j += gridDim.x * 256) bar[j] = 0;
  if (i < 16000) hA[i] = (_Float16)0.0f;
}

// ---------------- Kernel 7: tr-GRU scan, persistent, MFMA + tree barrier ----------------
// Per block-step: C[24 rows][8 b] = W[24][2048] * h[2048][8] via 2 M-tiles x 64 K-chunks,
// K split across 16 waves, cross-wave reduce through LDS parts.
// Grid sync: two-level (16 padded group counters -> 1 root), t-indexed (no reset hazard).
__global__ __launch_bounds__(1024) void k_trgru(
    const float* __restrict__ gi, const float* __restrict__ whh,
    const float* __restrict__ bhh, _Float16* __restrict__ hA,
    _Float16* __restrict__ hB, float* __restrict__ rt,
    int* __restrict__ grp, int* __restrict__ root) {
  __shared__ _Float16 wf0[32768];  // tile0 (rows 0-15): 64 chunks x 64 lanes x 8 f16
  __shared__ _Float16 wf1[16384];  // tile1 (rows 16-23): 64 chunks x 32 slots x 8 f16
  __shared__ _Float16 hf[16384];   // B-frags: 64 chunks x (4 kblk x 8 b) x 8 f16
  __shared__ float pt[4096];       // parts: [w 16][tile 2][lb 4][b 8][reg 4]
  int tid = threadIdx.x;
  int blk = blockIdx.x;
  int l = tid & 63, w = tid >> 6;

  // zero wf/hf (covers K-pad 2000..2047)
  {
    half8 z = {(_Float16)0, (_Float16)0, (_Float16)0, (_Float16)0,
               (_Float16)0, (_Float16)0, (_Float16)0, (_Float16)0};
    for (int i = tid; i < 8192; i += 1024) {
      if (i < 4096) ((half8*)wf0)[i] = z;
      else if (i < 6144) ((half8*)wf1)[i - 4096] = z;
      else ((half8*)hf)[i - 6144] = z;
    }
  }
  __syncthreads();
  // fill W fragments (one-time), f32 -> f16
  for (int i = tid; i < 6144; i += 1024) {
    if (i < 4096) {
      int c = i >> 6, ll = i & 63;
      int row = ll & 15, g = row >> 3, lj = row & 7;
      int kb = c * 32 + ((ll >> 4) << 3);
      if (kb <= 1992) {
        const float* src = whh + ((size_t)(g * 2000 + blk * 8 + lj)) * 2000 + kb;
        float4 v0 = *reinterpret_cast<const float4*>(src);
        float4 v1 = *reinterpret_cast<const float4*>(src + 4);
        half8 o = {(_Float16)v0.x, (_Float16)v0.y, (_Float16)v0.z, (_Float16)v0.w,
                   (_Float16)v1.x, (_Float16)v1.y, (_Float16)v1.z, (_Float16)v1.w};
        ((half8*)wf0)[i] = o;
      }
    } else {
      int idx = i - 4096;
      int c = idx >> 5, s = idx & 31;
      int lj = s & 7;
      int kb = c * 32 + ((s >> 3) << 3);
      if (kb <= 1992) {
        const float* src = whh + ((size_t)(2 * 2000 + blk * 8 + lj)) * 2000 + kb;
        float4 v0 = *reinterpret_cast<const float4*>(src);
        float4 v1 = *reinterpret_cast<const float4*>(src + 4);
        half8 o = {(_Float16)v0.x, (_Float16)v0.y, (_Float16)v0.z, (_Float16)v0.w,
                   (_Float16)v1.x, (_Float16)v1.y, (_Float16)v1.z, (_Float16)v1.w};
        ((half8*)wf1)[idx] = o;
      }
    }
  }

  // combine-thread state (tid < 64): (lj, cb)
  int lj = (tid >> 3) & 7, cb = tid & 7;
  int jg = blk * 8 + lj;
  float hold = 0.0f, bR = 0.f, bZ = 0.f, bN = 0.f;
  if (tid < 64) {
    bR = bhh[jg]; bZ = bhh[2000 + jg]; bN = bhh[4000 + jg];
  }
  int bslot = ((l >> 4) * 8 + (l & 7)) * 8;  // f16 offset within chunk (wf1 / hf)
  int mygrp = blk >> 4;                       // 16 groups: 15x16 + 1x10
  int gsz = (mygrp == 15) ? 10 : 16;
  __syncthreads();

  for (int t = 0; t < 96; t++) {
    const _Float16* hc = (t & 1) ? hB : hA;
    _Float16* hn = (t & 1) ? hA : hB;
    // prefetch gi for combine (overlaps staging + MFMA)
    float gir = 0.f, giz = 0.f, gin = 0.f;
    if (tid < 64) {
      const float* gp = gi + ((size_t)cb * 96 + t) * 6000;
      gir = gp[jg]; giz = gp[2000 + jg]; gin = gp[4000 + jg];
    }
    // stage h -> B fragments
    for (int i = tid; i < 2048; i += 1024) {
      int b = i & 7, k8 = i >> 3;
      if (k8 < 250) {
        half8 v = *reinterpret_cast<const half8*>(hc + b * 2000 + k8 * 8);
        *reinterpret_cast<half8*>(hf + ((k8 >> 2) * 256 + (k8 & 3) * 64 + b * 8)) = v;
      }
    }
    __syncthreads();
    // MFMA phase: wave w handles k-chunks 4w .. 4w+3
    f32x4 c0 = {0.f, 0.f, 0.f, 0.f}, c1 = {0.f, 0.f, 0.f, 0.f};
#pragma unroll
    for (int i = 0; i < 4; i++) {
      int c = w * 4 + i;
      half8 bv = *reinterpret_cast<const half8*>(hf + c * 256 + bslot);
      half8 a0 = *reinterpret_cast<const half8*>(wf0 + c * 512 + l * 8);
      half8 a1 = *reinterpret_cast<const half8*>(wf1 + c * 256 + bslot);
      c0 = __builtin_amdgcn_mfma_f32_16x16x32_f16(a0, bv, c0, 0, 0, 0);
      c1 = __builtin_amdgcn_mfma_f32_16x16x32_f16(a1, bv, c1, 0, 0, 0);
    }
    {
      int bcol = l & 15;
      if (bcol < 8) {
        int lb = l >> 4;
        *reinterpret_cast<f32x4*>(pt + w * 256 + ((0 * 4 + lb) * 8 + bcol) * 4) = c0;
        *reinterpret_cast<f32x4*>(pt + w * 256 + ((1 * 4 + lb) * 8 + bcol) * 4) = c1;
      }
    }
    __syncthreads();
    // combine (wave 0): reduce 16 wave-partials, GRU pointwise, write h / rt
    if (tid < 64) {
      float s[3];
#pragma unroll
      for (int g = 0; g < 3; g++) {
        int row = g * 8 + lj;
        int tile = row >> 4, rr = row & 15;
        int base = ((tile * 4 + (rr >> 2)) * 8 + cb) * 4 + (rr & 3);
        float acc = 0.f;
#pragma unroll
        for (int w2 = 0; w2 < 16; w2++) acc += pt[w2 * 256 + base];
        s[g] = acc;
      }
      float r_ = 1.0f / (1.0f + __expf(-(gir + s[0] + bR)));
      float z_ = 1.0f / (1.0f + __expf(-(giz + s[1] + bZ)));
      float n_ = tanhf(gin + r_ * (s[2] + bN));
      hold = (1.0f - z_) * n_ + z_ * hold;
      hn[cb * 2000 + jg] = (_Float16)hold;
      rt[((size_t)cb * 96 + t) * 2000 + jg] = hold;
    }
    // ---- two-level tree barrier (t-indexed counters, no reset hazard) ----
    if (tid == 0) {
      // ACQ_REL release drains this wave's h/rt stores to the coherence point
      int r = __hip_atomic_fetch_add(&grp[(t * NGRP + mygrp) * 32], 1,
                                     __ATOMIC_ACQ_REL, __HIP_MEMORY_SCOPE_AGENT);
      if (r == gsz - 1) {
        __hip_atomic_fetch_add(&root[t * 32], 1, __ATOMIC_ACQ_REL,
                               __HIP_MEMORY_SCOPE_AGENT);
      }
    }
    if (tid == 64) {
      while (__hip_atomic_load(&root[t * 32], __ATOMIC_ACQUIRE,
                               __HIP_MEMORY_SCOPE_AGENT) < NGRP) {
        __builtin_amdgcn_s_sleep(2);
      }
    }
    __syncthreads();
  }
}

// ---------------- Kernel 8: final combine + out matmul ----------------
__global__ __launch_bounds__(256) void k_final(
    const float* __restrict__ rs, const float* __restrict__ rt,
    const float* __restrict__ outW, const float* __restrict__ outb,
    float* __restrict__ out) {
  __shared__ float w[96];
  __shared__ float ob;
  int tid = threadIdx.x;
  if (tid < 96) w[tid] = outW[tid];
  if (tid == 0) ob = outb[0];
  __syncthreads();
  int gidx = blockIdx.x * 256 + tid;
  if (gidx >= 16000) return;
  int b = gidx / 2000, n = gidx % 2000;
  const float* rsp = rs + (size_t)gidx * 96;
  float acc = ob;
  for (int t4 = 0; t4 < 24; t4++) {
    float4 rv = *reinterpret_cast<const float4*>(rsp + t4 * 4);
    int t = t4 * 4;
    acc = fmaf(rv.x + rt[((size_t)b * 96 + t + 0) * 2000 + n], w[t + 0], acc);
    acc = fmaf(rv.y + rt[((size_t)b * 96 + t + 1) * 2000 + n], w[t + 1], acc);
    acc = fmaf(rv.z + rt[((size_t)b * 96 + t + 2) * 2000 + n], w[t + 2], acc);
    acc = fmaf(rv.w + rt[((size_t)b * 96 + t + 3) * 2000 + n], w[t + 3], acc);
  }
  out[gidx] = acc;
}

extern "C" void kernel_launch(void* const* d_in, const int* in_sizes, int n_in,
                              void* d_out, int out_size, void* d_ws, size_t ws_size,
                              hipStream_t stream) {
  const float* x      = (const float*)d_in[0];
  const float* x_mark = (const float*)d_in[1];
  const float* sp_emb = (const float*)d_in[2];
  const float* sp_W1  = (const float*)d_in[3];
  const float* sp_b1  = (const float*)d_in[4];
  const float* sp_W2  = (const float*)d_in[5];
  const float* sp_b2  = (const float*)d_in[6];
  const float* t_emb  = (const float*)d_in[7];
  const float* t_Wih  = (const float*)d_in[8];
  const float* t_Whh  = (const float*)d_in[9];
  const float* t_bih  = (const float*)d_in[10];
  const float* t_bhh  = (const float*)d_in[11];
  const float* gcn_W  = (const float*)d_in[12];
  const float* gcn_b  = (const float*)d_in[13];
  const float* fr_W1  = (const float*)d_in[14];
  const float* fr_b1  = (const float*)d_in[15];
  const float* fr_W2  = (const float*)d_in[16];
  const float* fr_b2  = (const float*)d_in[17];
  const float* tr_Wih = (const float*)d_in[18];
  const float* tr_Whh = (const float*)d_in[19];
  const float* tr_bih = (const float*)d_in[20];
  const float* tr_bhh = (const float*)d_in[21];
  const float* out_W  = (const float*)d_in[22];
  const float* out_b  = (const float*)d_in[23];
  (void)in_sizes; (void)n_in; (void)out_size; (void)ws_size;

  float* ws = (float*)d_ws;
  float* X0   = ws;                    // 8*2096*32 = 536576
  float* X1   = X0 + 536576;
  float* X2   = X1 + 536576;
  float* tgi  = X2 + 536576;           // 768*96 = 73728
  float* trgi = tgi + 73728;           // 8*96*6000 = 4608000
  float* hsl  = trgi + 4608000;        // 16000 f32 slot -> hA/hB (f16, 16000 each)
  float* rt   = hsl + 16000;           // 8*96*2000 = 1536000
  float* rs   = rt + 1536000;          // 8*2000*96 = 1536000
  float* barf = rs + 1536000;          // BAR_INTS ints (~204 KB)

  _Float16* hA = (_Float16*)hsl;
  _Float16* hB = hA + 16000;
  int* bar  = (int*)barf;
  int* grp  = bar;                     // [96][16] counters, 32-int padded
  int* root = bar + 96 * NGRP * 32;    // [96] counters, 32-int padded

  k_init<<<63, 256, 0, stream>>>(bar, hA);
  k_spatial<<<63, 256, 0, stream>>>(x, sp_emb, sp_W1, sp_b1, sp_W2, sp_b2, X0);
  k_tgi<<<96, 256, 0, stream>>>(x, x_mark, t_emb, t_Wih, t_bih, tgi);
  k_tgru<<<1, 256, 0, stream>>>(tgi, t_Whh, t_bhh, X0);

  dim3 gg(66, 8);
  k_gnn<<<gg, 256, 0, stream>>>(X0, X0, X1, gcn_W + 0 * 1024, gcn_b + 0 * 32);
  k_gnn<<<gg, 256, 0, stream>>>(X0, X1, X2, gcn_W + 1 * 1024, gcn_b + 1 * 32);
  k_gnn<<<gg, 256, 0, stream>>>(X2, X2, X0, gcn_W + 2 * 1024, gcn_b + 2 * 32);
  k_gnn<<<gg, 256, 0, stream>>>(X2, X0, X1, gcn_W + 3 * 1024, gcn_b + 3 * 32);

  k_rs<<<dim3(63, 8), 256, 0, stream>>>(X1, fr_W1, fr_b1, fr_W2, fr_b2, rs);
  k_trgi<<<dim3(16, 8), 256, 0, stream>>>(X1, tr_Wih, tr_bih, trgi);

  {
    const float* a0 = trgi;
    const float* a1 = tr_Whh;
    const float* a2 = tr_bhh;
    _Float16* a3 = hA;
    _Float16* a4 = hB;
    float* a5 = rt;
    int* a6 = grp;
    int* a7 = root;
    void* cargs[] = {&a0, &a1, &a2, &a3, &a4, &a5, &a6, &a7};
    hipLaunchCooperativeKernel((const void*)k_trgru, dim3(NBLK), dim3(1024), cargs, 0, stream);
  }

  k_final<<<63, 256, 0, stream>>>(rs, rt, out_W, out_b, (float*)d_out);
}

// Round 5
// 1812.817 us; speedup vs baseline: 1.9322x; 1.8486x over previous
//
#include <hip/hip_runtime.h>

typedef _Float16 h4 __attribute__((ext_vector_type(4)));
typedef _Float16 half8 __attribute__((ext_vector_type(8)));
typedef float f32x4 __attribute__((ext_vector_type(4)));

#define NBLK 250
#define NGRP 16
#define BAR_INTS (96 * NGRP * 32 + 96 * 32)

// ---------------- Kernel 1: spatial MLP -> X[:, 0:2000, :] ----------------
__global__ __launch_bounds__(256) void k_spatial(
    const float* __restrict__ x, const float* __restrict__ sp_emb,
    const float* __restrict__ W1, const float* __restrict__ b1,
    const float* __restrict__ W2, const float* __restrict__ b2,
    float* __restrict__ X) {
  __shared__ float W1s[128 * 32];
  __shared__ float W2s[32 * 32];
  __shared__ float b1s[32], b2s[32];
  int tid = threadIdx.x;
  for (int i = tid; i < 128 * 32; i += 256) W1s[i] = W1[i];
  for (int i = tid; i < 32 * 32; i += 256) W2s[i] = W2[i];
  if (tid < 32) { b1s[tid] = b1[tid]; b2s[tid] = b2[tid]; }
  __syncthreads();
  int gidx = blockIdx.x * 256 + tid;
  if (gidx >= 8 * 2000) return;
  int b = gidx / 2000, n = gidx % 2000;
  float h1[32];
#pragma unroll
  for (int l = 0; l < 32; l++) h1[l] = b1s[l];
  for (int k = 0; k < 96; k++) {
    float xv = x[((size_t)b * 96 + k) * 2000 + n];
#pragma unroll
    for (int l = 0; l < 32; l++) h1[l] = fmaf(xv, W1s[k * 32 + l], h1[l]);
  }
  for (int e4 = 0; e4 < 8; e4++) {
    float4 ev = *reinterpret_cast<const float4*>(&sp_emb[(size_t)n * 32 + e4 * 4]);
    float evs[4] = {ev.x, ev.y, ev.z, ev.w};
#pragma unroll
    for (int q = 0; q < 4; q++) {
      int e = e4 * 4 + q;
#pragma unroll
      for (int l = 0; l < 32; l++) h1[l] = fmaf(evs[q], W1s[(96 + e) * 32 + l], h1[l]);
    }
  }
  float out[32];
#pragma unroll
  for (int j = 0; j < 32; j++) out[j] = b2s[j];
  for (int l = 0; l < 32; l++) {
    float a = h1[l] > 0.0f ? h1[l] : (__expf(h1[l]) - 1.0f);
#pragma unroll
    for (int j = 0; j < 32; j++) out[j] = fmaf(a, W2s[l * 32 + j], out[j]);
  }
  float* dst = X + ((size_t)b * 2096 + n) * 32;
#pragma unroll
  for (int j = 0; j < 32; j++) dst[j] = out[j];
}

// ---------------- Kernel 2: temporal GRU input gates precompute ----------------
__global__ __launch_bounds__(256) void k_tgi(
    const float* __restrict__ x, const float* __restrict__ x_mark,
    const float* __restrict__ t_emb, const float* __restrict__ Wih,
    const float* __restrict__ bih, float* __restrict__ gi) {
  __shared__ float xs[8][2036];
  int tid = threadIdx.x;
  int row0 = blockIdx.x * 8;
  for (int rr = 0; rr < 8; rr++) {
    int row = row0 + rr;
    int b = row / 96, t = row % 96;
    for (int k = tid; k < 2036; k += 256) {
      float v;
      if (k < 2000) v = x[((size_t)b * 96 + t) * 2000 + k];
      else if (k < 2004) v = x_mark[((size_t)b * 96 + t) * 4 + (k - 2000)];
      else v = t_emb[(size_t)t * 32 + (k - 2004)];
      xs[rr][k] = v;
    }
  }
  __syncthreads();
  for (int oi = tid; oi < 8 * 96; oi += 256) {
    int rr = oi / 96, g = oi % 96;
    const float* w = Wih + (size_t)g * 2036;
    float acc = bih[g];
    for (int k = 0; k < 2036; k += 4) {
      float4 wv = *reinterpret_cast<const float4*>(w + k);
      acc = fmaf(xs[rr][k + 0], wv.x, acc);
      acc = fmaf(xs[rr][k + 1], wv.y, acc);
      acc = fmaf(xs[rr][k + 2], wv.z, acc);
      acc = fmaf(xs[rr][k + 3], wv.w, acc);
    }
    gi[(size_t)(row0 + rr) * 96 + g] = acc;
  }
}

// ---------------- Kernel 3: temporal GRU scan (hidden=32) ----------------
__global__ __launch_bounds__(256) void k_tgru(
    const float* __restrict__ gi, const float* __restrict__ Whh,
    const float* __restrict__ bhh, float* __restrict__ X) {
  __shared__ float Whs[96][33];
  __shared__ float hs[8][33];
  int tid = threadIdx.x;
  for (int i = tid; i < 96 * 32; i += 256) Whs[i / 32][i % 32] = Whh[i];
  int b = tid >> 5, j = tid & 31;
  hs[b][j] = 0.0f;
  __syncthreads();
  for (int t = 0; t < 96; t++) {
    float gr = bhh[j], gz = bhh[32 + j], gn = bhh[64 + j];
#pragma unroll 8
    for (int k = 0; k < 32; k++) {
      float hv = hs[b][k];
      gr = fmaf(hv, Whs[j][k], gr);
      gz = fmaf(hv, Whs[32 + j][k], gz);
      gn = fmaf(hv, Whs[64 + j][k], gn);
    }
    const float* g = gi + ((size_t)b * 96 + t) * 96;
    float ir = g[j], iz = g[32 + j], inn = g[64 + j];
    float r = 1.0f / (1.0f + __expf(-(ir + gr)));
    float z = 1.0f / (1.0f + __expf(-(iz + gz)));
    float n = tanhf(inn + r * gn);
    float hn = (1.0f - z) * n + z * hs[b][j];
    __syncthreads();
    hs[b][j] = hn;
    X[((size_t)b * 2096 + 2000 + t) * 32 + j] = hn;
    __syncthreads();
  }
}

// ---------------- Kernel 4: fused GNN pass ----------------
__global__ __launch_bounds__(256) void k_gnn(
    const float* __restrict__ Xa, const float* __restrict__ Xin,
    float* __restrict__ Xout, const float* __restrict__ W,
    const float* __restrict__ bias) {
  __shared__ float XaR[32][36];
  __shared__ float Xm[64][36];
  __shared__ float Xi[64][36];
  __shared__ float At[32][68];
  __shared__ float Ws[32][36];
  __shared__ float bs[32];
  int tid = threadIdx.x;
  int b = blockIdx.y;
  int r0 = blockIdx.x * 32;
  const float* Xab = Xa + (size_t)b * 2096 * 32;
  const float* Xib = Xin + (size_t)b * 2096 * 32;
  for (int i = tid; i < 32 * 32; i += 256) {
    int r = i >> 5, k = i & 31;
    XaR[r][k] = (r0 + r < 2096) ? Xab[(size_t)(r0 + r) * 32 + k] : 0.0f;
    Ws[r][k] = W[i];
  }
  if (tid < 32) bs[tid] = bias[tid];
  float acc[4] = {0.f, 0.f, 0.f, 0.f};
  int sm = tid & 63, rq = tid >> 6;
  int ar = tid & 31, fg = tid >> 5;
  for (int mt = 0; mt < 33; mt++) {
    int m0 = mt * 64;
    __syncthreads();
    for (int i = tid; i < 64 * 32; i += 256) {
      int m = i >> 5, k = i & 31;
      int gm = m0 + m;
      bool ok = gm < 2096;
      Xm[m][k] = ok ? Xab[(size_t)gm * 32 + k] : 0.0f;
      Xi[m][k] = ok ? Xib[(size_t)gm * 32 + k] : 0.0f;
    }
    __syncthreads();
    float xm[32];
#pragma unroll
    for (int k4 = 0; k4 < 8; k4++) {
      float4 v = *reinterpret_cast<const float4*>(&Xm[sm][k4 * 4]);
      xm[k4 * 4 + 0] = v.x; xm[k4 * 4 + 1] = v.y;
      xm[k4 * 4 + 2] = v.z; xm[k4 * 4 + 3] = v.w;
    }
#pragma unroll
    for (int i = 0; i < 8; i++) {
      int r = rq * 8 + i;
      float s = 0.0f;
#pragma unroll
      for (int k4 = 0; k4 < 8; k4++) {
        float4 xa = *reinterpret_cast<const float4*>(&XaR[r][k4 * 4]);
        s = fmaf(xa.x, xm[k4 * 4 + 0], s);
        s = fmaf(xa.y, xm[k4 * 4 + 1], s);
        s = fmaf(xa.z, xm[k4 * 4 + 2], s);
        s = fmaf(xa.w, xm[k4 * 4 + 3], s);
      }
      float e = __expf(-2.0f * fmaxf(s, 0.0f));
      At[r][sm] = (1.0f - e) / (1.0f + e);
    }
    __syncthreads();
    int f0 = fg * 4;
#pragma unroll
    for (int m = 0; m < 64; m += 4) {
      float4 av = *reinterpret_cast<const float4*>(&At[ar][m]);
      float4 x0 = *reinterpret_cast<const float4*>(&Xi[m + 0][f0]);
      float4 x1 = *reinterpret_cast<const float4*>(&Xi[m + 1][f0]);
      float4 x2 = *reinterpret_cast<const float4*>(&Xi[m + 2][f0]);
      float4 x3 = *reinterpret_cast<const float4*>(&Xi[m + 3][f0]);
      acc[0] = fmaf(av.x, x0.x, acc[0]); acc[1] = fmaf(av.x, x0.y, acc[1]);
      acc[2] = fmaf(av.x, x0.z, acc[2]); acc[3] = fmaf(av.x, x0.w, acc[3]);
      acc[0] = fmaf(av.y, x1.x, acc[0]); acc[1] = fmaf(av.y, x1.y, acc[1]);
      acc[2] = fmaf(av.y, x1.z, acc[2]); acc[3] = fmaf(av.y, x1.w, acc[3]);
      acc[0] = fmaf(av.z, x2.x, acc[0]); acc[1] = fmaf(av.z, x2.y, acc[1]);
      acc[2] = fmaf(av.z, x2.z, acc[2]); acc[3] = fmaf(av.z, x2.w, acc[3]);
      acc[0] = fmaf(av.w, x3.x, acc[0]); acc[1] = fmaf(av.w, x3.y, acc[1]);
      acc[2] = fmaf(av.w, x3.z, acc[2]); acc[3] = fmaf(av.w, x3.w, acc[3]);
    }
  }
  __syncthreads();
  {
    int f0 = fg * 4;
    Xm[ar][f0 + 0] = acc[0]; Xm[ar][f0 + 1] = acc[1];
    Xm[ar][f0 + 2] = acc[2]; Xm[ar][f0 + 3] = acc[3];
  }
  __syncthreads();
  int f0 = fg * 4;
  float o[4];
#pragma unroll
  for (int j = 0; j < 4; j++) o[j] = bs[f0 + j];
#pragma unroll
  for (int k = 0; k < 32; k++) {
    float mv = Xm[ar][k];
    float4 wv = *reinterpret_cast<const float4*>(&Ws[k][f0]);
    o[0] = fmaf(mv, wv.x, o[0]);
    o[1] = fmaf(mv, wv.y, o[1]);
    o[2] = fmaf(mv, wv.z, o[2]);
    o[3] = fmaf(mv, wv.w, o[3]);
  }
  int grr = r0 + ar;
  if (grr < 2096) {
    float* dst = Xout + ((size_t)b * 2096 + grr) * 32 + f0;
#pragma unroll
    for (int j = 0; j < 4; j++) {
      float v = o[j];
      dst[j] = v > 0.0f ? v : (__expf(v) - 1.0f);
    }
  }
}

// ---------------- Kernel 5: spatial readout MLP rs ----------------
__global__ __launch_bounds__(256) void k_rs(
    const float* __restrict__ X, const float* __restrict__ W1,
    const float* __restrict__ b1, const float* __restrict__ W2,
    const float* __restrict__ b2, float* __restrict__ rs) {
  __shared__ float Xt[32][33];
  __shared__ float W2s[96][100];
  __shared__ float Hl[32][100];
  __shared__ float b1s[96], b2s[96];
  int tid = threadIdx.x;
  int b = blockIdx.y;
  int n0 = blockIdx.x * 32;
  for (int i = tid; i < 96 * 96; i += 256) W2s[i / 96][i % 96] = W2[i];
  if (tid < 96) { b1s[tid] = b1[tid]; b2s[tid] = b2[tid]; }
  for (int i = tid; i < 32 * 32; i += 256) {
    int r = i >> 5, k = i & 31;
    Xt[r][k] = (n0 + r < 2000) ? X[((size_t)b * 2096 + n0 + r) * 32 + k] : 0.0f;
  }
  __syncthreads();
  int r = tid & 31, cg = tid >> 5;
#pragma unroll
  for (int i = 0; i < 12; i++) {
    int c = cg * 12 + i;
    float a = b1s[c];
    for (int k = 0; k < 32; k++) a = fmaf(Xt[r][k], W1[k * 96 + c], a);
    Hl[r][c] = a > 0.0f ? a : (__expf(a) - 1.0f);
  }
  __syncthreads();
  float o[12];
#pragma unroll
  for (int i = 0; i < 12; i++) o[i] = b2s[cg * 12 + i];
  for (int k = 0; k < 96; k++) {
    float hv = Hl[r][k];
#pragma unroll
    for (int i = 0; i < 12; i++) o[i] = fmaf(hv, W2s[k][cg * 12 + i], o[i]);
  }
  if (n0 + r < 2000) {
    float* dst = rs + ((size_t)b * 2000 + n0 + r) * 96 + cg * 12;
#pragma unroll
    for (int i = 0; i < 12; i++) dst[i] = o[i];
  }
}

// ---------------- Kernel 6: tr-GRU input gates precompute ----------------
__global__ __launch_bounds__(256) void k_trgi(
    const float* __restrict__ X, const float* __restrict__ Wih,
    const float* __restrict__ bih, float* __restrict__ gi) {
  __shared__ float Xs[96][33];
  __shared__ float Wsh[384][33];
  int tid = threadIdx.x;
  int b = blockIdx.y;
  int g0 = blockIdx.x * 384;
  for (int i = tid; i < 96 * 32; i += 256) {
    int t = i >> 5, k = i & 31;
    Xs[t][k] = X[((size_t)b * 2096 + 2000 + t) * 32 + k];
  }
  for (int i = tid; i < 384 * 32; i += 256) {
    int g = i >> 5, k = i & 31;
    Wsh[g][k] = (g0 + g < 6000) ? Wih[(size_t)(g0 + g) * 32 + k] : 0.0f;
  }
  __syncthreads();
  for (int oi = tid; oi < 96 * 384; oi += 256) {
    int t = oi / 384, g = oi % 384;
    if (g0 + g >= 6000) continue;
    float a = bih[g0 + g];
#pragma unroll
    for (int k = 0; k < 32; k++) a = fmaf(Xs[t][k], Wsh[g][k], a);
    gi[((size_t)b * 96 + t) * 6000 + g0 + g] = a;
  }
}

// ---------------- Kernel 6b: init barrier counters + zero h ----------------
__global__ __launch_bounds__(256) void k_init(int* __restrict__ bar,
                                              _Float16* __restrict__ hA) {
  int i = blockIdx.x * 256 + threadIdx.x;
  for (int j = i; j < BAR_INTS; j += gridDim.x * 256) bar[j] = 0;
  if (i < 16000) hA[i] = (_Float16)0.0f;
}

// ---------------- Kernel 7: tr-GRU scan, persistent, MFMA + low-maintenance barrier ----------------
// Per block-step: C[24 rows][8 b] = W[24][2048] * h[2048][8] via 2 M-tiles x 64 K-chunks,
// K split across 16 waves, cross-wave reduce through LDS parts.
// Barrier design: h stores are agent-scope write-through (visible at coherence point,
// no L2 writeback needed); counter RMWs RELAXED (no cache maintenance); poll RELAXED
// (no per-iteration invalidate); exactly ONE acquire (invalidate) per block per step.
__global__ __launch_bounds__(1024) void k_trgru(
    const float* __restrict__ gi, const float* __restrict__ whh,
    const float* __restrict__ bhh, _Float16* __restrict__ hA,
    _Float16* __restrict__ hB, float* __restrict__ rt,
    int* __restrict__ grp, int* __restrict__ root) {
  __shared__ _Float16 wf0[32768];  // tile0 (rows 0-15): 64 chunks x 64 lanes x 8 f16
  __shared__ _Float16 wf1[16384];  // tile1 (rows 16-23): 64 chunks x 32 slots x 8 f16
  __shared__ _Float16 hf[16384];   // B-frags: 64 chunks x (4 kblk x 8 b) x 8 f16
  __shared__ float pt[4096];       // parts: [w 16][tile 2][lb 4][b 8][reg 4]
  int tid = threadIdx.x;
  int blk = blockIdx.x;
  int l = tid & 63, w = tid >> 6;

  // zero wf/hf (covers K-pad 2000..2047)
  {
    half8 z = {(_Float16)0, (_Float16)0, (_Float16)0, (_Float16)0,
               (_Float16)0, (_Float16)0, (_Float16)0, (_Float16)0};
    for (int i = tid; i < 8192; i += 1024) {
      if (i < 4096) ((half8*)wf0)[i] = z;
      else if (i < 6144) ((half8*)wf1)[i - 4096] = z;
      else ((half8*)hf)[i - 6144] = z;
    }
  }
  __syncthreads();
  // fill W fragments (one-time), f32 -> f16
  for (int i = tid; i < 6144; i += 1024) {
    if (i < 4096) {
      int c = i >> 6, ll = i & 63;
      int row = ll & 15, g = row >> 3, lj = row & 7;
      int kb = c * 32 + ((ll >> 4) << 3);
      if (kb <= 1992) {
        const float* src = whh + ((size_t)(g * 2000 + blk * 8 + lj)) * 2000 + kb;
        float4 v0 = *reinterpret_cast<const float4*>(src);
        float4 v1 = *reinterpret_cast<const float4*>(src + 4);
        half8 o = {(_Float16)v0.x, (_Float16)v0.y, (_Float16)v0.z, (_Float16)v0.w,
                   (_Float16)v1.x, (_Float16)v1.y, (_Float16)v1.z, (_Float16)v1.w};
        ((half8*)wf0)[i] = o;
      }
    } else {
      int idx = i - 4096;
      int c = idx >> 5, s = idx & 31;
      int lj = s & 7;
      int kb = c * 32 + ((s >> 3) << 3);
      if (kb <= 1992) {
        const float* src = whh + ((size_t)(2 * 2000 + blk * 8 + lj)) * 2000 + kb;
        float4 v0 = *reinterpret_cast<const float4*>(src);
        float4 v1 = *reinterpret_cast<const float4*>(src + 4);
        half8 o = {(_Float16)v0.x, (_Float16)v0.y, (_Float16)v0.z, (_Float16)v0.w,
                   (_Float16)v1.x, (_Float16)v1.y, (_Float16)v1.z, (_Float16)v1.w};
        ((half8*)wf1)[idx] = o;
      }
    }
  }

  // combine-thread state (tid < 64): (lj, cb)
  int lj = (tid >> 3) & 7, cb = tid & 7;
  int jg = blk * 8 + lj;
  float hold = 0.0f, bR = 0.f, bZ = 0.f, bN = 0.f;
  if (tid < 64) {
    bR = bhh[jg]; bZ = bhh[2000 + jg]; bN = bhh[4000 + jg];
  }
  int bslot = ((l >> 4) * 8 + (l & 7)) * 8;  // f16 offset within chunk (wf1 / hf)
  int mygrp = blk >> 4;                       // 16 groups: 15x16 + 1x10
  int gsz = (mygrp == 15) ? 10 : 16;
  __syncthreads();

  for (int t = 0; t < 96; t++) {
    const _Float16* hc = (t & 1) ? hB : hA;
    _Float16* hn = (t & 1) ? hA : hB;
    // prefetch gi for combine (overlaps staging + MFMA)
    float gir = 0.f, giz = 0.f, gin = 0.f;
    if (tid < 64) {
      const float* gp = gi + ((size_t)cb * 96 + t) * 6000;
      gir = gp[jg]; giz = gp[2000 + jg]; gin = gp[4000 + jg];
    }
    // stage h -> B fragments
    for (int i = tid; i < 2048; i += 1024) {
      int b = i & 7, k8 = i >> 3;
      if (k8 < 250) {
        half8 v = *reinterpret_cast<const half8*>(hc + b * 2000 + k8 * 8);
        *reinterpret_cast<half8*>(hf + ((k8 >> 2) * 256 + (k8 & 3) * 64 + b * 8)) = v;
      }
    }
    __syncthreads();
    // MFMA phase: wave w handles k-chunks 4w .. 4w+3
    f32x4 c0 = {0.f, 0.f, 0.f, 0.f}, c1 = {0.f, 0.f, 0.f, 0.f};
#pragma unroll
    for (int i = 0; i < 4; i++) {
      int c = w * 4 + i;
      half8 bv = *reinterpret_cast<const half8*>(hf + c * 256 + bslot);
      half8 a0 = *reinterpret_cast<const half8*>(wf0 + c * 512 + l * 8);
      half8 a1 = *reinterpret_cast<const half8*>(wf1 + c * 256 + bslot);
      c0 = __builtin_amdgcn_mfma_f32_16x16x32_f16(a0, bv, c0, 0, 0, 0);
      c1 = __builtin_amdgcn_mfma_f32_16x16x32_f16(a1, bv, c1, 0, 0, 0);
    }
    {
      int bcol = l & 15;
      if (bcol < 8) {
        int lb = l >> 4;
        *reinterpret_cast<f32x4*>(pt + w * 256 + ((0 * 4 + lb) * 8 + bcol) * 4) = c0;
        *reinterpret_cast<f32x4*>(pt + w * 256 + ((1 * 4 + lb) * 8 + bcol) * 4) = c1;
      }
    }
    __syncthreads();
    // combine (wave 0): reduce 16 wave-partials, GRU pointwise, write h / rt
    if (tid < 64) {
      float s[3];
#pragma unroll
      for (int g = 0; g < 3; g++) {
        int row = g * 8 + lj;
        int tile = row >> 4, rr = row & 15;
        int base = ((tile * 4 + (rr >> 2)) * 8 + cb) * 4 + (rr & 3);
        float acc = 0.f;
#pragma unroll
        for (int w2 = 0; w2 < 16; w2++) acc += pt[w2 * 256 + base];
        s[g] = acc;
      }
      float r_ = 1.0f / (1.0f + __expf(-(gir + s[0] + bR)));
      float z_ = 1.0f / (1.0f + __expf(-(giz + s[1] + bZ)));
      float n_ = tanhf(gin + r_ * (s[2] + bN));
      hold = (1.0f - z_) * n_ + z_ * hold;
      // write-through h store: visible at coherence point without L2 writeback
      {
        _Float16 hv16 = (_Float16)hold;
        unsigned short hbits;
        __builtin_memcpy(&hbits, &hv16, 2);
        __hip_atomic_store((unsigned short*)(hn + cb * 2000 + jg), hbits,
                           __ATOMIC_RELAXED, __HIP_MEMORY_SCOPE_AGENT);
      }
      rt[((size_t)cb * 96 + t) * 2000 + jg] = hold;  // consumed post-kernel only
    }
    // __syncthreads drains all waves' vmcnt -> h stores are at coherence point
    __syncthreads();
    // ---- tree barrier: relaxed RMWs, relaxed poll, single acquire at exit ----
    if (tid == 0) {
      int r = __hip_atomic_fetch_add(&grp[(t * NGRP + mygrp) * 32], 1,
                                     __ATOMIC_RELAXED, __HIP_MEMORY_SCOPE_AGENT);
      if (r == gsz - 1) {
        __hip_atomic_fetch_add(&root[t * 32], 1, __ATOMIC_RELAXED,
                               __HIP_MEMORY_SCOPE_AGENT);
      }
    }
    if (tid == 64) {
      while (__hip_atomic_load(&root[t * 32], __ATOMIC_RELAXED,
                               __HIP_MEMORY_SCOPE_AGENT) < NGRP) {
        __builtin_amdgcn_s_sleep(4);
      }
      // one acquire: invalidate stale cached h lines before next step's staging
      (void)__hip_atomic_load(&root[t * 32], __ATOMIC_ACQUIRE,
                              __HIP_MEMORY_SCOPE_AGENT);
    }
    __syncthreads();
  }
}

// ---------------- Kernel 8: final combine + out matmul ----------------
__global__ __launch_bounds__(256) void k_final(
    const float* __restrict__ rs, const float* __restrict__ rt,
    const float* __restrict__ outW, const float* __restrict__ outb,
    float* __restrict__ out) {
  __shared__ float w[96];
  __shared__ float ob;
  int tid = threadIdx.x;
  if (tid < 96) w[tid] = outW[tid];
  if (tid == 0) ob = outb[0];
  __syncthreads();
  int gidx = blockIdx.x * 256 + tid;
  if (gidx >= 16000) return;
  int b = gidx / 2000, n = gidx % 2000;
  const float* rsp = rs + (size_t)gidx * 96;
  float acc = ob;
  for (int t4 = 0; t4 < 24; t4++) {
    float4 rv = *reinterpret_cast<const float4*>(rsp + t4 * 4);
    int t = t4 * 4;
    acc = fmaf(rv.x + rt[((size_t)b * 96 + t + 0) * 2000 + n], w[t + 0], acc);
    acc = fmaf(rv.y + rt[((size_t)b * 96 + t + 1) * 2000 + n], w[t + 1], acc);
    acc = fmaf(rv.z + rt[((size_t)b * 96 + t + 2) * 2000 + n], w[t + 2], acc);
    acc = fmaf(rv.w + rt[((size_t)b * 96 + t + 3) * 2000 + n], w[t + 3], acc);
  }
  out[gidx] = acc;
}

extern "C" void kernel_launch(void* const* d_in, const int* in_sizes, int n_in,
                              void* d_out, int out_size, void* d_ws, size_t ws_size,
                              hipStream_t stream) {
  const float* x      = (const float*)d_in[0];
  const float* x_mark = (const float*)d_in[1];
  const float* sp_emb = (const float*)d_in[2];
  const float* sp_W1  = (const float*)d_in[3];
  const float* sp_b1  = (const float*)d_in[4];
  const float* sp_W2  = (const float*)d_in[5];
  const float* sp_b2  = (const float*)d_in[6];
  const float* t_emb  = (const float*)d_in[7];
  const float* t_Wih  = (const float*)d_in[8];
  const float* t_Whh  = (const float*)d_in[9];
  const float* t_bih  = (const float*)d_in[10];
  const float* t_bhh  = (const float*)d_in[11];
  const float* gcn_W  = (const float*)d_in[12];
  const float* gcn_b  = (const float*)d_in[13];
  const float* fr_W1  = (const float*)d_in[14];
  const float* fr_b1  = (const float*)d_in[15];
  const float* fr_W2  = (const float*)d_in[16];
  const float* fr_b2  = (const float*)d_in[17];
  const float* tr_Wih = (const float*)d_in[18];
  const float* tr_Whh = (const float*)d_in[19];
  const float* tr_bih = (const float*)d_in[20];
  const float* tr_bhh = (const float*)d_in[21];
  const float* out_W  = (const float*)d_in[22];
  const float* out_b  = (const float*)d_in[23];
  (void)in_sizes; (void)n_in; (void)out_size; (void)ws_size;

  float* ws = (float*)d_ws;
  float* X0   = ws;                    // 8*2096*32 = 536576
  float* X1   = X0 + 536576;
  float* X2   = X1 + 536576;
  float* tgi  = X2 + 536576;           // 768*96 = 73728
  float* trgi = tgi + 73728;           // 8*96*6000 = 4608000
  float* hsl  = trgi + 4608000;        // 16000 f32 slot -> hA/hB (f16, 16000 each)
  float* rt   = hsl + 16000;           // 8*96*2000 = 1536000
  float* rs   = rt + 1536000;          // 8*2000*96 = 1536000
  float* barf = rs + 1536000;          // BAR_INTS ints (~204 KB)

  _Float16* hA = (_Float16*)hsl;
  _Float16* hB = hA + 16000;
  int* bar  = (int*)barf;
  int* grp  = bar;                     // [96][16] counters, 32-int padded
  int* root = bar + 96 * NGRP * 32;    // [96] counters, 32-int padded

  k_init<<<63, 256, 0, stream>>>(bar, hA);
  k_spatial<<<63, 256, 0, stream>>>(x, sp_emb, sp_W1, sp_b1, sp_W2, sp_b2, X0);
  k_tgi<<<96, 256, 0, stream>>>(x, x_mark, t_emb, t_Wih, t_bih, tgi);
  k_tgru<<<1, 256, 0, stream>>>(tgi, t_Whh, t_bhh, X0);

  dim3 gg(66, 8);
  k_gnn<<<gg, 256, 0, stream>>>(X0, X0, X1, gcn_W + 0 * 1024, gcn_b + 0 * 32);
  k_gnn<<<gg, 256, 0, stream>>>(X0, X1, X2, gcn_W + 1 * 1024, gcn_b + 1 * 32);
  k_gnn<<<gg, 256, 0, stream>>>(X2, X2, X0, gcn_W + 2 * 1024, gcn_b + 2 * 32);
  k_gnn<<<gg, 256, 0, stream>>>(X2, X0, X1, gcn_W + 3 * 1024, gcn_b + 3 * 32);

  k_rs<<<dim3(63, 8), 256, 0, stream>>>(X1, fr_W1, fr_b1, fr_W2, fr_b2, rs);
  k_trgi<<<dim3(16, 8), 256, 0, stream>>>(X1, tr_Wih, tr_bih, trgi);

  {
    const float* a0 = trgi;
    const float* a1 = tr_Whh;
    const float* a2 = tr_bhh;
    _Float16* a3 = hA;
    _Float16* a4 = hB;
    float* a5 = rt;
    int* a6 = grp;
    int* a7 = root;
    void* cargs[] = {&a0, &a1, &a2, &a3, &a4, &a5, &a6, &a7};
    hipLaunchCooperativeKernel((const void*)k_trgru, dim3(NBLK), dim3(1024), cargs, 0, stream);
  }

  k_final<<<63, 256, 0, stream>>>(rs, rt, out_W, out_b, (float*)d_out);
}

// Round 6
// 1530.090 us; speedup vs baseline: 2.2893x; 1.1848x over previous
//
#include <hip/hip_runtime.h>

typedef _Float16 h4 __attribute__((ext_vector_type(4)));
typedef _Float16 half8 __attribute__((ext_vector_type(8)));
typedef float f32x4 __attribute__((ext_vector_type(4)));

#define NBLK 250
#define NGRP 16
#define BAR_INTS (96 * NGRP * 32 + 96 * 32)

// ---------------- Kernel 1: spatial MLP -> X[:, 0:2000, :] ----------------
__global__ __launch_bounds__(256) void k_spatial(
    const float* __restrict__ x, const float* __restrict__ sp_emb,
    const float* __restrict__ W1, const float* __restrict__ b1,
    const float* __restrict__ W2, const float* __restrict__ b2,
    float* __restrict__ X) {
  __shared__ float W1s[128 * 32];
  __shared__ float W2s[32 * 32];
  __shared__ float b1s[32], b2s[32];
  int tid = threadIdx.x;
  for (int i = tid; i < 128 * 32; i += 256) W1s[i] = W1[i];
  for (int i = tid; i < 32 * 32; i += 256) W2s[i] = W2[i];
  if (tid < 32) { b1s[tid] = b1[tid]; b2s[tid] = b2[tid]; }
  __syncthreads();
  int gidx = blockIdx.x * 256 + tid;
  if (gidx >= 8 * 2000) return;
  int b = gidx / 2000, n = gidx % 2000;
  float h1[32];
#pragma unroll
  for (int l = 0; l < 32; l++) h1[l] = b1s[l];
  for (int k = 0; k < 96; k++) {
    float xv = x[((size_t)b * 96 + k) * 2000 + n];
#pragma unroll
    for (int l = 0; l < 32; l++) h1[l] = fmaf(xv, W1s[k * 32 + l], h1[l]);
  }
  for (int e4 = 0; e4 < 8; e4++) {
    float4 ev = *reinterpret_cast<const float4*>(&sp_emb[(size_t)n * 32 + e4 * 4]);
    float evs[4] = {ev.x, ev.y, ev.z, ev.w};
#pragma unroll
    for (int q = 0; q < 4; q++) {
      int e = e4 * 4 + q;
#pragma unroll
      for (int l = 0; l < 32; l++) h1[l] = fmaf(evs[q], W1s[(96 + e) * 32 + l], h1[l]);
    }
  }
  float out[32];
#pragma unroll
  for (int j = 0; j < 32; j++) out[j] = b2s[j];
  for (int l = 0; l < 32; l++) {
    float a = h1[l] > 0.0f ? h1[l] : (__expf(h1[l]) - 1.0f);
#pragma unroll
    for (int j = 0; j < 32; j++) out[j] = fmaf(a, W2s[l * 32 + j], out[j]);
  }
  float* dst = X + ((size_t)b * 2096 + n) * 32;
#pragma unroll
  for (int j = 0; j < 32; j++) dst[j] = out[j];
}

// ---------------- Kernel 2: temporal GRU input gates precompute ----------------
__global__ __launch_bounds__(256) void k_tgi(
    const float* __restrict__ x, const float* __restrict__ x_mark,
    const float* __restrict__ t_emb, const float* __restrict__ Wih,
    const float* __restrict__ bih, float* __restrict__ gi) {
  __shared__ float xs[8][2036];
  int tid = threadIdx.x;
  int row0 = blockIdx.x * 8;
  for (int rr = 0; rr < 8; rr++) {
    int row = row0 + rr;
    int b = row / 96, t = row % 96;
    for (int k = tid; k < 2036; k += 256) {
      float v;
      if (k < 2000) v = x[((size_t)b * 96 + t) * 2000 + k];
      else if (k < 2004) v = x_mark[((size_t)b * 96 + t) * 4 + (k - 2000)];
      else v = t_emb[(size_t)t * 32 + (k - 2004)];
      xs[rr][k] = v;
    }
  }
  __syncthreads();
  for (int oi = tid; oi < 8 * 96; oi += 256) {
    int rr = oi / 96, g = oi % 96;
    const float* w = Wih + (size_t)g * 2036;
    float acc = bih[g];
    for (int k = 0; k < 2036; k += 4) {
      float4 wv = *reinterpret_cast<const float4*>(w + k);
      acc = fmaf(xs[rr][k + 0], wv.x, acc);
      acc = fmaf(xs[rr][k + 1], wv.y, acc);
      acc = fmaf(xs[rr][k + 2], wv.z, acc);
      acc = fmaf(xs[rr][k + 3], wv.w, acc);
    }
    gi[(size_t)(row0 + rr) * 96 + g] = acc;
  }
}

// ---------------- Kernel 3: temporal GRU scan (hidden=32) ----------------
__global__ __launch_bounds__(256) void k_tgru(
    const float* __restrict__ gi, const float* __restrict__ Whh,
    const float* __restrict__ bhh, float* __restrict__ X) {
  __shared__ float Whs[96][33];
  __shared__ float hs[8][33];
  int tid = threadIdx.x;
  for (int i = tid; i < 96 * 32; i += 256) Whs[i / 32][i % 32] = Whh[i];
  int b = tid >> 5, j = tid & 31;
  hs[b][j] = 0.0f;
  __syncthreads();
  for (int t = 0; t < 96; t++) {
    float gr = bhh[j], gz = bhh[32 + j], gn = bhh[64 + j];
#pragma unroll 8
    for (int k = 0; k < 32; k++) {
      float hv = hs[b][k];
      gr = fmaf(hv, Whs[j][k], gr);
      gz = fmaf(hv, Whs[32 + j][k], gz);
      gn = fmaf(hv, Whs[64 + j][k], gn);
    }
    const float* g = gi + ((size_t)b * 96 + t) * 96;
    float ir = g[j], iz = g[32 + j], inn = g[64 + j];
    float r = 1.0f / (1.0f + __expf(-(ir + gr)));
    float z = 1.0f / (1.0f + __expf(-(iz + gz)));
    float n = tanhf(inn + r * gn);
    float hn = (1.0f - z) * n + z * hs[b][j];
    __syncthreads();
    hs[b][j] = hn;
    X[((size_t)b * 2096 + 2000 + t) * 32 + j] = hn;
    __syncthreads();
  }
}

// ---------------- Kernel 4: fused GNN pass (MFMA) ----------------
// Xout = elu( (A @ Xin) @ W + bias ), A = tanh(relu(Xa @ Xa^T)) recomputed per col-tile.
// Block: 32 output rows x batch. 33 col-tiles of 64. 4 waves:
//   S-phase: wave (smt=w>>1, snt2=w&1): S[16 rows][32 cols] = 2 MFMA (K=32 feats, one shot)
//   P-phase: wave (pmt=w>>1, pnt=w&1): P[16 rows][16 feats] accumulated over K=64 cols (2 MFMA)
__global__ __launch_bounds__(256) void k_gnn(
    const float* __restrict__ Xa, const float* __restrict__ Xin,
    float* __restrict__ Xout, const float* __restrict__ W,
    const float* __restrict__ bias) {
  __shared__ _Float16 XaR[32][40];    // A-op rows (frag-hoisted)
  __shared__ _Float16 Xm[2][64][40];  // S-phase B-op (dbuf)
  __shared__ _Float16 Xq[2][64][41];  // P-phase B-op, odd pad for b16 gathers (dbuf)
  __shared__ _Float16 At[32][72];     // activated A tile
  __shared__ float Pm[32][36];        // P epilogue staging
  __shared__ float Ws[32][36];
  __shared__ float bs[32];
  int tid = threadIdx.x;
  int l = tid & 63, w = tid >> 6;
  int b = blockIdx.y;
  int r0 = blockIdx.x * 32;
  const float* Xab = Xa + (size_t)b * 2096 * 32;
  const float* Xib = Xin + (size_t)b * 2096 * 32;

  // prologue: W, bias, XaR, tile0
  for (int i = tid; i < 1024; i += 256) {
    int r = i >> 5, k = i & 31;
    Ws[r][k] = W[i];
    XaR[r][k] = (_Float16)((r0 + r < 2096) ? Xab[(size_t)(r0 + r) * 32 + k] : 0.0f);
  }
  if (tid < 32) bs[tid] = bias[tid];
  for (int i = tid; i < 2048; i += 256) {
    int r = i >> 5, k = i & 31;
    bool ok = r < 2096;  // tile 0: gm = r
    Xm[0][r][k] = (_Float16)(ok ? Xab[(size_t)r * 32 + k] : 0.0f);
    Xq[0][r][k] = (_Float16)(ok ? Xib[(size_t)r * 32 + k] : 0.0f);
  }
  __syncthreads();

  int lr = l & 15, lk = (l >> 4) * 8, lq = (l >> 4) * 4;
  int smt = w >> 1, snt2 = w & 1;
  int pmt = w >> 1, pnt = w & 1;
  half8 afrag = *reinterpret_cast<const half8*>(&XaR[smt * 16 + lr][lk]);
  f32x4 pacc = {0.f, 0.f, 0.f, 0.f};

  for (int tt = 0; tt < 33; tt++) {
    int cur = tt & 1;
    // stage next tile into other buffer
    if (tt + 1 < 33) {
      int m0 = (tt + 1) * 64;
      int nb = cur ^ 1;
      for (int i = tid; i < 2048; i += 256) {
        int r = i >> 5, k = i & 31;
        int gm = m0 + r;
        bool ok = gm < 2096;
        Xm[nb][r][k] = (_Float16)(ok ? Xab[(size_t)gm * 32 + k] : 0.0f);
        Xq[nb][r][k] = (_Float16)(ok ? Xib[(size_t)gm * 32 + k] : 0.0f);
      }
    }
    // S-phase + activation -> At
#pragma unroll
    for (int n16 = 0; n16 < 2; n16++) {
      int c0 = snt2 * 32 + n16 * 16;
      half8 bfrag = *reinterpret_cast<const half8*>(&Xm[cur][c0 + lr][lk]);
      f32x4 s4 = __builtin_amdgcn_mfma_f32_16x16x32_f16(
          afrag, bfrag, (f32x4){0.f, 0.f, 0.f, 0.f}, 0, 0, 0);
#pragma unroll
      for (int j = 0; j < 4; j++) {
        float e = __expf(-2.0f * fmaxf(s4[j], 0.0f));
        float a = (1.0f - e) / (1.0f + e);
        At[smt * 16 + lq + j][c0 + lr] = (_Float16)a;
      }
    }
    __syncthreads();
    // P-phase: accumulate over this tile's 64 cols
#pragma unroll
    for (int kc = 0; kc < 2; kc++) {
      half8 af = *reinterpret_cast<const half8*>(&At[pmt * 16 + lr][kc * 32 + lk]);
      half8 bf;
      int kb = kc * 32 + lk;
      int nn = pnt * 16 + lr;
#pragma unroll
      for (int e = 0; e < 8; e++) bf[e] = Xq[cur][kb + e][nn];
      pacc = __builtin_amdgcn_mfma_f32_16x16x32_f16(af, bf, pacc, 0, 0, 0);
    }
    __syncthreads();
  }

  // epilogue: P -> LDS, then out = elu(P @ W + b)
#pragma unroll
  for (int j = 0; j < 4; j++) Pm[pmt * 16 + lq + j][pnt * 16 + lr] = pacc[j];
  __syncthreads();
  int r = tid & 31, fgr = tid >> 5;
  int f0 = fgr * 4;
  float o[4];
#pragma unroll
  for (int j = 0; j < 4; j++) o[j] = bs[f0 + j];
#pragma unroll
  for (int k = 0; k < 32; k++) {
    float mv = Pm[r][k];
    float4 wv = *reinterpret_cast<const float4*>(&Ws[k][f0]);
    o[0] = fmaf(mv, wv.x, o[0]);
    o[1] = fmaf(mv, wv.y, o[1]);
    o[2] = fmaf(mv, wv.z, o[2]);
    o[3] = fmaf(mv, wv.w, o[3]);
  }
  int grr = r0 + r;
  if (grr < 2096) {
    float* dst = Xout + ((size_t)b * 2096 + grr) * 32 + f0;
#pragma unroll
    for (int j = 0; j < 4; j++) {
      float v = o[j];
      dst[j] = v > 0.0f ? v : (__expf(v) - 1.0f);
    }
  }
}

// ---------------- Kernel 5: spatial readout MLP rs ----------------
__global__ __launch_bounds__(256) void k_rs(
    const float* __restrict__ X, const float* __restrict__ W1,
    const float* __restrict__ b1, const float* __restrict__ W2,
    const float* __restrict__ b2, float* __restrict__ rs) {
  __shared__ float Xt[32][33];
  __shared__ float W2s[96][100];
  __shared__ float Hl[32][100];
  __shared__ float b1s[96], b2s[96];
  int tid = threadIdx.x;
  int b = blockIdx.y;
  int n0 = blockIdx.x * 32;
  for (int i = tid; i < 96 * 96; i += 256) W2s[i / 96][i % 96] = W2[i];
  if (tid < 96) { b1s[tid] = b1[tid]; b2s[tid] = b2[tid]; }
  for (int i = tid; i < 32 * 32; i += 256) {
    int r = i >> 5, k = i & 31;
    Xt[r][k] = (n0 + r < 2000) ? X[((size_t)b * 2096 + n0 + r) * 32 + k] : 0.0f;
  }
  __syncthreads();
  int r = tid & 31, cg = tid >> 5;
#pragma unroll
  for (int i = 0; i < 12; i++) {
    int c = cg * 12 + i;
    float a = b1s[c];
    for (int k = 0; k < 32; k++) a = fmaf(Xt[r][k], W1[k * 96 + c], a);
    Hl[r][c] = a > 0.0f ? a : (__expf(a) - 1.0f);
  }
  __syncthreads();
  float o[12];
#pragma unroll
  for (int i = 0; i < 12; i++) o[i] = b2s[cg * 12 + i];
  for (int k = 0; k < 96; k++) {
    float hv = Hl[r][k];
#pragma unroll
    for (int i = 0; i < 12; i++) o[i] = fmaf(hv, W2s[k][cg * 12 + i], o[i]);
  }
  if (n0 + r < 2000) {
    float* dst = rs + ((size_t)b * 2000 + n0 + r) * 96 + cg * 12;
#pragma unroll
    for (int i = 0; i < 12; i++) dst[i] = o[i];
  }
}

// ---------------- Kernel 6: tr-GRU input gates precompute ----------------
__global__ __launch_bounds__(256) void k_trgi(
    const float* __restrict__ X, const float* __restrict__ Wih,
    const float* __restrict__ bih, float* __restrict__ gi) {
  __shared__ float Xs[96][33];
  __shared__ float Wsh[384][33];
  int tid = threadIdx.x;
  int b = blockIdx.y;
  int g0 = blockIdx.x * 384;
  for (int i = tid; i < 96 * 32; i += 256) {
    int t = i >> 5, k = i & 31;
    Xs[t][k] = X[((size_t)b * 2096 + 2000 + t) * 32 + k];
  }
  for (int i = tid; i < 384 * 32; i += 256) {
    int g = i >> 5, k = i & 31;
    Wsh[g][k] = (g0 + g < 6000) ? Wih[(size_t)(g0 + g) * 32 + k] : 0.0f;
  }
  __syncthreads();
  for (int oi = tid; oi < 96 * 384; oi += 256) {
    int t = oi / 384, g = oi % 384;
    if (g0 + g >= 6000) continue;
    float a = bih[g0 + g];
#pragma unroll
    for (int k = 0; k < 32; k++) a = fmaf(Xs[t][k], Wsh[g][k], a);
    gi[((size_t)b * 96 + t) * 6000 + g0 + g] = a;
  }
}

// ---------------- Kernel 6b: init barrier counters + zero h ----------------
__global__ __launch_bounds__(256) void k_init(int* __restrict__ bar,
                                              _Float16* __restrict__ hA) {
  int i = blockIdx.x * 256 + threadIdx.x;
  for (int j = i; j < BAR_INTS; j += gridDim.x * 256) bar[j] = 0;
  if (i < 16000) hA[i] = (_Float16)0.0f;
}

// ---------------- Kernel 7: tr-GRU scan, persistent, MFMA + low-maintenance barrier ----------------
__global__ __launch_bounds__(1024) void k_trgru(
    const float* __restrict__ gi, const float* __restrict__ whh,
    const float* __restrict__ bhh, _Float16* __restrict__ hA,
    _Float16* __restrict__ hB, float* __restrict__ rt,
    int* __restrict__ grp, int* __restrict__ root) {
  __shared__ _Float16 wf0[32768];  // tile0 (rows 0-15): 64 chunks x 64 lanes x 8 f16
  __shared__ _Float16 wf1[16384];  // tile1 (rows 16-23): 64 chunks x 32 slots x 8 f16
  __shared__ _Float16 hf[16384];   // B-frags: 64 chunks x (4 kblk x 8 b) x 8 f16
  __shared__ float pt[4096];       // parts: [w 16][tile 2][lb 4][b 8][reg 4]
  int tid = threadIdx.x;
  int blk = blockIdx.x;
  int l = tid & 63, w = tid >> 6;

  {
    half8 z = {(_Float16)0, (_Float16)0, (_Float16)0, (_Float16)0,
               (_Float16)0, (_Float16)0, (_Float16)0, (_Float16)0};
    for (int i = tid; i < 8192; i += 1024) {
      if (i < 4096) ((half8*)wf0)[i] = z;
      else if (i < 6144) ((half8*)wf1)[i - 4096] = z;
      else ((half8*)hf)[i - 6144] = z;
    }
  }
  __syncthreads();
  for (int i = tid; i < 6144; i += 1024) {
    if (i < 4096) {
      int c = i >> 6, ll = i & 63;
      int row = ll & 15, g = row >> 3, lj = row & 7;
      int kb = c * 32 + ((ll >> 4) << 3);
      if (kb <= 1992) {
        const float* src = whh + ((size_t)(g * 2000 + blk * 8 + lj)) * 2000 + kb;
        float4 v0 = *reinterpret_cast<const float4*>(src);
        float4 v1 = *reinterpret_cast<const float4*>(src + 4);
        half8 o = {(_Float16)v0.x, (_Float16)v0.y, (_Float16)v0.z, (_Float16)v0.w,
                   (_Float16)v1.x, (_Float16)v1.y, (_Float16)v1.z, (_Float16)v1.w};
        ((half8*)wf0)[i] = o;
      }
    } else {
      int idx = i - 4096;
      int c = idx >> 5, s = idx & 31;
      int lj = s & 7;
      int kb = c * 32 + ((s >> 3) << 3);
      if (kb <= 1992) {
        const float* src = whh + ((size_t)(2 * 2000 + blk * 8 + lj)) * 2000 + kb;
        float4 v0 = *reinterpret_cast<const float4*>(src);
        float4 v1 = *reinterpret_cast<const float4*>(src + 4);
        half8 o = {(_Float16)v0.x, (_Float16)v0.y, (_Float16)v0.z, (_Float16)v0.w,
                   (_Float16)v1.x, (_Float16)v1.y, (_Float16)v1.z, (_Float16)v1.w};
        ((half8*)wf1)[idx] = o;
      }
    }
  }

  int lj = (tid >> 3) & 7, cb = tid & 7;
  int jg = blk * 8 + lj;
  float hold = 0.0f, bR = 0.f, bZ = 0.f, bN = 0.f;
  if (tid < 64) {
    bR = bhh[jg]; bZ = bhh[2000 + jg]; bN = bhh[4000 + jg];
  }
  int bslot = ((l >> 4) * 8 + (l & 7)) * 8;
  int mygrp = blk >> 4;
  int gsz = (mygrp == 15) ? 10 : 16;
  __syncthreads();

  for (int t = 0; t < 96; t++) {
    const _Float16* hc = (t & 1) ? hB : hA;
    _Float16* hn = (t & 1) ? hA : hB;
    float gir = 0.f, giz = 0.f, gin = 0.f;
    if (tid < 64) {
      const float* gp = gi + ((size_t)cb * 96 + t) * 6000;
      gir = gp[jg]; giz = gp[2000 + jg]; gin = gp[4000 + jg];
    }
    for (int i = tid; i < 2048; i += 1024) {
      int b = i & 7, k8 = i >> 3;
      if (k8 < 250) {
        half8 v = *reinterpret_cast<const half8*>(hc + b * 2000 + k8 * 8);
        *reinterpret_cast<half8*>(hf + ((k8 >> 2) * 256 + (k8 & 3) * 64 + b * 8)) = v;
      }
    }
    __syncthreads();
    f32x4 c0 = {0.f, 0.f, 0.f, 0.f}, c1 = {0.f, 0.f, 0.f, 0.f};
#pragma unroll
    for (int i = 0; i < 4; i++) {
      int c = w * 4 + i;
      half8 bv = *reinterpret_cast<const half8*>(hf + c * 256 + bslot);
      half8 a0 = *reinterpret_cast<const half8*>(wf0 + c * 512 + l * 8);
      half8 a1 = *reinterpret_cast<const half8*>(wf1 + c * 256 + bslot);
      c0 = __builtin_amdgcn_mfma_f32_16x16x32_f16(a0, bv, c0, 0, 0, 0);
      c1 = __builtin_amdgcn_mfma_f32_16x16x32_f16(a1, bv, c1, 0, 0, 0);
    }
    {
      int bcol = l & 15;
      if (bcol < 8) {
        int lb = l >> 4;
        *reinterpret_cast<f32x4*>(pt + w * 256 + ((0 * 4 + lb) * 8 + bcol) * 4) = c0;
        *reinterpret_cast<f32x4*>(pt + w * 256 + ((1 * 4 + lb) * 8 + bcol) * 4) = c1;
      }
    }
    __syncthreads();
    if (tid < 64) {
      float s[3];
#pragma unroll
      for (int g = 0; g < 3; g++) {
        int row = g * 8 + lj;
        int tile = row >> 4, rr = row & 15;
        int base = ((tile * 4 + (rr >> 2)) * 8 + cb) * 4 + (rr & 3);
        float acc = 0.f;
#pragma unroll
        for (int w2 = 0; w2 < 16; w2++) acc += pt[w2 * 256 + base];
        s[g] = acc;
      }
      float r_ = 1.0f / (1.0f + __expf(-(gir + s[0] + bR)));
      float z_ = 1.0f / (1.0f + __expf(-(giz + s[1] + bZ)));
      float n_ = tanhf(gin + r_ * (s[2] + bN));
      hold = (1.0f - z_) * n_ + z_ * hold;
      {
        _Float16 hv16 = (_Float16)hold;
        unsigned short hbits;
        __builtin_memcpy(&hbits, &hv16, 2);
        __hip_atomic_store((unsigned short*)(hn + cb * 2000 + jg), hbits,
                           __ATOMIC_RELAXED, __HIP_MEMORY_SCOPE_AGENT);
      }
      rt[((size_t)cb * 96 + t) * 2000 + jg] = hold;
    }
    __syncthreads();
    if (tid == 0) {
      int r = __hip_atomic_fetch_add(&grp[(t * NGRP + mygrp) * 32], 1,
                                     __ATOMIC_RELAXED, __HIP_MEMORY_SCOPE_AGENT);
      if (r == gsz - 1) {
        __hip_atomic_fetch_add(&root[t * 32], 1, __ATOMIC_RELAXED,
                               __HIP_MEMORY_SCOPE_AGENT);
      }
    }
    if (tid == 64) {
      while (__hip_atomic_load(&root[t * 32], __ATOMIC_RELAXED,
                               __HIP_MEMORY_SCOPE_AGENT) < NGRP) {
        __builtin_amdgcn_s_sleep(4);
      }
      (void)__hip_atomic_load(&root[t * 32], __ATOMIC_ACQUIRE,
                              __HIP_MEMORY_SCOPE_AGENT);
    }
    __syncthreads();
  }
}

// ---------------- Kernel 8: final combine + out matmul ----------------
__global__ __launch_bounds__(256) void k_final(
    const float* __restrict__ rs, const float* __restrict__ rt,
    const float* __restrict__ outW, const float* __restrict__ outb,
    float* __restrict__ out) {
  __shared__ float w[96];
  __shared__ float ob;
  int tid = threadIdx.x;
  if (tid < 96) w[tid] = outW[tid];
  if (tid == 0) ob = outb[0];
  __syncthreads();
  int gidx = blockIdx.x * 256 + tid;
  if (gidx >= 16000) return;
  int b = gidx / 2000, n = gidx % 2000;
  const float* rsp = rs + (size_t)gidx * 96;
  float acc = ob;
  for (int t4 = 0; t4 < 24; t4++) {
    float4 rv = *reinterpret_cast<const float4*>(rsp + t4 * 4);
    int t = t4 * 4;
    acc = fmaf(rv.x + rt[((size_t)b * 96 + t + 0) * 2000 + n], w[t + 0], acc);
    acc = fmaf(rv.y + rt[((size_t)b * 96 + t + 1) * 2000 + n], w[t + 1], acc);
    acc = fmaf(rv.z + rt[((size_t)b * 96 + t + 2) * 2000 + n], w[t + 2], acc);
    acc = fmaf(rv.w + rt[((size_t)b * 96 + t + 3) * 2000 + n], w[t + 3], acc);
  }
  out[gidx] = acc;
}

extern "C" void kernel_launch(void* const* d_in, const int* in_sizes, int n_in,
                              void* d_out, int out_size, void* d_ws, size_t ws_size,
                              hipStream_t stream) {
  const float* x      = (const float*)d_in[0];
  const float* x_mark = (const float*)d_in[1];
  const float* sp_emb = (const float*)d_in[2];
  const float* sp_W1  = (const float*)d_in[3];
  const float* sp_b1  = (const float*)d_in[4];
  const float* sp_W2  = (const float*)d_in[5];
  const float* sp_b2  = (const float*)d_in[6];
  const float* t_emb  = (const float*)d_in[7];
  const float* t_Wih  = (const float*)d_in[8];
  const float* t_Whh  = (const float*)d_in[9];
  const float* t_bih  = (const float*)d_in[10];
  const float* t_bhh  = (const float*)d_in[11];
  const float* gcn_W  = (const float*)d_in[12];
  const float* gcn_b  = (const float*)d_in[13];
  const float* fr_W1  = (const float*)d_in[14];
  const float* fr_b1  = (const float*)d_in[15];
  const float* fr_W2  = (const float*)d_in[16];
  const float* fr_b2  = (const float*)d_in[17];
  const float* tr_Wih = (const float*)d_in[18];
  const float* tr_Whh = (const float*)d_in[19];
  const float* tr_bih = (const float*)d_in[20];
  const float* tr_bhh = (const float*)d_in[21];
  const float* out_W  = (const float*)d_in[22];
  const float* out_b  = (const float*)d_in[23];
  (void)in_sizes; (void)n_in; (void)out_size; (void)ws_size;

  float* ws = (float*)d_ws;
  float* X0   = ws;                    // 8*2096*32 = 536576
  float* X1   = X0 + 536576;
  float* X2   = X1 + 536576;
  float* tgi  = X2 + 536576;           // 768*96 = 73728
  float* trgi = tgi + 73728;           // 8*96*6000 = 4608000
  float* hsl  = trgi + 4608000;        // 16000 f32 slot -> hA/hB (f16, 16000 each)
  float* rt   = hsl + 16000;           // 8*96*2000 = 1536000
  float* rs   = rt + 1536000;          // 8*2000*96 = 1536000
  float* barf = rs + 1536000;          // BAR_INTS ints (~204 KB)

  _Float16* hA = (_Float16*)hsl;
  _Float16* hB = hA + 16000;
  int* bar  = (int*)barf;
  int* grp  = bar;
  int* root = bar + 96 * NGRP * 32;

  k_init<<<63, 256, 0, stream>>>(bar, hA);
  k_spatial<<<63, 256, 0, stream>>>(x, sp_emb, sp_W1, sp_b1, sp_W2, sp_b2, X0);
  k_tgi<<<96, 256, 0, stream>>>(x, x_mark, t_emb, t_Wih, t_bih, tgi);
  k_tgru<<<1, 256, 0, stream>>>(tgi, t_Whh, t_bhh, X0);

  dim3 gg(66, 8);
  k_gnn<<<gg, 256, 0, stream>>>(X0, X0, X1, gcn_W + 0 * 1024, gcn_b + 0 * 32);
  k_gnn<<<gg, 256, 0, stream>>>(X0, X1, X2, gcn_W + 1 * 1024, gcn_b + 1 * 32);
  k_gnn<<<gg, 256, 0, stream>>>(X2, X2, X0, gcn_W + 2 * 1024, gcn_b + 2 * 32);
  k_gnn<<<gg, 256, 0, stream>>>(X2, X0, X1, gcn_W + 3 * 1024, gcn_b + 3 * 32);

  k_rs<<<dim3(63, 8), 256, 0, stream>>>(X1, fr_W1, fr_b1, fr_W2, fr_b2, rs);
  k_trgi<<<dim3(16, 8), 256, 0, stream>>>(X1, tr_Wih, tr_bih, trgi);

  {
    const float* a0 = trgi;
    const float* a1 = tr_Whh;
    const float* a2 = tr_bhh;
    _Float16* a3 = hA;
    _Float16* a4 = hB;
    float* a5 = rt;
    int* a6 = grp;
    int* a7 = root;
    void* cargs[] = {&a0, &a1, &a2, &a3, &a4, &a5, &a6, &a7};
    hipLaunchCooperativeKernel((const void*)k_trgru, dim3(NBLK), dim3(1024), cargs, 0, stream);
  }

  k_final<<<63, 256, 0, stream>>>(rs, rt, out_W, out_b, (float*)d_out);
}

// Round 7
// 1479.810 us; speedup vs baseline: 2.3671x; 1.0340x over previous
//
#include <hip/hip_runtime.h>

typedef _Float16 half8 __attribute__((ext_vector_type(8)));
typedef float f32x4 __attribute__((ext_vector_type(4)));

#define NBLK 125
#define NGRP 16
#define BAR_INTS (96 * NGRP * 32 + 96 * 32)

// ---------------- Kernel 1: spatial MLP -> X[:, 0:2000, :]  (+ fused init) ----------------
__global__ __launch_bounds__(256) void k_spatial(
    const float* __restrict__ x, const float* __restrict__ sp_emb,
    const float* __restrict__ W1, const float* __restrict__ b1,
    const float* __restrict__ W2, const float* __restrict__ b2,
    float* __restrict__ X, int* __restrict__ bar, unsigned char* __restrict__ hA) {
  __shared__ float W1s[128 * 32];
  __shared__ float W2s[32 * 32];
  __shared__ float b1s[32], b2s[32];
  int tid = threadIdx.x;
  int gidx = blockIdx.x * 256 + tid;
  // fused init: barrier counters + zero h0 (fp8)
  for (int i = gidx; i < BAR_INTS; i += 63 * 256) bar[i] = 0;
  for (int i = gidx; i < 4000; i += 63 * 256) ((unsigned int*)hA)[i] = 0u;
  for (int i = tid; i < 128 * 32; i += 256) W1s[i] = W1[i];
  for (int i = tid; i < 32 * 32; i += 256) W2s[i] = W2[i];
  if (tid < 32) { b1s[tid] = b1[tid]; b2s[tid] = b2[tid]; }
  __syncthreads();
  if (gidx >= 8 * 2000) return;
  int b = gidx / 2000, n = gidx % 2000;
  float h1[32];
#pragma unroll
  for (int l = 0; l < 32; l++) h1[l] = b1s[l];
  for (int k = 0; k < 96; k++) {
    float xv = x[((size_t)b * 96 + k) * 2000 + n];
#pragma unroll
    for (int l = 0; l < 32; l++) h1[l] = fmaf(xv, W1s[k * 32 + l], h1[l]);
  }
  for (int e4 = 0; e4 < 8; e4++) {
    float4 ev = *reinterpret_cast<const float4*>(&sp_emb[(size_t)n * 32 + e4 * 4]);
    float evs[4] = {ev.x, ev.y, ev.z, ev.w};
#pragma unroll
    for (int q = 0; q < 4; q++) {
      int e = e4 * 4 + q;
#pragma unroll
      for (int l = 0; l < 32; l++) h1[l] = fmaf(evs[q], W1s[(96 + e) * 32 + l], h1[l]);
    }
  }
  float out[32];
#pragma unroll
  for (int j = 0; j < 32; j++) out[j] = b2s[j];
  for (int l = 0; l < 32; l++) {
    float a = h1[l] > 0.0f ? h1[l] : (__expf(h1[l]) - 1.0f);
#pragma unroll
    for (int j = 0; j < 32; j++) out[j] = fmaf(a, W2s[l * 32 + j], out[j]);
  }
  float* dst = X + ((size_t)b * 2096 + n) * 32;
#pragma unroll
  for (int j = 0; j < 32; j++) dst[j] = out[j];
}

// ---------------- Kernel 2: temporal GRU input gates precompute ----------------
// g-mapping: 8 lanes share a Wih row -> broadcast-coalesced weight reads.
__global__ __launch_bounds__(256) void k_tgi(
    const float* __restrict__ x, const float* __restrict__ x_mark,
    const float* __restrict__ t_emb, const float* __restrict__ Wih,
    const float* __restrict__ bih, float* __restrict__ gi) {
  __shared__ float xs[8][2036];
  int tid = threadIdx.x;
  int row0 = blockIdx.x * 8;
  for (int rr = 0; rr < 8; rr++) {
    int row = row0 + rr;
    int b = row / 96, t = row % 96;
    for (int k = tid; k < 2036; k += 256) {
      float v;
      if (k < 2000) v = x[((size_t)b * 96 + t) * 2000 + k];
      else if (k < 2004) v = x_mark[((size_t)b * 96 + t) * 4 + (k - 2000)];
      else v = t_emb[(size_t)t * 32 + (k - 2004)];
      xs[rr][k] = v;
    }
  }
  __syncthreads();
  for (int oi = tid; oi < 8 * 96; oi += 256) {
    int rr = oi & 7, g = oi >> 3;
    const float* w = Wih + (size_t)g * 2036;
    float acc = bih[g];
    for (int k = 0; k < 2036; k += 4) {
      float4 wv = *reinterpret_cast<const float4*>(w + k);
      acc = fmaf(xs[rr][k + 0], wv.x, acc);
      acc = fmaf(xs[rr][k + 1], wv.y, acc);
      acc = fmaf(xs[rr][k + 2], wv.z, acc);
      acc = fmaf(xs[rr][k + 3], wv.w, acc);
    }
    gi[(size_t)(row0 + rr) * 96 + g] = acc;
  }
}

// ---------------- Kernel 3: temporal GRU scan (hidden=32), 768 threads ----------------
__global__ __launch_bounds__(768) void k_tgru(
    const float* __restrict__ gi, const float* __restrict__ Whh,
    const float* __restrict__ bhh, float* __restrict__ X) {
  __shared__ float Whs[96][33];
  __shared__ float hs[8][33];
  __shared__ float ga[3][8][33];
  int tid = threadIdx.x;
  for (int i = tid; i < 96 * 32; i += 768) Whs[i >> 5][i & 31] = Whh[i];
  if (tid < 256) hs[tid >> 5][tid & 31] = 0.0f;
  int g = tid >> 8, j = (tid >> 3) & 31, b = tid & 7;
  int row = g * 32 + j;
  float bb0 = 0.f, bb1 = 0.f, bb2 = 0.f;
  if (tid < 256) {
    int jj = tid & 31;
    bb0 = bhh[jj]; bb1 = bhh[32 + jj]; bb2 = bhh[64 + jj];
  }
  __syncthreads();
  for (int t = 0; t < 96; t++) {
    float acc = 0.0f;
#pragma unroll
    for (int k = 0; k < 32; k++) acc = fmaf(hs[b][k], Whs[row][k], acc);
    ga[g][b][j] = acc;
    __syncthreads();
    if (tid < 256) {
      int bb = tid >> 5, jj = tid & 31;
      const float* gp = gi + ((size_t)bb * 96 + t) * 96;
      float gr = ga[0][bb][jj] + bb0;
      float gz = ga[1][bb][jj] + bb1;
      float gn = ga[2][bb][jj] + bb2;
      float r = 1.0f / (1.0f + __expf(-(gp[jj] + gr)));
      float z = 1.0f / (1.0f + __expf(-(gp[32 + jj] + gz)));
      float n = tanhf(gp[64 + jj] + r * gn);
      float hn = (1.0f - z) * n + z * hs[bb][jj];
      hs[bb][jj] = hn;
      X[((size_t)bb * 2096 + 2000 + t) * 32 + jj] = hn;
    }
    __syncthreads();
  }
}

// ---------------- Kernel 4: fused GNN pass (MFMA) ----------------
__global__ __launch_bounds__(256) void k_gnn(
    const float* __restrict__ Xa, const float* __restrict__ Xin,
    float* __restrict__ Xout, const float* __restrict__ W,
    const float* __restrict__ bias) {
  __shared__ _Float16 XaR[32][40];
  __shared__ _Float16 Xm[2][64][40];
  __shared__ _Float16 Xq[2][64][41];
  __shared__ _Float16 At[32][72];
  __shared__ float Pm[32][36];
  __shared__ float Ws[32][36];
  __shared__ float bs[32];
  int tid = threadIdx.x;
  int l = tid & 63, w = tid >> 6;
  int b = blockIdx.y;
  int r0 = blockIdx.x * 32;
  const float* Xab = Xa + (size_t)b * 2096 * 32;
  const float* Xib = Xin + (size_t)b * 2096 * 32;

  for (int i = tid; i < 1024; i += 256) {
    int r = i >> 5, k = i & 31;
    Ws[r][k] = W[i];
    XaR[r][k] = (_Float16)((r0 + r < 2096) ? Xab[(size_t)(r0 + r) * 32 + k] : 0.0f);
  }
  if (tid < 32) bs[tid] = bias[tid];
  for (int i = tid; i < 2048; i += 256) {
    int r = i >> 5, k = i & 31;
    bool ok = r < 2096;
    Xm[0][r][k] = (_Float16)(ok ? Xab[(size_t)r * 32 + k] : 0.0f);
    Xq[0][r][k] = (_Float16)(ok ? Xib[(size_t)r * 32 + k] : 0.0f);
  }
  __syncthreads();

  int lr = l & 15, lk = (l >> 4) * 8, lq = (l >> 4) * 4;
  int smt = w >> 1, snt2 = w & 1;
  int pmt = w >> 1, pnt = w & 1;
  half8 afrag = *reinterpret_cast<const half8*>(&XaR[smt * 16 + lr][lk]);
  f32x4 pacc = {0.f, 0.f, 0.f, 0.f};

  for (int tt = 0; tt < 33; tt++) {
    int cur = tt & 1;
    if (tt + 1 < 33) {
      int m0 = (tt + 1) * 64;
      int nb = cur ^ 1;
      for (int i = tid; i < 2048; i += 256) {
        int r = i >> 5, k = i & 31;
        int gm = m0 + r;
        bool ok = gm < 2096;
        Xm[nb][r][k] = (_Float16)(ok ? Xab[(size_t)gm * 32 + k] : 0.0f);
        Xq[nb][r][k] = (_Float16)(ok ? Xib[(size_t)gm * 32 + k] : 0.0f);
      }
    }
#pragma unroll
    for (int n16 = 0; n16 < 2; n16++) {
      int c0 = snt2 * 32 + n16 * 16;
      half8 bfrag = *reinterpret_cast<const half8*>(&Xm[cur][c0 + lr][lk]);
      f32x4 s4 = __builtin_amdgcn_mfma_f32_16x16x32_f16(
          afrag, bfrag, (f32x4){0.f, 0.f, 0.f, 0.f}, 0, 0, 0);
#pragma unroll
      for (int j = 0; j < 4; j++) {
        float e = __expf(-2.0f * fmaxf(s4[j], 0.0f));
        float a = (1.0f - e) / (1.0f + e);
        At[smt * 16 + lq + j][c0 + lr] = (_Float16)a;
      }
    }
    __syncthreads();
#pragma unroll
    for (int kc = 0; kc < 2; kc++) {
      half8 af = *reinterpret_cast<const half8*>(&At[pmt * 16 + lr][kc * 32 + lk]);
      half8 bf;
      int kb = kc * 32 + lk;
      int nn = pnt * 16 + lr;
#pragma unroll
      for (int e = 0; e < 8; e++) bf[e] = Xq[cur][kb + e][nn];
      pacc = __builtin_amdgcn_mfma_f32_16x16x32_f16(af, bf, pacc, 0, 0, 0);
    }
    __syncthreads();
  }

#pragma unroll
  for (int j = 0; j < 4; j++) Pm[pmt * 16 + lq + j][pnt * 16 + lr] = pacc[j];
  __syncthreads();
  int r = tid & 31, fgr = tid >> 5;
  int f0 = fgr * 4;
  float o[4];
#pragma unroll
  for (int j = 0; j < 4; j++) o[j] = bs[f0 + j];
#pragma unroll
  for (int k = 0; k < 32; k++) {
    float mv = Pm[r][k];
    float4 wv = *reinterpret_cast<const float4*>(&Ws[k][f0]);
    o[0] = fmaf(mv, wv.x, o[0]);
    o[1] = fmaf(mv, wv.y, o[1]);
    o[2] = fmaf(mv, wv.z, o[2]);
    o[3] = fmaf(mv, wv.w, o[3]);
  }
  int grr = r0 + r;
  if (grr < 2096) {
    float* dst = Xout + ((size_t)b * 2096 + grr) * 32 + f0;
#pragma unroll
    for (int j = 0; j < 4; j++) {
      float v = o[j];
      dst[j] = v > 0.0f ? v : (__expf(v) - 1.0f);
    }
  }
}

// ---------------- Kernel 5: spatial readout MLP rs ----------------
__global__ __launch_bounds__(256) void k_rs(
    const float* __restrict__ X, const float* __restrict__ W1,
    const float* __restrict__ b1, const float* __restrict__ W2,
    const float* __restrict__ b2, float* __restrict__ rs) {
  __shared__ float Xt[32][33];
  __shared__ float W2s[96][100];
  __shared__ float Hl[32][100];
  __shared__ float b1s[96], b2s[96];
  int tid = threadIdx.x;
  int b = blockIdx.y;
  int n0 = blockIdx.x * 32;
  for (int i = tid; i < 96 * 96; i += 256) W2s[i / 96][i % 96] = W2[i];
  if (tid < 96) { b1s[tid] = b1[tid]; b2s[tid] = b2[tid]; }
  for (int i = tid; i < 32 * 32; i += 256) {
    int r = i >> 5, k = i & 31;
    Xt[r][k] = (n0 + r < 2000) ? X[((size_t)b * 2096 + n0 + r) * 32 + k] : 0.0f;
  }
  __syncthreads();
  int r = tid & 31, cg = tid >> 5;
#pragma unroll
  for (int i = 0; i < 12; i++) {
    int c = cg * 12 + i;
    float a = b1s[c];
    for (int k = 0; k < 32; k++) a = fmaf(Xt[r][k], W1[k * 96 + c], a);
    Hl[r][c] = a > 0.0f ? a : (__expf(a) - 1.0f);
  }
  __syncthreads();
  float o[12];
#pragma unroll
  for (int i = 0; i < 12; i++) o[i] = b2s[cg * 12 + i];
  for (int k = 0; k < 96; k++) {
    float hv = Hl[r][k];
#pragma unroll
    for (int i = 0; i < 12; i++) o[i] = fmaf(hv, W2s[k][cg * 12 + i], o[i]);
  }
  if (n0 + r < 2000) {
    float* dst = rs + ((size_t)b * 2000 + n0 + r) * 96 + cg * 12;
#pragma unroll
    for (int i = 0; i < 12; i++) dst[i] = o[i];
  }
}

// ---------------- Kernel 6: tr-GRU input gates precompute ----------------
__global__ __launch_bounds__(256) void k_trgi(
    const float* __restrict__ X, const float* __restrict__ Wih,
    const float* __restrict__ bih, float* __restrict__ gi) {
  __shared__ float Xs[96][33];
  __shared__ float Wsh[384][33];
  int tid = threadIdx.x;
  int b = blockIdx.y;
  int g0 = blockIdx.x * 384;
  for (int i = tid; i < 96 * 32; i += 256) {
    int t = i >> 5, k = i & 31;
    Xs[t][k] = X[((size_t)b * 2096 + 2000 + t) * 32 + k];
  }
  for (int i = tid; i < 384 * 32; i += 256) {
    int g = i >> 5, k = i & 31;
    Wsh[g][k] = (g0 + g < 6000) ? Wih[(size_t)(g0 + g) * 32 + k] : 0.0f;
  }
  __syncthreads();
  for (int oi = tid; oi < 96 * 384; oi += 256) {
    int t = oi / 384, g = oi % 384;
    if (g0 + g >= 6000) continue;
    float a = bih[g0 + g];
#pragma unroll
    for (int k = 0; k < 32; k++) a = fmaf(Xs[t][k], Wsh[g][k], a);
    gi[((size_t)b * 96 + t) * 6000 + g0 + g] = a;
  }
}

// ---------------- Kernel 7: tr-GRU scan, persistent, FP8 MFMA, 125 blocks ----------------
// Per block-step: C[48 rows][8 b] = W[48][2048] * h[2048][8]; rows = gate*16 + j (j<16).
// 3 M-tiles (one per gate) x 64 K-chunks of 32; 16 waves x 4 chunks; LDS partial reduce.
// Weights fp8 e4m3 in LDS (96 KB); h broadcast as fp8 (16 KB/step); hold kept f32 in reg.
__global__ __launch_bounds__(1024) void k_trgru(
    const float* __restrict__ gi, const float* __restrict__ whh,
    const float* __restrict__ bhh, unsigned char* __restrict__ hA,
    unsigned char* __restrict__ hB, float* __restrict__ rt,
    int* __restrict__ grp, int* __restrict__ root) {
  __shared__ unsigned char wf[3 * 32768];  // [tile][chunk 64][lane 64][8B]
  __shared__ unsigned char hf[16384];      // [chunk 64][slot 32][8B]
  __shared__ float pt[6144];               // [wave 16][tile 3][lb 4][b 8][reg 4]
  int tid = threadIdx.x;
  int blk = blockIdx.x;
  int l = tid & 63, w = tid >> 6;

  // zero wf/hf (covers K-pad 2000..2047)
  for (int i = tid; i < (3 * 32768 + 16384) / 8; i += 1024)
    ((unsigned long long*)wf)[i] = 0ull;  // wf and hf are adjacent shared arrays? not guaranteed
  __syncthreads();
  for (int i = tid; i < 16384 / 8; i += 1024) ((unsigned long long*)hf)[i] = 0ull;
  __syncthreads();

  // one-time weight fill: f32 -> fp8 e4m3 fragments
  // slot idx: g (tile/gate), c (chunk), l2 (lane): row j=l2&15, k0=c*32+(l2>>4)*8
  for (int i = tid; i < 3 * 64 * 64; i += 1024) {
    int g = i >> 12;
    int c = (i >> 6) & 63;
    int l2 = i & 63;
    int j = l2 & 15;
    int k0 = c * 32 + ((l2 >> 4) << 3);
    if (k0 <= 1992) {
      const float* src = whh + ((size_t)(g * 2000 + blk * 16 + j)) * 2000 + k0;
      float4 v0 = *reinterpret_cast<const float4*>(src);
      float4 v1 = *reinterpret_cast<const float4*>(src + 4);
      unsigned int lo = __builtin_amdgcn_cvt_pk_fp8_f32(v0.x, v0.y, 0, false);
      lo = __builtin_amdgcn_cvt_pk_fp8_f32(v0.z, v0.w, lo, true);
      unsigned int hi = __builtin_amdgcn_cvt_pk_fp8_f32(v1.x, v1.y, 0, false);
      hi = __builtin_amdgcn_cvt_pk_fp8_f32(v1.z, v1.w, hi, true);
      unsigned long long q = ((unsigned long long)hi << 32) | (unsigned long long)lo;
      *reinterpret_cast<unsigned long long*>(wf + (size_t)g * 32768 + c * 512 + l2 * 8) = q;
    }
  }

  // combine-thread state (tid < 128): j = tid>>3 (0..15), b = tid&7
  int cj = tid >> 3, cb = tid & 7;
  int jg = blk * 16 + cj;
  float hold = 0.0f, bR = 0.f, bZ = 0.f, bN = 0.f;
  if (tid < 128) {
    bR = bhh[jg]; bZ = bhh[2000 + jg]; bN = bhh[4000 + jg];
  }
  int bslot = ((l >> 4) * 8 + (l & 7)) * 8;  // byte offset within chunk (hf)
  int mygrp = blk >> 3;                       // 16 groups: 15x8 + 1x5
  int gsz = (mygrp == 15) ? 5 : 8;
  __syncthreads();

  for (int t = 0; t < 96; t++) {
    const unsigned char* hc = (t & 1) ? hB : hA;
    unsigned char* hn = (t & 1) ? hA : hB;
    // prefetch gi for combine (overlaps staging + MFMA)
    float gir = 0.f, giz = 0.f, gin = 0.f;
    if (tid < 128) {
      const float* gp = gi + ((size_t)cb * 96 + t) * 6000;
      gir = gp[jg]; giz = gp[2000 + jg]; gin = gp[4000 + jg];
    }
    // stage h (fp8 bytes) -> B fragments
    for (int i = tid; i < 2048; i += 1024) {
      int c = i >> 5, s = i & 31;
      int b = s & 7;
      int k0 = c * 32 + ((s >> 3) << 3);
      if (k0 < 2000) {
        unsigned long long v =
            *reinterpret_cast<const unsigned long long*>(hc + b * 2000 + k0);
        *reinterpret_cast<unsigned long long*>(hf + c * 256 + s * 8) = v;
      }
    }
    __syncthreads();
    // MFMA: wave w handles chunks 4w..4w+3, 3 tiles each
    f32x4 a0 = {0.f, 0.f, 0.f, 0.f}, a1 = {0.f, 0.f, 0.f, 0.f}, a2 = {0.f, 0.f, 0.f, 0.f};
#pragma unroll
    for (int i = 0; i < 4; i++) {
      int c = w * 4 + i;
      long long bv = *reinterpret_cast<const long long*>(hf + c * 256 + bslot);
      long long w0 = *reinterpret_cast<const long long*>(wf + 0 * 32768 + c * 512 + l * 8);
      long long w1 = *reinterpret_cast<const long long*>(wf + 1 * 32768 + c * 512 + l * 8);
      long long w2 = *reinterpret_cast<const long long*>(wf + 2 * 32768 + c * 512 + l * 8);
      a0 = __builtin_amdgcn_mfma_f32_16x16x32_fp8_fp8(w0, bv, a0, 0, 0, 0);
      a1 = __builtin_amdgcn_mfma_f32_16x16x32_fp8_fp8(w1, bv, a1, 0, 0, 0);
      a2 = __builtin_amdgcn_mfma_f32_16x16x32_fp8_fp8(w2, bv, a2, 0, 0, 0);
    }
    {
      int bcol = l & 15;
      if (bcol < 8) {
        int lb = l >> 4;
        *reinterpret_cast<f32x4*>(pt + w * 384 + 0 * 128 + lb * 32 + bcol * 4) = a0;
        *reinterpret_cast<f32x4*>(pt + w * 384 + 1 * 128 + lb * 32 + bcol * 4) = a1;
        *reinterpret_cast<f32x4*>(pt + w * 384 + 2 * 128 + lb * 32 + bcol * 4) = a2;
      }
    }
    __syncthreads();
    // combine (tid<128): reduce 16 wave-partials, GRU pointwise, write h (fp8) / rt
    if (tid < 128) {
      float s[3];
#pragma unroll
      for (int g = 0; g < 3; g++) {
        int base = g * 128 + (cj >> 2) * 32 + cb * 4 + (cj & 3);
        float acc = 0.f;
#pragma unroll
        for (int w2 = 0; w2 < 16; w2++) acc += pt[w2 * 384 + base];
        s[g] = acc;
      }
      float r_ = 1.0f / (1.0f + __expf(-(gir + s[0] + bR)));
      float z_ = 1.0f / (1.0f + __expf(-(giz + s[1] + bZ)));
      float n_ = tanhf(gin + r_ * (s[2] + bN));
      hold = (1.0f - z_) * n_ + z_ * hold;
      {
        unsigned int p = __builtin_amdgcn_cvt_pk_fp8_f32(hold, 0.0f, 0, false);
        __hip_atomic_store(hn + cb * 2000 + jg, (unsigned char)(p & 0xFF),
                           __ATOMIC_RELAXED, __HIP_MEMORY_SCOPE_AGENT);
      }
      rt[((size_t)cb * 96 + t) * 2000 + jg] = hold;
    }
    // __syncthreads drains all waves' stores to the coherence point
    __syncthreads();
    // tree barrier: relaxed RMWs, relaxed poll, single acquire at exit
    if (tid == 0) {
      int r = __hip_atomic_fetch_add(&grp[(t * NGRP + mygrp) * 32], 1,
                                     __ATOMIC_RELAXED, __HIP_MEMORY_SCOPE_AGENT);
      if (r == gsz - 1) {
        __hip_atomic_fetch_add(&root[t * 32], 1, __ATOMIC_RELAXED,
                               __HIP_MEMORY_SCOPE_AGENT);
      }
    }
    if (tid == 128) {
      while (__hip_atomic_load(&root[t * 32], __ATOMIC_RELAXED,
                               __HIP_MEMORY_SCOPE_AGENT) < NGRP) {
        __builtin_amdgcn_s_sleep(1);
      }
      (void)__hip_atomic_load(&root[t * 32], __ATOMIC_ACQUIRE,
                              __HIP_MEMORY_SCOPE_AGENT);
    }
    __syncthreads();
  }
}

// ---------------- Kernel 8: final combine + out matmul ----------------
__global__ __launch_bounds__(256) void k_final(
    const float* __restrict__ rs, const float* __restrict__ rt,
    const float* __restrict__ outW, const float* __restrict__ outb,
    float* __restrict__ out) {
  __shared__ float w[96];
  __shared__ float ob;
  int tid = threadIdx.x;
  if (tid < 96) w[tid] = outW[tid];
  if (tid == 0) ob = outb[0];
  __syncthreads();
  int gidx = blockIdx.x * 256 + tid;
  if (gidx >= 16000) return;
  int b = gidx / 2000, n = gidx % 2000;
  const float* rsp = rs + (size_t)gidx * 96;
  float acc = ob;
  for (int t4 = 0; t4 < 24; t4++) {
    float4 rv = *reinterpret_cast<const float4*>(rsp + t4 * 4);
    int t = t4 * 4;
    acc = fmaf(rv.x + rt[((size_t)b * 96 + t + 0) * 2000 + n], w[t + 0], acc);
    acc = fmaf(rv.y + rt[((size_t)b * 96 + t + 1) * 2000 + n], w[t + 1], acc);
    acc = fmaf(rv.z + rt[((size_t)b * 96 + t + 2) * 2000 + n], w[t + 2], acc);
    acc = fmaf(rv.w + rt[((size_t)b * 96 + t + 3) * 2000 + n], w[t + 3], acc);
  }
  out[gidx] = acc;
}

extern "C" void kernel_launch(void* const* d_in, const int* in_sizes, int n_in,
                              void* d_out, int out_size, void* d_ws, size_t ws_size,
                              hipStream_t stream) {
  const float* x      = (const float*)d_in[0];
  const float* x_mark = (const float*)d_in[1];
  const float* sp_emb = (const float*)d_in[2];
  const float* sp_W1  = (const float*)d_in[3];
  const float* sp_b1  = (const float*)d_in[4];
  const float* sp_W2  = (const float*)d_in[5];
  const float* sp_b2  = (const float*)d_in[6];
  const float* t_emb  = (const float*)d_in[7];
  const float* t_Wih  = (const float*)d_in[8];
  const float* t_Whh  = (const float*)d_in[9];
  const float* t_bih  = (const float*)d_in[10];
  const float* t_bhh  = (const float*)d_in[11];
  const float* gcn_W  = (const float*)d_in[12];
  const float* gcn_b  = (const float*)d_in[13];
  const float* fr_W1  = (const float*)d_in[14];
  const float* fr_b1  = (const float*)d_in[15];
  const float* fr_W2  = (const float*)d_in[16];
  const float* fr_b2  = (const float*)d_in[17];
  const float* tr_Wih = (const float*)d_in[18];
  const float* tr_Whh = (const float*)d_in[19];
  const float* tr_bih = (const float*)d_in[20];
  const float* tr_bhh = (const float*)d_in[21];
  const float* out_W  = (const float*)d_in[22];
  const float* out_b  = (const float*)d_in[23];
  (void)in_sizes; (void)n_in; (void)out_size; (void)ws_size;

  float* ws = (float*)d_ws;
  float* X0   = ws;                    // 8*2096*32 = 536576
  float* X1   = X0 + 536576;
  float* X2   = X1 + 536576;
  float* tgi  = X2 + 536576;           // 768*96 = 73728
  float* trgi = tgi + 73728;           // 8*96*6000 = 4608000
  float* hsl  = trgi + 4608000;        // 16000 f32 slot -> hA/hB (fp8, 16000 B each)
  float* rt   = hsl + 16000;           // 8*96*2000 = 1536000
  float* rs   = rt + 1536000;          // 8*2000*96 = 1536000
  float* barf = rs + 1536000;          // BAR_INTS ints

  unsigned char* hA = (unsigned char*)hsl;
  unsigned char* hB = hA + 16000;
  int* bar  = (int*)barf;
  int* grp  = bar;
  int* root = bar + 96 * NGRP * 32;

  k_spatial<<<63, 256, 0, stream>>>(x, sp_emb, sp_W1, sp_b1, sp_W2, sp_b2, X0, bar, hA);
  k_tgi<<<96, 256, 0, stream>>>(x, x_mark, t_emb, t_Wih, t_bih, tgi);
  k_tgru<<<1, 768, 0, stream>>>(tgi, t_Whh, t_bhh, X0);

  dim3 gg(66, 8);
  k_gnn<<<gg, 256, 0, stream>>>(X0, X0, X1, gcn_W + 0 * 1024, gcn_b + 0 * 32);
  k_gnn<<<gg, 256, 0, stream>>>(X0, X1, X2, gcn_W + 1 * 1024, gcn_b + 1 * 32);
  k_gnn<<<gg, 256, 0, stream>>>(X2, X2, X0, gcn_W + 2 * 1024, gcn_b + 2 * 32);
  k_gnn<<<gg, 256, 0, stream>>>(X2, X0, X1, gcn_W + 3 * 1024, gcn_b + 3 * 32);

  k_rs<<<dim3(63, 8), 256, 0, stream>>>(X1, fr_W1, fr_b1, fr_W2, fr_b2, rs);
  k_trgi<<<dim3(16, 8), 256, 0, stream>>>(X1, tr_Wih, tr_bih, trgi);

  {
    const float* a0 = trgi;
    const float* a1 = tr_Whh;
    const float* a2 = tr_bhh;
    unsigned char* a3 = hA;
    unsigned char* a4 = hB;
    float* a5 = rt;
    int* a6 = grp;
    int* a7 = root;
    void* cargs[] = {&a0, &a1, &a2, &a3, &a4, &a5, &a6, &a7};
    hipLaunchCooperativeKernel((const void*)k_trgru, dim3(NBLK), dim3(1024), cargs, 0, stream);
  }

  k_final<<<63, 256, 0, stream>>>(rs, rt, out_W, out_b, (float*)d_out);
}

// Round 8
// 1240.855 us; speedup vs baseline: 2.8229x; 1.1926x over previous
//
#include <hip/hip_runtime.h>

typedef _Float16 half8 __attribute__((ext_vector_type(8)));
typedef float f32x4 __attribute__((ext_vector_type(4)));

#define NBLK 125
#define NGRP 16
#define BAR_INTS (96 * NGRP * 32 + 96 * 32)

// ---------------- Kernel 1: spatial MLP -> X[:, 0:2000, :] (f16 out, + fused init) ----------------
__global__ __launch_bounds__(256) void k_spatial(
    const float* __restrict__ x, const float* __restrict__ sp_emb,
    const float* __restrict__ W1, const float* __restrict__ b1,
    const float* __restrict__ W2, const float* __restrict__ b2,
    _Float16* __restrict__ X, int* __restrict__ bar, unsigned char* __restrict__ hA) {
  __shared__ float W1s[128 * 32];
  __shared__ float W2s[32 * 32];
  __shared__ float b1s[32], b2s[32];
  int tid = threadIdx.x;
  int gidx = blockIdx.x * 256 + tid;
  for (int i = gidx; i < BAR_INTS; i += 63 * 256) bar[i] = 0;
  for (int i = gidx; i < 4000; i += 63 * 256) ((unsigned int*)hA)[i] = 0u;
  for (int i = tid; i < 128 * 32; i += 256) W1s[i] = W1[i];
  for (int i = tid; i < 32 * 32; i += 256) W2s[i] = W2[i];
  if (tid < 32) { b1s[tid] = b1[tid]; b2s[tid] = b2[tid]; }
  __syncthreads();
  if (gidx >= 8 * 2000) return;
  int b = gidx / 2000, n = gidx % 2000;
  float h1[32];
#pragma unroll
  for (int l = 0; l < 32; l++) h1[l] = b1s[l];
  for (int k = 0; k < 96; k++) {
    float xv = x[((size_t)b * 96 + k) * 2000 + n];
#pragma unroll
    for (int l = 0; l < 32; l++) h1[l] = fmaf(xv, W1s[k * 32 + l], h1[l]);
  }
  for (int e4 = 0; e4 < 8; e4++) {
    float4 ev = *reinterpret_cast<const float4*>(&sp_emb[(size_t)n * 32 + e4 * 4]);
    float evs[4] = {ev.x, ev.y, ev.z, ev.w};
#pragma unroll
    for (int q = 0; q < 4; q++) {
      int e = e4 * 4 + q;
#pragma unroll
      for (int l = 0; l < 32; l++) h1[l] = fmaf(evs[q], W1s[(96 + e) * 32 + l], h1[l]);
    }
  }
  float out[32];
#pragma unroll
  for (int j = 0; j < 32; j++) out[j] = b2s[j];
  for (int l = 0; l < 32; l++) {
    float a = h1[l] > 0.0f ? h1[l] : (__expf(h1[l]) - 1.0f);
#pragma unroll
    for (int j = 0; j < 32; j++) out[j] = fmaf(a, W2s[l * 32 + j], out[j]);
  }
  _Float16* dst = X + ((size_t)b * 2096 + n) * 32;
#pragma unroll
  for (int j8 = 0; j8 < 4; j8++) {
    half8 v;
#pragma unroll
    for (int q = 0; q < 8; q++) v[q] = (_Float16)out[j8 * 8 + q];
    *reinterpret_cast<half8*>(dst + j8 * 8) = v;
  }
}

// ---------------- Kernel 2: temporal GRU input gates precompute ----------------
__global__ __launch_bounds__(256) void k_tgi(
    const float* __restrict__ x, const float* __restrict__ x_mark,
    const float* __restrict__ t_emb, const float* __restrict__ Wih,
    const float* __restrict__ bih, float* __restrict__ gi) {
  __shared__ float xs[8][2036];
  int tid = threadIdx.x;
  int row0 = blockIdx.x * 8;
  for (int rr = 0; rr < 8; rr++) {
    int row = row0 + rr;
    int b = row / 96, t = row % 96;
    for (int k = tid; k < 2036; k += 256) {
      float v;
      if (k < 2000) v = x[((size_t)b * 96 + t) * 2000 + k];
      else if (k < 2004) v = x_mark[((size_t)b * 96 + t) * 4 + (k - 2000)];
      else v = t_emb[(size_t)t * 32 + (k - 2004)];
      xs[rr][k] = v;
    }
  }
  __syncthreads();
  for (int oi = tid; oi < 8 * 96; oi += 256) {
    int rr = oi & 7, g = oi >> 3;
    const float* w = Wih + (size_t)g * 2036;
    float acc = bih[g];
    for (int k = 0; k < 2036; k += 4) {
      float4 wv = *reinterpret_cast<const float4*>(w + k);
      acc = fmaf(xs[rr][k + 0], wv.x, acc);
      acc = fmaf(xs[rr][k + 1], wv.y, acc);
      acc = fmaf(xs[rr][k + 2], wv.z, acc);
      acc = fmaf(xs[rr][k + 3], wv.w, acc);
    }
    gi[(size_t)(row0 + rr) * 96 + g] = acc;
  }
}

// ---------------- Kernel 3: temporal GRU scan (hidden=32), f16 X out ----------------
__global__ __launch_bounds__(768) void k_tgru(
    const float* __restrict__ gi, const float* __restrict__ Whh,
    const float* __restrict__ bhh, _Float16* __restrict__ X) {
  __shared__ float Whs[96][33];
  __shared__ float hs[8][33];
  __shared__ float ga[3][8][33];
  int tid = threadIdx.x;
  for (int i = tid; i < 96 * 32; i += 768) Whs[i >> 5][i & 31] = Whh[i];
  if (tid < 256) hs[tid >> 5][tid & 31] = 0.0f;
  int g = tid >> 8, j = (tid >> 3) & 31, b = tid & 7;
  int row = g * 32 + j;
  float bb0 = 0.f, bb1 = 0.f, bb2 = 0.f;
  if (tid < 256) {
    int jj = tid & 31;
    bb0 = bhh[jj]; bb1 = bhh[32 + jj]; bb2 = bhh[64 + jj];
  }
  __syncthreads();
  for (int t = 0; t < 96; t++) {
    float acc = 0.0f;
#pragma unroll
    for (int k = 0; k < 32; k++) acc = fmaf(hs[b][k], Whs[row][k], acc);
    ga[g][b][j] = acc;
    __syncthreads();
    if (tid < 256) {
      int bb = tid >> 5, jj = tid & 31;
      const float* gp = gi + ((size_t)bb * 96 + t) * 96;
      float gr = ga[0][bb][jj] + bb0;
      float gz = ga[1][bb][jj] + bb1;
      float gn = ga[2][bb][jj] + bb2;
      float r = 1.0f / (1.0f + __expf(-(gp[jj] + gr)));
      float z = 1.0f / (1.0f + __expf(-(gp[32 + jj] + gz)));
      float n = tanhf(gp[64 + jj] + r * gn);
      float hn = (1.0f - z) * n + z * hs[bb][jj];
      hs[bb][jj] = hn;
      X[((size_t)bb * 2096 + 2000 + t) * 32 + jj] = (_Float16)hn;
    }
    __syncthreads();
  }
}

// ---------------- Kernel 4: fused GNN pass (MFMA, f16 X, async-staged) ----------------
__global__ __launch_bounds__(256) void k_gnn(
    const _Float16* __restrict__ Xa, const _Float16* __restrict__ Xin,
    _Float16* __restrict__ Xout, const float* __restrict__ W,
    const float* __restrict__ bias) {
  __shared__ _Float16 XaR[32][40];
  __shared__ _Float16 Xm[2][64][40];
  __shared__ _Float16 Xq[2][64][40];
  __shared__ _Float16 At[32][72];
  __shared__ float Pm[32][36];
  __shared__ float Ws[32][36];
  __shared__ float bs[32];
  int tid = threadIdx.x;
  int l = tid & 63, w = tid >> 6;
  int b = blockIdx.y;
  int r0 = blockIdx.x * 32;
  const _Float16* Xab = Xa + (size_t)b * 2096 * 32;
  const _Float16* Xib = Xin + (size_t)b * 2096 * 32;
  half8 hz = {(_Float16)0, (_Float16)0, (_Float16)0, (_Float16)0,
              (_Float16)0, (_Float16)0, (_Float16)0, (_Float16)0};

  for (int i = tid; i < 1024; i += 256) Ws[i >> 5][i & 31] = W[i];
  if (tid < 32) bs[tid] = bias[tid];
  if (tid < 128) {
    int r = tid >> 2, k = (tid & 3) * 8;
    half8 v = (r0 + r < 2096)
                  ? *reinterpret_cast<const half8*>(Xab + (size_t)(r0 + r) * 32 + k)
                  : hz;
    *reinterpret_cast<half8*>(&XaR[r][k]) = v;
  }
  int sr = tid >> 2, sk = (tid & 3) * 8;
  {
    *reinterpret_cast<half8*>(&Xm[0][sr][sk]) =
        *reinterpret_cast<const half8*>(Xab + (size_t)sr * 32 + sk);
    *reinterpret_cast<half8*>(&Xq[0][sr][sk]) =
        *reinterpret_cast<const half8*>(Xib + (size_t)sr * 32 + sk);
  }
  __syncthreads();

  int lr = l & 15, lk = (l >> 4) * 8, lq = (l >> 4) * 4;
  int smt = w >> 1, snt2 = w & 1;
  int pmt = w >> 1, pnt = w & 1;
  half8 afrag = *reinterpret_cast<const half8*>(&XaR[smt * 16 + lr][lk]);
  f32x4 pacc = {0.f, 0.f, 0.f, 0.f};

  for (int tt = 0; tt < 33; tt++) {
    int cur = tt & 1, nb = cur ^ 1;
    // issue next-tile loads early (consumed after P-phase -> latency hidden)
    half8 vm = hz, vq = hz;
    bool hv = (tt + 1 < 33);
    if (hv) {
      int gm = (tt + 1) * 64 + sr;
      if (gm < 2096) {
        vm = *reinterpret_cast<const half8*>(Xab + (size_t)gm * 32 + sk);
        vq = *reinterpret_cast<const half8*>(Xib + (size_t)gm * 32 + sk);
      }
    }
    // S-phase + activation -> At
#pragma unroll
    for (int n16 = 0; n16 < 2; n16++) {
      int c0 = snt2 * 32 + n16 * 16;
      half8 bfrag = *reinterpret_cast<const half8*>(&Xm[cur][c0 + lr][lk]);
      f32x4 s4 = __builtin_amdgcn_mfma_f32_16x16x32_f16(
          afrag, bfrag, (f32x4){0.f, 0.f, 0.f, 0.f}, 0, 0, 0);
#pragma unroll
      for (int j = 0; j < 4; j++) {
        float e = __expf(-2.0f * fmaxf(s4[j], 0.0f));
        At[smt * 16 + lq + j][c0 + lr] = (_Float16)((1.0f - e) / (1.0f + e));
      }
    }
    __syncthreads();
    // P-phase
#pragma unroll
    for (int kc = 0; kc < 2; kc++) {
      half8 af = *reinterpret_cast<const half8*>(&At[pmt * 16 + lr][kc * 32 + lk]);
      half8 bf;
      int kb = kc * 32 + lk;
      int nn = pnt * 16 + lr;
#pragma unroll
      for (int e = 0; e < 8; e++) bf[e] = Xq[cur][kb + e][nn];
      pacc = __builtin_amdgcn_mfma_f32_16x16x32_f16(af, bf, pacc, 0, 0, 0);
    }
    // write staged regs late (other buffer; no hazard with P reads of cur)
    if (hv) {
      *reinterpret_cast<half8*>(&Xm[nb][sr][sk]) = vm;
      *reinterpret_cast<half8*>(&Xq[nb][sr][sk]) = vq;
    }
    __syncthreads();
  }

#pragma unroll
  for (int j = 0; j < 4; j++) Pm[pmt * 16 + lq + j][pnt * 16 + lr] = pacc[j];
  __syncthreads();
  int r = tid & 31, fgr = tid >> 5;
  int f0 = fgr * 4;
  float o[4];
#pragma unroll
  for (int j = 0; j < 4; j++) o[j] = bs[f0 + j];
#pragma unroll
  for (int k = 0; k < 32; k++) {
    float mv = Pm[r][k];
    float4 wv = *reinterpret_cast<const float4*>(&Ws[k][f0]);
    o[0] = fmaf(mv, wv.x, o[0]);
    o[1] = fmaf(mv, wv.y, o[1]);
    o[2] = fmaf(mv, wv.z, o[2]);
    o[3] = fmaf(mv, wv.w, o[3]);
  }
  int grr = r0 + r;
  if (grr < 2096) {
    _Float16* dst = Xout + ((size_t)b * 2096 + grr) * 32 + f0;
#pragma unroll
    for (int j = 0; j < 4; j++) {
      float v = o[j];
      dst[j] = (_Float16)(v > 0.0f ? v : (__expf(v) - 1.0f));
    }
  }
}

// ---------------- Kernel 5: spatial readout MLP rs (f16 X in) ----------------
__global__ __launch_bounds__(256) void k_rs(
    const _Float16* __restrict__ X, const float* __restrict__ W1,
    const float* __restrict__ b1, const float* __restrict__ W2,
    const float* __restrict__ b2, float* __restrict__ rs) {
  __shared__ float Xt[32][33];
  __shared__ float W2s[96][100];
  __shared__ float Hl[32][100];
  __shared__ float b1s[96], b2s[96];
  int tid = threadIdx.x;
  int b = blockIdx.y;
  int n0 = blockIdx.x * 32;
  for (int i = tid; i < 96 * 96; i += 256) W2s[i / 96][i % 96] = W2[i];
  if (tid < 96) { b1s[tid] = b1[tid]; b2s[tid] = b2[tid]; }
  for (int i = tid; i < 32 * 32; i += 256) {
    int r = i >> 5, k = i & 31;
    Xt[r][k] = (n0 + r < 2000) ? (float)X[((size_t)b * 2096 + n0 + r) * 32 + k] : 0.0f;
  }
  __syncthreads();
  int r = tid & 31, cg = tid >> 5;
#pragma unroll
  for (int i = 0; i < 12; i++) {
    int c = cg * 12 + i;
    float a = b1s[c];
    for (int k = 0; k < 32; k++) a = fmaf(Xt[r][k], W1[k * 96 + c], a);
    Hl[r][c] = a > 0.0f ? a : (__expf(a) - 1.0f);
  }
  __syncthreads();
  float o[12];
#pragma unroll
  for (int i = 0; i < 12; i++) o[i] = b2s[cg * 12 + i];
  for (int k = 0; k < 96; k++) {
    float hv = Hl[r][k];
#pragma unroll
    for (int i = 0; i < 12; i++) o[i] = fmaf(hv, W2s[k][cg * 12 + i], o[i]);
  }
  if (n0 + r < 2000) {
    float* dst = rs + ((size_t)b * 2000 + n0 + r) * 96 + cg * 12;
#pragma unroll
    for (int i = 0; i < 12; i++) dst[i] = o[i];
  }
}

// ---------------- Kernel 6: tr-GRU input gates precompute (f16 X in) ----------------
__global__ __launch_bounds__(256) void k_trgi(
    const _Float16* __restrict__ X, const float* __restrict__ Wih,
    const float* __restrict__ bih, float* __restrict__ gi) {
  __shared__ float Xs[96][33];
  __shared__ float Wsh[384][33];
  int tid = threadIdx.x;
  int b = blockIdx.y;
  int g0 = blockIdx.x * 384;
  for (int i = tid; i < 96 * 32; i += 256) {
    int t = i >> 5, k = i & 31;
    Xs[t][k] = (float)X[((size_t)b * 2096 + 2000 + t) * 32 + k];
  }
  for (int i = tid; i < 384 * 32; i += 256) {
    int g = i >> 5, k = i & 31;
    Wsh[g][k] = (g0 + g < 6000) ? Wih[(size_t)(g0 + g) * 32 + k] : 0.0f;
  }
  __syncthreads();
  for (int oi = tid; oi < 96 * 384; oi += 256) {
    int t = oi / 384, g = oi % 384;
    if (g0 + g >= 6000) continue;
    float a = bih[g0 + g];
#pragma unroll
    for (int k = 0; k < 32; k++) a = fmaf(Xs[t][k], Wsh[g][k], a);
    gi[((size_t)b * 96 + t) * 6000 + g0 + g] = a;
  }
}

// ---------------- Kernel 7: tr-GRU scan, persistent, FP8 MFMA, 125 blocks ----------------
__global__ __launch_bounds__(1024) void k_trgru(
    const float* __restrict__ gi, const float* __restrict__ whh,
    const float* __restrict__ bhh, unsigned char* __restrict__ hA,
    unsigned char* __restrict__ hB, float* __restrict__ rt,
    int* __restrict__ grp, int* __restrict__ root) {
  __shared__ unsigned char wf[3 * 32768];  // [tile][chunk 64][lane 64][8B]
  __shared__ unsigned char hf[16384];      // [chunk 64][slot 32][8B]
  __shared__ float pt[6144];               // [wave 16][tile 3][lb 4][b 8][reg 4]
  int tid = threadIdx.x;
  int blk = blockIdx.x;
  int l = tid & 63, w = tid >> 6;

  for (int i = tid; i < 12288; i += 1024) ((unsigned long long*)wf)[i] = 0ull;
  for (int i = tid; i < 2048; i += 1024) ((unsigned long long*)hf)[i] = 0ull;
  __syncthreads();

  // one-time weight fill: f32 -> fp8 e4m3 fragments
  for (int i = tid; i < 3 * 64 * 64; i += 1024) {
    int g = i >> 12;
    int c = (i >> 6) & 63;
    int l2 = i & 63;
    int j = l2 & 15;
    int k0 = c * 32 + ((l2 >> 4) << 3);
    if (k0 <= 1992) {
      const float* src = whh + ((size_t)(g * 2000 + blk * 16 + j)) * 2000 + k0;
      float4 v0 = *reinterpret_cast<const float4*>(src);
      float4 v1 = *reinterpret_cast<const float4*>(src + 4);
      unsigned int lo = __builtin_amdgcn_cvt_pk_fp8_f32(v0.x, v0.y, 0, false);
      lo = __builtin_amdgcn_cvt_pk_fp8_f32(v0.z, v0.w, lo, true);
      unsigned int hi = __builtin_amdgcn_cvt_pk_fp8_f32(v1.x, v1.y, 0, false);
      hi = __builtin_amdgcn_cvt_pk_fp8_f32(v1.z, v1.w, hi, true);
      unsigned long long q = ((unsigned long long)hi << 32) | (unsigned long long)lo;
      *reinterpret_cast<unsigned long long*>(wf + (size_t)g * 32768 + c * 512 + l2 * 8) = q;
    }
  }

  int cj = tid >> 3, cb = tid & 7;
  int jg = blk * 16 + cj;
  float hold = 0.0f, bR = 0.f, bZ = 0.f, bN = 0.f;
  if (tid < 128) {
    bR = bhh[jg]; bZ = bhh[2000 + jg]; bN = bhh[4000 + jg];
  }
  int bslot = ((l >> 4) * 8 + (l & 7)) * 8;
  int mygrp = blk >> 3;
  int gsz = (mygrp == 15) ? 5 : 8;
  __syncthreads();

  for (int t = 0; t < 96; t++) {
    const unsigned char* hc = (t & 1) ? hB : hA;
    unsigned char* hn = (t & 1) ? hA : hB;
    float gir = 0.f, giz = 0.f, gin = 0.f;
    if (tid < 128) {
      const float* gp = gi + ((size_t)cb * 96 + t) * 6000;
      gir = gp[jg]; giz = gp[2000 + jg]; gin = gp[4000 + jg];
    }
    for (int i = tid; i < 2048; i += 1024) {
      int c = i >> 5, s = i & 31;
      int b = s & 7;
      int k0 = c * 32 + ((s >> 3) << 3);
      if (k0 < 2000) {
        unsigned long long v =
            *reinterpret_cast<const unsigned long long*>(hc + b * 2000 + k0);
        *reinterpret_cast<unsigned long long*>(hf + c * 256 + s * 8) = v;
      }
    }
    __syncthreads();
    f32x4 a0 = {0.f, 0.f, 0.f, 0.f}, a1 = {0.f, 0.f, 0.f, 0.f}, a2 = {0.f, 0.f, 0.f, 0.f};
#pragma unroll
    for (int i = 0; i < 4; i++) {
      int c = w * 4 + i;
      long long bv = *reinterpret_cast<const long long*>(hf + c * 256 + bslot);
      long long w0 = *reinterpret_cast<const long long*>(wf + 0 * 32768 + c * 512 + l * 8);
      long long w1 = *reinterpret_cast<const long long*>(wf + 1 * 32768 + c * 512 + l * 8);
      long long w2 = *reinterpret_cast<const long long*>(wf + 2 * 32768 + c * 512 + l * 8);
      a0 = __builtin_amdgcn_mfma_f32_16x16x32_fp8_fp8(w0, bv, a0, 0, 0, 0);
      a1 = __builtin_amdgcn_mfma_f32_16x16x32_fp8_fp8(w1, bv, a1, 0, 0, 0);
      a2 = __builtin_amdgcn_mfma_f32_16x16x32_fp8_fp8(w2, bv, a2, 0, 0, 0);
    }
    {
      int bcol = l & 15;
      if (bcol < 8) {
        int lb = l >> 4;
        *reinterpret_cast<f32x4*>(pt + w * 384 + 0 * 128 + lb * 32 + bcol * 4) = a0;
        *reinterpret_cast<f32x4*>(pt + w * 384 + 1 * 128 + lb * 32 + bcol * 4) = a1;
        *reinterpret_cast<f32x4*>(pt + w * 384 + 2 * 128 + lb * 32 + bcol * 4) = a2;
      }
    }
    __syncthreads();
    if (tid < 128) {
      float s[3];
#pragma unroll
      for (int g = 0; g < 3; g++) {
        int base = g * 128 + (cj >> 2) * 32 + cb * 4 + (cj & 3);
        float acc = 0.f;
#pragma unroll
        for (int w2 = 0; w2 < 16; w2++) acc += pt[w2 * 384 + base];
        s[g] = acc;
      }
      float r_ = 1.0f / (1.0f + __expf(-(gir + s[0] + bR)));
      float z_ = 1.0f / (1.0f + __expf(-(giz + s[1] + bZ)));
      float n_ = tanhf(gin + r_ * (s[2] + bN));
      hold = (1.0f - z_) * n_ + z_ * hold;
      {
        unsigned int p = __builtin_amdgcn_cvt_pk_fp8_f32(hold, 0.0f, 0, false);
        __hip_atomic_store(hn + cb * 2000 + jg, (unsigned char)(p & 0xFF),
                           __ATOMIC_RELAXED, __HIP_MEMORY_SCOPE_AGENT);
      }
      rt[((size_t)cb * 96 + t) * 2000 + jg] = hold;
    }
    __syncthreads();
    if (tid == 0) {
      int r = __hip_atomic_fetch_add(&grp[(t * NGRP + mygrp) * 32], 1,
                                     __ATOMIC_RELAXED, __HIP_MEMORY_SCOPE_AGENT);
      if (r == gsz - 1) {
        __hip_atomic_fetch_add(&root[t * 32], 1, __ATOMIC_RELAXED,
                               __HIP_MEMORY_SCOPE_AGENT);
      }
    }
    if (tid == 128) {
      while (__hip_atomic_load(&root[t * 32], __ATOMIC_RELAXED,
                               __HIP_MEMORY_SCOPE_AGENT) < NGRP) {
        __builtin_amdgcn_s_sleep(1);
      }
      (void)__hip_atomic_load(&root[t * 32], __ATOMIC_ACQUIRE,
                              __HIP_MEMORY_SCOPE_AGENT);
    }
    __syncthreads();
  }
}

// ---------------- Kernel 8: final combine + out matmul ----------------
__global__ __launch_bounds__(256) void k_final(
    const float* __restrict__ rs, const float* __restrict__ rt,
    const float* __restrict__ outW, const float* __restrict__ outb,
    float* __restrict__ out) {
  __shared__ float w[96];
  __shared__ float ob;
  int tid = threadIdx.x;
  if (tid < 96) w[tid] = outW[tid];
  if (tid == 0) ob = outb[0];
  __syncthreads();
  int gidx = blockIdx.x * 256 + tid;
  if (gidx >= 16000) return;
  int b = gidx / 2000, n = gidx % 2000;
  const float* rsp = rs + (size_t)gidx * 96;
  float acc = ob;
  for (int t4 = 0; t4 < 24; t4++) {
    float4 rv = *reinterpret_cast<const float4*>(rsp + t4 * 4);
    int t = t4 * 4;
    acc = fmaf(rv.x + rt[((size_t)b * 96 + t + 0) * 2000 + n], w[t + 0], acc);
    acc = fmaf(rv.y + rt[((size_t)b * 96 + t + 1) * 2000 + n], w[t + 1], acc);
    acc = fmaf(rv.z + rt[((size_t)b * 96 + t + 2) * 2000 + n], w[t + 2], acc);
    acc = fmaf(rv.w + rt[((size_t)b * 96 + t + 3) * 2000 + n], w[t + 3], acc);
  }
  out[gidx] = acc;
}

extern "C" void kernel_launch(void* const* d_in, const int* in_sizes, int n_in,
                              void* d_out, int out_size, void* d_ws, size_t ws_size,
                              hipStream_t stream) {
  const float* x      = (const float*)d_in[0];
  const float* x_mark = (const float*)d_in[1];
  const float* sp_emb = (const float*)d_in[2];
  const float* sp_W1  = (const float*)d_in[3];
  const float* sp_b1  = (const float*)d_in[4];
  const float* sp_W2  = (const float*)d_in[5];
  const float* sp_b2  = (const float*)d_in[6];
  const float* t_emb  = (const float*)d_in[7];
  const float* t_Wih  = (const float*)d_in[8];
  const float* t_Whh  = (const float*)d_in[9];
  const float* t_bih  = (const float*)d_in[10];
  const float* t_bhh  = (const float*)d_in[11];
  const float* gcn_W  = (const float*)d_in[12];
  const float* gcn_b  = (const float*)d_in[13];
  const float* fr_W1  = (const float*)d_in[14];
  const float* fr_b1  = (const float*)d_in[15];
  const float* fr_W2  = (const float*)d_in[16];
  const float* fr_b2  = (const float*)d_in[17];
  const float* tr_Wih = (const float*)d_in[18];
  const float* tr_Whh = (const float*)d_in[19];
  const float* tr_bih = (const float*)d_in[20];
  const float* tr_bhh = (const float*)d_in[21];
  const float* out_W  = (const float*)d_in[22];
  const float* out_b  = (const float*)d_in[23];
  (void)in_sizes; (void)n_in; (void)out_size; (void)ws_size;

  float* ws = (float*)d_ws;
  float* X0   = ws;                    // slots sized for f32; f16 uses half
  float* X1   = X0 + 536576;
  float* X2   = X1 + 536576;
  float* tgi  = X2 + 536576;           // 768*96 = 73728
  float* trgi = tgi + 73728;           // 8*96*6000 = 4608000
  float* hsl  = trgi + 4608000;        // hA/hB (fp8, 16000 B each)
  float* rt   = hsl + 16000;           // 8*96*2000 = 1536000
  float* rs   = rt + 1536000;          // 8*2000*96 = 1536000
  float* barf = rs + 1536000;          // BAR_INTS ints

  _Float16* X0h = (_Float16*)X0;
  _Float16* X1h = (_Float16*)X1;
  _Float16* X2h = (_Float16*)X2;
  unsigned char* hA = (unsigned char*)hsl;
  unsigned char* hB = hA + 16000;
  int* bar  = (int*)barf;
  int* grp  = bar;
  int* root = bar + 96 * NGRP * 32;

  k_spatial<<<63, 256, 0, stream>>>(x, sp_emb, sp_W1, sp_b1, sp_W2, sp_b2, X0h, bar, hA);
  k_tgi<<<96, 256, 0, stream>>>(x, x_mark, t_emb, t_Wih, t_bih, tgi);
  k_tgru<<<1, 768, 0, stream>>>(tgi, t_Whh, t_bhh, X0h);

  dim3 gg(66, 8);
  k_gnn<<<gg, 256, 0, stream>>>(X0h, X0h, X1h, gcn_W + 0 * 1024, gcn_b + 0 * 32);
  k_gnn<<<gg, 256, 0, stream>>>(X0h, X1h, X2h, gcn_W + 1 * 1024, gcn_b + 1 * 32);
  k_gnn<<<gg, 256, 0, stream>>>(X2h, X2h, X0h, gcn_W + 2 * 1024, gcn_b + 2 * 32);
  k_gnn<<<gg, 256, 0, stream>>>(X2h, X0h, X1h, gcn_W + 3 * 1024, gcn_b + 3 * 32);

  k_rs<<<dim3(63, 8), 256, 0, stream>>>(X1h, fr_W1, fr_b1, fr_W2, fr_b2, rs);
  k_trgi<<<dim3(16, 8), 256, 0, stream>>>(X1h, tr_Wih, tr_bih, trgi);

  {
    const float* a0 = trgi;
    const float* a1 = tr_Whh;
    const float* a2 = tr_bhh;
    unsigned char* a3 = hA;
    unsigned char* a4 = hB;
    float* a5 = rt;
    int* a6 = grp;
    int* a7 = root;
    void* cargs[] = {&a0, &a1, &a2, &a3, &a4, &a5, &a6, &a7};
    hipLaunchCooperativeKernel((const void*)k_trgru, dim3(NBLK), dim3(1024), cargs, 0, stream);
  }

  k_final<<<63, 256, 0, stream>>>(rs, rt, out_W, out_b, (float*)d_out);
}

// Round 9
// 1001.462 us; speedup vs baseline: 3.4977x; 1.2390x over previous
//
#include <hip/hip_runtime.h>

typedef _Float16 half8 __attribute__((ext_vector_type(8)));
typedef float f32x4 __attribute__((ext_vector_type(4)));

#define NBLK 125
#define BAR_INTS (NBLK * 32)

// ---------------- Kernel 1: spatial MLP -> X[:, 0:2000, :] (f16 out, + fused init) ----------------
__global__ __launch_bounds__(256) void k_spatial(
    const float* __restrict__ x, const float* __restrict__ sp_emb,
    const float* __restrict__ W1, const float* __restrict__ b1,
    const float* __restrict__ W2, const float* __restrict__ b2,
    _Float16* __restrict__ X, int* __restrict__ bar, unsigned char* __restrict__ hA) {
  __shared__ float W1s[128 * 32];
  __shared__ float W2s[32 * 32];
  __shared__ float b1s[32], b2s[32];
  int tid = threadIdx.x;
  int gidx = blockIdx.x * 256 + tid;
  for (int i = gidx; i < BAR_INTS; i += 63 * 256) bar[i] = 0;
  for (int i = gidx; i < 4000; i += 63 * 256) ((unsigned int*)hA)[i] = 0u;
  for (int i = tid; i < 128 * 32; i += 256) W1s[i] = W1[i];
  for (int i = tid; i < 32 * 32; i += 256) W2s[i] = W2[i];
  if (tid < 32) { b1s[tid] = b1[tid]; b2s[tid] = b2[tid]; }
  __syncthreads();
  if (gidx >= 8 * 2000) return;
  int b = gidx / 2000, n = gidx % 2000;
  float h1[32];
#pragma unroll
  for (int l = 0; l < 32; l++) h1[l] = b1s[l];
  for (int k = 0; k < 96; k++) {
    float xv = x[((size_t)b * 96 + k) * 2000 + n];
#pragma unroll
    for (int l = 0; l < 32; l++) h1[l] = fmaf(xv, W1s[k * 32 + l], h1[l]);
  }
  for (int e4 = 0; e4 < 8; e4++) {
    float4 ev = *reinterpret_cast<const float4*>(&sp_emb[(size_t)n * 32 + e4 * 4]);
    float evs[4] = {ev.x, ev.y, ev.z, ev.w};
#pragma unroll
    for (int q = 0; q < 4; q++) {
      int e = e4 * 4 + q;
#pragma unroll
      for (int l = 0; l < 32; l++) h1[l] = fmaf(evs[q], W1s[(96 + e) * 32 + l], h1[l]);
    }
  }
  float out[32];
#pragma unroll
  for (int j = 0; j < 32; j++) out[j] = b2s[j];
  for (int l = 0; l < 32; l++) {
    float a = h1[l] > 0.0f ? h1[l] : (__expf(h1[l]) - 1.0f);
#pragma unroll
    for (int j = 0; j < 32; j++) out[j] = fmaf(a, W2s[l * 32 + j], out[j]);
  }
  _Float16* dst = X + ((size_t)b * 2096 + n) * 32;
#pragma unroll
  for (int j8 = 0; j8 < 4; j8++) {
    half8 v;
#pragma unroll
    for (int q = 0; q < 8; q++) v[q] = (_Float16)out[j8 * 8 + q];
    *reinterpret_cast<half8*>(dst + j8 * 8) = v;
  }
}

// ---------------- Kernel 2: temporal GRU input gates precompute ----------------
__global__ __launch_bounds__(256) void k_tgi(
    const float* __restrict__ x, const float* __restrict__ x_mark,
    const float* __restrict__ t_emb, const float* __restrict__ Wih,
    const float* __restrict__ bih, float* __restrict__ gi) {
  __shared__ float xs[8][2036];
  int tid = threadIdx.x;
  int row0 = blockIdx.x * 8;
  for (int rr = 0; rr < 8; rr++) {
    int row = row0 + rr;
    int b = row / 96, t = row % 96;
    for (int k = tid; k < 2036; k += 256) {
      float v;
      if (k < 2000) v = x[((size_t)b * 96 + t) * 2000 + k];
      else if (k < 2004) v = x_mark[((size_t)b * 96 + t) * 4 + (k - 2000)];
      else v = t_emb[(size_t)t * 32 + (k - 2004)];
      xs[rr][k] = v;
    }
  }
  __syncthreads();
  for (int oi = tid; oi < 8 * 96; oi += 256) {
    int rr = oi & 7, g = oi >> 3;
    const float* w = Wih + (size_t)g * 2036;
    float acc = bih[g];
    for (int k = 0; k < 2036; k += 4) {
      float4 wv = *reinterpret_cast<const float4*>(w + k);
      acc = fmaf(xs[rr][k + 0], wv.x, acc);
      acc = fmaf(xs[rr][k + 1], wv.y, acc);
      acc = fmaf(xs[rr][k + 2], wv.z, acc);
      acc = fmaf(xs[rr][k + 3], wv.w, acc);
    }
    gi[(size_t)(row0 + rr) * 96 + g] = acc;
  }
}

// ---------------- Kernel 3: temporal GRU scan (hidden=32), f16 X out ----------------
__global__ __launch_bounds__(768) void k_tgru(
    const float* __restrict__ gi, const float* __restrict__ Whh,
    const float* __restrict__ bhh, _Float16* __restrict__ X) {
  __shared__ float Whs[96][33];
  __shared__ float hs[8][33];
  __shared__ float ga[3][8][33];
  int tid = threadIdx.x;
  for (int i = tid; i < 96 * 32; i += 768) Whs[i >> 5][i & 31] = Whh[i];
  if (tid < 256) hs[tid >> 5][tid & 31] = 0.0f;
  int g = tid >> 8, j = (tid >> 3) & 31, b = tid & 7;
  int row = g * 32 + j;
  float bb0 = 0.f, bb1 = 0.f, bb2 = 0.f;
  if (tid < 256) {
    int jj = tid & 31;
    bb0 = bhh[jj]; bb1 = bhh[32 + jj]; bb2 = bhh[64 + jj];
  }
  __syncthreads();
  for (int t = 0; t < 96; t++) {
    float acc = 0.0f;
#pragma unroll
    for (int k = 0; k < 32; k++) acc = fmaf(hs[b][k], Whs[row][k], acc);
    ga[g][b][j] = acc;
    __syncthreads();
    if (tid < 256) {
      int bb = tid >> 5, jj = tid & 31;
      const float* gp = gi + ((size_t)bb * 96 + t) * 96;
      float gr = ga[0][bb][jj] + bb0;
      float gz = ga[1][bb][jj] + bb1;
      float gn = ga[2][bb][jj] + bb2;
      float r = 1.0f / (1.0f + __expf(-(gp[jj] + gr)));
      float z = 1.0f / (1.0f + __expf(-(gp[32 + jj] + gz)));
      float n = tanhf(gp[64 + jj] + r * gn);
      float hn = (1.0f - z) * n + z * hs[bb][jj];
      hs[bb][jj] = hn;
      X[((size_t)bb * 2096 + 2000 + t) * 32 + jj] = (_Float16)hn;
    }
    __syncthreads();
  }
}

// ---------------- Kernel 4: fused GNN pass (MFMA, f16 X, async-staged) ----------------
__global__ __launch_bounds__(256) void k_gnn(
    const _Float16* __restrict__ Xa, const _Float16* __restrict__ Xin,
    _Float16* __restrict__ Xout, const float* __restrict__ W,
    const float* __restrict__ bias) {
  __shared__ _Float16 XaR[32][40];
  __shared__ _Float16 Xm[2][64][40];
  __shared__ _Float16 Xq[2][64][40];
  __shared__ _Float16 At[32][72];
  __shared__ float Pm[32][36];
  __shared__ float Ws[32][36];
  __shared__ float bs[32];
  int tid = threadIdx.x;
  int l = tid & 63, w = tid >> 6;
  int b = blockIdx.y;
  int r0 = blockIdx.x * 32;
  const _Float16* Xab = Xa + (size_t)b * 2096 * 32;
  const _Float16* Xib = Xin + (size_t)b * 2096 * 32;
  half8 hz = {(_Float16)0, (_Float16)0, (_Float16)0, (_Float16)0,
              (_Float16)0, (_Float16)0, (_Float16)0, (_Float16)0};

  for (int i = tid; i < 1024; i += 256) Ws[i >> 5][i & 31] = W[i];
  if (tid < 32) bs[tid] = bias[tid];
  if (tid < 128) {
    int r = tid >> 2, k = (tid & 3) * 8;
    half8 v = (r0 + r < 2096)
                  ? *reinterpret_cast<const half8*>(Xab + (size_t)(r0 + r) * 32 + k)
                  : hz;
    *reinterpret_cast<half8*>(&XaR[r][k]) = v;
  }
  int sr = tid >> 2, sk = (tid & 3) * 8;
  {
    *reinterpret_cast<half8*>(&Xm[0][sr][sk]) =
        *reinterpret_cast<const half8*>(Xab + (size_t)sr * 32 + sk);
    *reinterpret_cast<half8*>(&Xq[0][sr][sk]) =
        *reinterpret_cast<const half8*>(Xib + (size_t)sr * 32 + sk);
  }
  __syncthreads();

  int lr = l & 15, lk = (l >> 4) * 8, lq = (l >> 4) * 4;
  int smt = w >> 1, snt2 = w & 1;
  int pmt = w >> 1, pnt = w & 1;
  half8 afrag = *reinterpret_cast<const half8*>(&XaR[smt * 16 + lr][lk]);
  f32x4 pacc = {0.f, 0.f, 0.f, 0.f};

  for (int tt = 0; tt < 33; tt++) {
    int cur = tt & 1, nb = cur ^ 1;
    half8 vm = hz, vq = hz;
    bool hv = (tt + 1 < 33);
    if (hv) {
      int gm = (tt + 1) * 64 + sr;
      if (gm < 2096) {
        vm = *reinterpret_cast<const half8*>(Xab + (size_t)gm * 32 + sk);
        vq = *reinterpret_cast<const half8*>(Xib + (size_t)gm * 32 + sk);
      }
    }
#pragma unroll
    for (int n16 = 0; n16 < 2; n16++) {
      int c0 = snt2 * 32 + n16 * 16;
      half8 bfrag = *reinterpret_cast<const half8*>(&Xm[cur][c0 + lr][lk]);
      f32x4 s4 = __builtin_amdgcn_mfma_f32_16x16x32_f16(
          afrag, bfrag, (f32x4){0.f, 0.f, 0.f, 0.f}, 0, 0, 0);
#pragma unroll
      for (int j = 0; j < 4; j++) {
        float e = __expf(-2.0f * fmaxf(s4[j], 0.0f));
        At[smt * 16 + lq + j][c0 + lr] = (_Float16)((1.0f - e) / (1.0f + e));
      }
    }
    __syncthreads();
#pragma unroll
    for (int kc = 0; kc < 2; kc++) {
      half8 af = *reinterpret_cast<const half8*>(&At[pmt * 16 + lr][kc * 32 + lk]);
      half8 bf;
      int kb = kc * 32 + lk;
      int nn = pnt * 16 + lr;
#pragma unroll
      for (int e = 0; e < 8; e++) bf[e] = Xq[cur][kb + e][nn];
      pacc = __builtin_amdgcn_mfma_f32_16x16x32_f16(af, bf, pacc, 0, 0, 0);
    }
    if (hv) {
      *reinterpret_cast<half8*>(&Xm[nb][sr][sk]) = vm;
      *reinterpret_cast<half8*>(&Xq[nb][sr][sk]) = vq;
    }
    __syncthreads();
  }

#pragma unroll
  for (int j = 0; j < 4; j++) Pm[pmt * 16 + lq + j][pnt * 16 + lr] = pacc[j];
  __syncthreads();
  int r = tid & 31, fgr = tid >> 5;
  int f0 = fgr * 4;
  float o[4];
#pragma unroll
  for (int j = 0; j < 4; j++) o[j] = bs[f0 + j];
#pragma unroll
  for (int k = 0; k < 32; k++) {
    float mv = Pm[r][k];
    float4 wv = *reinterpret_cast<const float4*>(&Ws[k][f0]);
    o[0] = fmaf(mv, wv.x, o[0]);
    o[1] = fmaf(mv, wv.y, o[1]);
    o[2] = fmaf(mv, wv.z, o[2]);
    o[3] = fmaf(mv, wv.w, o[3]);
  }
  int grr = r0 + r;
  if (grr < 2096) {
    _Float16* dst = Xout + ((size_t)b * 2096 + grr) * 32 + f0;
#pragma unroll
    for (int j = 0; j < 4; j++) {
      float v = o[j];
      dst[j] = (_Float16)(v > 0.0f ? v : (__expf(v) - 1.0f));
    }
  }
}

// ---------------- Kernel 7: fused persistent kernel ----------------
// Blocks 0..124: tr-GRU scan (FP8 MFMA, seq-array barrier, own-slice gi prologue).
// Blocks 125..249: spatial readout MLP rs (runs on otherwise-idle CUs).
__global__ __launch_bounds__(1024) void k_trgru(
    const _Float16* __restrict__ X, const float* __restrict__ wih,
    const float* __restrict__ bih, float* __restrict__ gi,
    const float* __restrict__ whh, const float* __restrict__ bhh,
    unsigned char* __restrict__ hA, unsigned char* __restrict__ hB,
    float* __restrict__ rt, int* __restrict__ seq,
    const float* __restrict__ frW1, const float* __restrict__ frb1,
    const float* __restrict__ frW2, const float* __restrict__ frb2,
    float* __restrict__ rs) {
  __shared__ __align__(16) unsigned char SM[139264];
  int tid = threadIdx.x;
  int blk = blockIdx.x;

  if (blk >= NBLK) {
    // ================= rs path (spare blocks) =================
    float* W1s = (float*)(SM);            // 32*96 f32
    float* W2s = (float*)(SM + 12288);    // 96*100 f32
    float* b1s = (float*)(SM + 50688);    // 96
    float* b2s = (float*)(SM + 51072);    // 96
    float* Xt  = (float*)(SM + 51456);    // 32*33
    float* Hl  = (float*)(SM + 55680);    // 32*100
    for (int i = tid; i < 32 * 96; i += 1024) W1s[i] = frW1[i];
    for (int i = tid; i < 96 * 96; i += 1024) W2s[(i / 96) * 100 + (i % 96)] = frW2[i];
    if (tid < 96) { b1s[tid] = frb1[tid]; b2s[tid] = frb2[tid]; }
    __syncthreads();
    for (int ti = blk - NBLK; ti < 504; ti += NBLK) {
      int b = ti / 63, n0 = (ti % 63) * 32;
      {
        int r = tid >> 5, k = tid & 31;
        Xt[r * 33 + k] =
            (n0 + r < 2000) ? (float)X[((size_t)b * 2096 + n0 + r) * 32 + k] : 0.0f;
      }
      __syncthreads();
#pragma unroll
      for (int q = 0; q < 3; q++) {
        int idx = q * 1024 + tid;
        int r = idx / 96, c = idx % 96;
        float a = b1s[c];
#pragma unroll 8
        for (int k = 0; k < 32; k++) a = fmaf(Xt[r * 33 + k], W1s[k * 96 + c], a);
        Hl[r * 100 + c] = a > 0.0f ? a : (__expf(a) - 1.0f);
      }
      __syncthreads();
#pragma unroll
      for (int q = 0; q < 3; q++) {
        int idx = q * 1024 + tid;
        int r = idx / 96, c = idx % 96;
        float o = b2s[c];
#pragma unroll 8
        for (int k = 0; k < 96; k++) o = fmaf(Hl[r * 100 + k], W2s[k * 100 + c], o);
        if (n0 + r < 2000) rs[((size_t)b * 2000 + n0 + r) * 96 + c] = o;
      }
      __syncthreads();
    }
    return;
  }

  // ================= GRU path =================
  unsigned char* wf = SM;                       // 3*32768: [tile][chunk 64][lane 64][8B]
  unsigned char* hf = SM + 98304;               // 16384:   [chunk 64][slot 32][8B]
  float* pt = (float*)(SM + 114688);            // 6144 f32: [wave 16][tile 3][lb 4][b 8][reg 4]
  int l = tid & 63, w = tid >> 6;

  for (int i = tid; i < 12288; i += 1024) ((unsigned long long*)wf)[i] = 0ull;
  for (int i = tid; i < 2048; i += 1024) ((unsigned long long*)hf)[i] = 0ull;

  // gi prologue: this block's own 48 gate-rows (g*2000 + blk*16 + j), all (t,b)
  if (tid < 768) {
    int t = tid >> 3, b = tid & 7;
    float xr[32];
    const _Float16* xp = X + ((size_t)b * 2096 + 2000 + t) * 32;
#pragma unroll
    for (int k = 0; k < 32; k++) xr[k] = (float)xp[k];
    float* gp = gi + ((size_t)b * 96 + t) * 6000;
    for (int g = 0; g < 3; g++) {
#pragma unroll
      for (int j = 0; j < 16; j++) {
        int row = g * 2000 + blk * 16 + j;
        const float* wr = wih + (size_t)row * 32;
        float a = bih[row];
#pragma unroll 8
        for (int k = 0; k < 32; k++) a = fmaf(xr[k], wr[k], a);
        gp[row] = a;
      }
    }
  }
  __syncthreads();

  // one-time weight fill: f32 -> fp8 e4m3 fragments
  for (int i = tid; i < 3 * 64 * 64; i += 1024) {
    int g = i >> 12;
    int c = (i >> 6) & 63;
    int l2 = i & 63;
    int j = l2 & 15;
    int k0 = c * 32 + ((l2 >> 4) << 3);
    if (k0 <= 1992) {
      const float* src = whh + ((size_t)(g * 2000 + blk * 16 + j)) * 2000 + k0;
      float4 v0 = *reinterpret_cast<const float4*>(src);
      float4 v1 = *reinterpret_cast<const float4*>(src + 4);
      unsigned int lo = __builtin_amdgcn_cvt_pk_fp8_f32(v0.x, v0.y, 0, false);
      lo = __builtin_amdgcn_cvt_pk_fp8_f32(v0.z, v0.w, lo, true);
      unsigned int hi = __builtin_amdgcn_cvt_pk_fp8_f32(v1.x, v1.y, 0, false);
      hi = __builtin_amdgcn_cvt_pk_fp8_f32(v1.z, v1.w, hi, true);
      unsigned long long q = ((unsigned long long)hi << 32) | (unsigned long long)lo;
      *reinterpret_cast<unsigned long long*>(wf + (size_t)g * 32768 + c * 512 + l2 * 8) = q;
    }
  }

  int cj = tid >> 3, cb = tid & 7;
  int jg = blk * 16 + cj;
  float hold = 0.0f, bR = 0.f, bZ = 0.f, bN = 0.f;
  if (tid < 128) {
    bR = bhh[jg]; bZ = bhh[2000 + jg]; bN = bhh[4000 + jg];
  }
  int bslot = ((l >> 4) * 8 + (l & 7)) * 8;
  __syncthreads();

  for (int t = 0; t < 96; t++) {
    const unsigned char* hc = (t & 1) ? hB : hA;
    unsigned char* hn = (t & 1) ? hA : hB;
    float gir = 0.f, giz = 0.f, gin = 0.f;
    if (tid < 128) {
      const float* gp = gi + ((size_t)cb * 96 + t) * 6000;
      gir = gp[jg]; giz = gp[2000 + jg]; gin = gp[4000 + jg];
    }
    for (int i = tid; i < 2048; i += 1024) {
      int c = i >> 5, s = i & 31;
      int b = s & 7;
      int k0 = c * 32 + ((s >> 3) << 3);
      if (k0 < 2000) {
        unsigned long long v =
            *reinterpret_cast<const unsigned long long*>(hc + b * 2000 + k0);
        *reinterpret_cast<unsigned long long*>(hf + c * 256 + s * 8) = v;
      }
    }
    __syncthreads();
    f32x4 a0 = {0.f, 0.f, 0.f, 0.f}, a1 = {0.f, 0.f, 0.f, 0.f}, a2 = {0.f, 0.f, 0.f, 0.f};
#pragma unroll
    for (int i = 0; i < 4; i++) {
      int c = w * 4 + i;
      long long bv = *reinterpret_cast<const long long*>(hf + c * 256 + bslot);
      long long w0 = *reinterpret_cast<const long long*>(wf + 0 * 32768 + c * 512 + l * 8);
      long long w1 = *reinterpret_cast<const long long*>(wf + 1 * 32768 + c * 512 + l * 8);
      long long w2 = *reinterpret_cast<const long long*>(wf + 2 * 32768 + c * 512 + l * 8);
      a0 = __builtin_amdgcn_mfma_f32_16x16x32_fp8_fp8(w0, bv, a0, 0, 0, 0);
      a1 = __builtin_amdgcn_mfma_f32_16x16x32_fp8_fp8(w1, bv, a1, 0, 0, 0);
      a2 = __builtin_amdgcn_mfma_f32_16x16x32_fp8_fp8(w2, bv, a2, 0, 0, 0);
    }
    {
      int bcol = l & 15;
      if (bcol < 8) {
        int lb = l >> 4;
        *reinterpret_cast<f32x4*>(pt + w * 384 + 0 * 128 + lb * 32 + bcol * 4) = a0;
        *reinterpret_cast<f32x4*>(pt + w * 384 + 1 * 128 + lb * 32 + bcol * 4) = a1;
        *reinterpret_cast<f32x4*>(pt + w * 384 + 2 * 128 + lb * 32 + bcol * 4) = a2;
      }
    }
    __syncthreads();
    if (tid < 128) {
      float s[3];
#pragma unroll
      for (int g = 0; g < 3; g++) {
        int base = g * 128 + (cj >> 2) * 32 + cb * 4 + (cj & 3);
        float acc = 0.f;
#pragma unroll
        for (int w2 = 0; w2 < 16; w2++) acc += pt[w2 * 384 + base];
        s[g] = acc;
      }
      float r_ = 1.0f / (1.0f + __expf(-(gir + s[0] + bR)));
      float z_ = 1.0f / (1.0f + __expf(-(giz + s[1] + bZ)));
      float n_ = tanhf(gin + r_ * (s[2] + bN));
      hold = (1.0f - z_) * n_ + z_ * hold;
      {
        unsigned int p = __builtin_amdgcn_cvt_pk_fp8_f32(hold, 0.0f, 0, false);
        __hip_atomic_store(hn + cb * 2000 + jg, (unsigned char)(p & 0xFF),
                           __ATOMIC_RELAXED, __HIP_MEMORY_SCOPE_AGENT);
      }
      rt[((size_t)cb * 96 + t) * 2000 + jg] = hold;
    }
    // barrier drain: all waves' h stores reach the coherence point
    __syncthreads();
    // flat seq barrier: one fire-and-forget store; wave 2 polls all 125 directly
    if (tid == 0) {
      __hip_atomic_store(&seq[blk * 32], t + 1, __ATOMIC_RELAXED,
                         __HIP_MEMORY_SCOPE_AGENT);
    }
    if ((tid >> 6) == 2) {
      int lane = tid & 63;
      const int* s1 = &seq[lane * 32];
      const int* s2 = &seq[((lane + 64) < NBLK ? (lane + 64) : lane) * 32];
      while (true) {
        int v1 = __hip_atomic_load(s1, __ATOMIC_RELAXED, __HIP_MEMORY_SCOPE_AGENT);
        int v2 = __hip_atomic_load(s2, __ATOMIC_RELAXED, __HIP_MEMORY_SCOPE_AGENT);
        if (__all(v1 > t && v2 > t)) break;
        __builtin_amdgcn_s_sleep(1);
      }
      if (lane == 0) {
        (void)__hip_atomic_load(s1, __ATOMIC_ACQUIRE, __HIP_MEMORY_SCOPE_AGENT);
      }
    }
    __syncthreads();
  }
}

// ---------------- Kernel 8: final combine + out matmul ----------------
__global__ __launch_bounds__(256) void k_final(
    const float* __restrict__ rs, const float* __restrict__ rt,
    const float* __restrict__ outW, const float* __restrict__ outb,
    float* __restrict__ out) {
  __shared__ float w[96];
  __shared__ float ob;
  int tid = threadIdx.x;
  if (tid < 96) w[tid] = outW[tid];
  if (tid == 0) ob = outb[0];
  __syncthreads();
  int gidx = blockIdx.x * 256 + tid;
  if (gidx >= 16000) return;
  int b = gidx / 2000, n = gidx % 2000;
  const float* rsp = rs + (size_t)gidx * 96;
  float acc = ob;
  for (int t4 = 0; t4 < 24; t4++) {
    float4 rv = *reinterpret_cast<const float4*>(rsp + t4 * 4);
    int t = t4 * 4;
    acc = fmaf(rv.x + rt[((size_t)b * 96 + t + 0) * 2000 + n], w[t + 0], acc);
    acc = fmaf(rv.y + rt[((size_t)b * 96 + t + 1) * 2000 + n], w[t + 1], acc);
    acc = fmaf(rv.z + rt[((size_t)b * 96 + t + 2) * 2000 + n], w[t + 2], acc);
    acc = fmaf(rv.w + rt[((size_t)b * 96 + t + 3) * 2000 + n], w[t + 3], acc);
  }
  out[gidx] = acc;
}

extern "C" void kernel_launch(void* const* d_in, const int* in_sizes, int n_in,
                              void* d_out, int out_size, void* d_ws, size_t ws_size,
                              hipStream_t stream) {
  const float* x      = (const float*)d_in[0];
  const float* x_mark = (const float*)d_in[1];
  const float* sp_emb = (const float*)d_in[2];
  const float* sp_W1  = (const float*)d_in[3];
  const float* sp_b1  = (const float*)d_in[4];
  const float* sp_W2  = (const float*)d_in[5];
  const float* sp_b2  = (const float*)d_in[6];
  const float* t_emb  = (const float*)d_in[7];
  const float* t_Wih  = (const float*)d_in[8];
  const float* t_Whh  = (const float*)d_in[9];
  const float* t_bih  = (const float*)d_in[10];
  const float* t_bhh  = (const float*)d_in[11];
  const float* gcn_W  = (const float*)d_in[12];
  const float* gcn_b  = (const float*)d_in[13];
  const float* fr_W1  = (const float*)d_in[14];
  const float* fr_b1  = (const float*)d_in[15];
  const float* fr_W2  = (const float*)d_in[16];
  const float* fr_b2  = (const float*)d_in[17];
  const float* tr_Wih = (const float*)d_in[18];
  const float* tr_Whh = (const float*)d_in[19];
  const float* tr_bih = (const float*)d_in[20];
  const float* tr_bhh = (const float*)d_in[21];
  const float* out_W  = (const float*)d_in[22];
  const float* out_b  = (const float*)d_in[23];
  (void)in_sizes; (void)n_in; (void)out_size; (void)ws_size;

  float* ws = (float*)d_ws;
  float* X0   = ws;                    // slots sized for f32; f16 uses half
  float* X1   = X0 + 536576;
  float* X2   = X1 + 536576;
  float* tgi  = X2 + 536576;           // 768*96
  float* trgi = tgi + 73728;           // 8*96*6000
  float* hsl  = trgi + 4608000;        // hA/hB (fp8, 16000 B each)
  float* rt   = hsl + 16000;           // 8*96*2000
  float* rs   = rt + 1536000;          // 8*2000*96
  float* barf = rs + 1536000;          // BAR_INTS ints (seq)

  _Float16* X0h = (_Float16*)X0;
  _Float16* X1h = (_Float16*)X1;
  _Float16* X2h = (_Float16*)X2;
  unsigned char* hA = (unsigned char*)hsl;
  unsigned char* hB = hA + 16000;
  int* seq = (int*)barf;

  k_spatial<<<63, 256, 0, stream>>>(x, sp_emb, sp_W1, sp_b1, sp_W2, sp_b2, X0h, seq, hA);
  k_tgi<<<96, 256, 0, stream>>>(x, x_mark, t_emb, t_Wih, t_bih, tgi);
  k_tgru<<<1, 768, 0, stream>>>(tgi, t_Whh, t_bhh, X0h);

  dim3 gg(66, 8);
  k_gnn<<<gg, 256, 0, stream>>>(X0h, X0h, X1h, gcn_W + 0 * 1024, gcn_b + 0 * 32);
  k_gnn<<<gg, 256, 0, stream>>>(X0h, X1h, X2h, gcn_W + 1 * 1024, gcn_b + 1 * 32);
  k_gnn<<<gg, 256, 0, stream>>>(X2h, X2h, X0h, gcn_W + 2 * 1024, gcn_b + 2 * 32);
  k_gnn<<<gg, 256, 0, stream>>>(X2h, X0h, X1h, gcn_W + 3 * 1024, gcn_b + 3 * 32);

  {
    const _Float16* a0 = X1h;
    const float* a1 = tr_Wih;
    const float* a2 = tr_bih;
    float* a3 = trgi;
    const float* a4 = tr_Whh;
    const float* a5 = tr_bhh;
    unsigned char* a6 = hA;
    unsigned char* a7 = hB;
    float* a8 = rt;
    int* a9 = seq;
    const float* a10 = fr_W1;
    const float* a11 = fr_b1;
    const float* a12 = fr_W2;
    const float* a13 = fr_b2;
    float* a14 = rs;
    void* cargs[] = {&a0, &a1, &a2, &a3, &a4, &a5, &a6, &a7,
                     &a8, &a9, &a10, &a11, &a12, &a13, &a14};
    hipLaunchCooperativeKernel((const void*)k_trgru, dim3(250), dim3(1024), cargs, 0, stream);
  }

  k_final<<<63, 256, 0, stream>>>(rs, rt, out_W, out_b, (float*)d_out);
}

// Round 10
// 932.104 us; speedup vs baseline: 3.7580x; 1.0744x over previous
//
#include <hip/hip_runtime.h>

typedef _Float16 half8 __attribute__((ext_vector_type(8)));
typedef float f32x4 __attribute__((ext_vector_type(4)));

#define NBLK 125
#define TOTBLK 250
#define BAR_INTS (TOTBLK * 32)

// ---------------- Kernel 1: fused spatial MLP (blocks 0-62) + tgi (blocks 63-158) ----------------
__global__ __launch_bounds__(256) void k_pre(
    const float* __restrict__ x, const float* __restrict__ x_mark,
    const float* __restrict__ sp_emb,
    const float* __restrict__ spW1, const float* __restrict__ spb1,
    const float* __restrict__ spW2, const float* __restrict__ spb2,
    const float* __restrict__ t_emb, const float* __restrict__ tWih,
    const float* __restrict__ tbih,
    _Float16* __restrict__ X, float* __restrict__ gi,
    int* __restrict__ seq, unsigned char* __restrict__ hA) {
  __shared__ __align__(16) unsigned char PSM[65152];
  int tid = threadIdx.x;
  if (blockIdx.x < 63) {
    // ===== spatial path =====
    float* W1s = (float*)PSM;              // 128*32
    float* W2s = (float*)(PSM + 16384);    // 32*32
    float* b1s = (float*)(PSM + 20480);    // 32
    float* b2s = (float*)(PSM + 20608);    // 32
    int gidx = blockIdx.x * 256 + tid;
    for (int i = gidx; i < BAR_INTS; i += 63 * 256) seq[i] = 0;
    for (int i = gidx; i < 4000; i += 63 * 256) ((unsigned int*)hA)[i] = 0u;
    for (int i = tid; i < 128 * 32; i += 256) W1s[i] = spW1[i];
    for (int i = tid; i < 32 * 32; i += 256) W2s[i] = spW2[i];
    if (tid < 32) { b1s[tid] = spb1[tid]; b2s[tid] = spb2[tid]; }
    __syncthreads();
    if (gidx >= 8 * 2000) return;
    int b = gidx / 2000, n = gidx % 2000;
    float h1[32];
#pragma unroll
    for (int l = 0; l < 32; l++) h1[l] = b1s[l];
    for (int k = 0; k < 96; k++) {
      float xv = x[((size_t)b * 96 + k) * 2000 + n];
#pragma unroll
      for (int l = 0; l < 32; l++) h1[l] = fmaf(xv, W1s[k * 32 + l], h1[l]);
    }
    for (int e4 = 0; e4 < 8; e4++) {
      float4 ev = *reinterpret_cast<const float4*>(&sp_emb[(size_t)n * 32 + e4 * 4]);
      float evs[4] = {ev.x, ev.y, ev.z, ev.w};
#pragma unroll
      for (int q = 0; q < 4; q++) {
        int e = e4 * 4 + q;
#pragma unroll
        for (int l = 0; l < 32; l++) h1[l] = fmaf(evs[q], W1s[(96 + e) * 32 + l], h1[l]);
      }
    }
    float out[32];
#pragma unroll
    for (int j = 0; j < 32; j++) out[j] = b2s[j];
    for (int l = 0; l < 32; l++) {
      float a = h1[l] > 0.0f ? h1[l] : (__expf(h1[l]) - 1.0f);
#pragma unroll
      for (int j = 0; j < 32; j++) out[j] = fmaf(a, W2s[l * 32 + j], out[j]);
    }
    _Float16* dst = X + ((size_t)b * 2096 + n) * 32;
#pragma unroll
    for (int j8 = 0; j8 < 4; j8++) {
      half8 v;
#pragma unroll
      for (int q = 0; q < 8; q++) v[q] = (_Float16)out[j8 * 8 + q];
      *reinterpret_cast<half8*>(dst + j8 * 8) = v;
    }
  } else {
    // ===== tgi path =====
    float (*xs)[2036] = (float(*)[2036])PSM;
    int row0 = (blockIdx.x - 63) * 8;
    for (int rr = 0; rr < 8; rr++) {
      int row = row0 + rr;
      int b = row / 96, t = row % 96;
      for (int k = tid; k < 2036; k += 256) {
        float v;
        if (k < 2000) v = x[((size_t)b * 96 + t) * 2000 + k];
        else if (k < 2004) v = x_mark[((size_t)b * 96 + t) * 4 + (k - 2000)];
        else v = t_emb[(size_t)t * 32 + (k - 2004)];
        xs[rr][k] = v;
      }
    }
    __syncthreads();
    for (int oi = tid; oi < 8 * 96; oi += 256) {
      int rr = oi & 7, g = oi >> 3;
      const float* w = tWih + (size_t)g * 2036;
      float acc = tbih[g];
      for (int k = 0; k < 2036; k += 4) {
        float4 wv = *reinterpret_cast<const float4*>(w + k);
        acc = fmaf(xs[rr][k + 0], wv.x, acc);
        acc = fmaf(xs[rr][k + 1], wv.y, acc);
        acc = fmaf(xs[rr][k + 2], wv.z, acc);
        acc = fmaf(xs[rr][k + 3], wv.w, acc);
      }
      gi[(size_t)(row0 + rr) * 96 + g] = acc;
    }
  }
}

// ---------------- Kernel 3: temporal GRU scan (hidden=32), f16 X out ----------------
__global__ __launch_bounds__(768) void k_tgru(
    const float* __restrict__ gi, const float* __restrict__ Whh,
    const float* __restrict__ bhh, _Float16* __restrict__ X) {
  __shared__ float Whs[96][33];
  __shared__ float hs[8][33];
  __shared__ float ga[3][8][33];
  int tid = threadIdx.x;
  for (int i = tid; i < 96 * 32; i += 768) Whs[i >> 5][i & 31] = Whh[i];
  if (tid < 256) hs[tid >> 5][tid & 31] = 0.0f;
  int g = tid >> 8, j = (tid >> 3) & 31, b = tid & 7;
  int row = g * 32 + j;
  float bb0 = 0.f, bb1 = 0.f, bb2 = 0.f;
  if (tid < 256) {
    int jj = tid & 31;
    bb0 = bhh[jj]; bb1 = bhh[32 + jj]; bb2 = bhh[64 + jj];
  }
  __syncthreads();
  for (int t = 0; t < 96; t++) {
    float acc = 0.0f;
#pragma unroll
    for (int k = 0; k < 32; k++) acc = fmaf(hs[b][k], Whs[row][k], acc);
    ga[g][b][j] = acc;
    __syncthreads();
    if (tid < 256) {
      int bb = tid >> 5, jj = tid & 31;
      const float* gp = gi + ((size_t)bb * 96 + t) * 96;
      float gr = ga[0][bb][jj] + bb0;
      float gz = ga[1][bb][jj] + bb1;
      float gn = ga[2][bb][jj] + bb2;
      float r = 1.0f / (1.0f + __expf(-(gp[jj] + gr)));
      float z = 1.0f / (1.0f + __expf(-(gp[32 + jj] + gz)));
      float n = tanhf(gp[64 + jj] + r * gn);
      float hn = (1.0f - z) * n + z * hs[bb][jj];
      hs[bb][jj] = hn;
      X[((size_t)bb * 2096 + 2000 + t) * 32 + jj] = (_Float16)hn;
    }
    __syncthreads();
  }
}

// ---------------- Kernel 4: fused GNN pass (MFMA, f16 X, transposed Xq) ----------------
__global__ __launch_bounds__(256) void k_gnn(
    const _Float16* __restrict__ Xa, const _Float16* __restrict__ Xin,
    _Float16* __restrict__ Xout, const float* __restrict__ W,
    const float* __restrict__ bias) {
  __shared__ _Float16 XaR[32][40];
  __shared__ _Float16 Xm[2][64][40];
  __shared__ _Float16 XqT[2][32][72];   // transposed: [feat][node], stride 72 (16B-aligned rows)
  __shared__ _Float16 At[32][72];
  __shared__ float Pm[32][36];
  __shared__ float Ws[32][36];
  __shared__ float bs[32];
  int tid = threadIdx.x;
  int l = tid & 63, w = tid >> 6;
  int b = blockIdx.y;
  int r0 = blockIdx.x * 32;
  const _Float16* Xab = Xa + (size_t)b * 2096 * 32;
  const _Float16* Xib = Xin + (size_t)b * 2096 * 32;
  half8 hz = {(_Float16)0, (_Float16)0, (_Float16)0, (_Float16)0,
              (_Float16)0, (_Float16)0, (_Float16)0, (_Float16)0};

  for (int i = tid; i < 1024; i += 256) Ws[i >> 5][i & 31] = W[i];
  if (tid < 32) bs[tid] = bias[tid];
  if (tid < 128) {
    int r = tid >> 2, k = (tid & 3) * 8;
    half8 v = (r0 + r < 2096)
                  ? *reinterpret_cast<const half8*>(Xab + (size_t)(r0 + r) * 32 + k)
                  : hz;
    *reinterpret_cast<half8*>(&XaR[r][k]) = v;
  }
  int sr = tid >> 2, sk = (tid & 3) * 8;
  {
    *reinterpret_cast<half8*>(&Xm[0][sr][sk]) =
        *reinterpret_cast<const half8*>(Xab + (size_t)sr * 32 + sk);
    half8 vq = *reinterpret_cast<const half8*>(Xib + (size_t)sr * 32 + sk);
#pragma unroll
    for (int e = 0; e < 8; e++) XqT[0][sk + e][sr] = vq[e];
  }
  __syncthreads();

  int lr = l & 15, lk = (l >> 4) * 8, lq = (l >> 4) * 4;
  int smt = w >> 1, snt2 = w & 1;
  int pmt = w >> 1, pnt = w & 1;
  half8 afrag = *reinterpret_cast<const half8*>(&XaR[smt * 16 + lr][lk]);
  f32x4 pacc = {0.f, 0.f, 0.f, 0.f};

  for (int tt = 0; tt < 33; tt++) {
    int cur = tt & 1, nb = cur ^ 1;
    half8 vm = hz, vq = hz;
    bool hv = (tt + 1 < 33);
    if (hv) {
      int gm = (tt + 1) * 64 + sr;
      if (gm < 2096) {
        vm = *reinterpret_cast<const half8*>(Xab + (size_t)gm * 32 + sk);
        vq = *reinterpret_cast<const half8*>(Xib + (size_t)gm * 32 + sk);
      }
    }
#pragma unroll
    for (int n16 = 0; n16 < 2; n16++) {
      int c0 = snt2 * 32 + n16 * 16;
      half8 bfrag = *reinterpret_cast<const half8*>(&Xm[cur][c0 + lr][lk]);
      f32x4 s4 = __builtin_amdgcn_mfma_f32_16x16x32_f16(
          afrag, bfrag, (f32x4){0.f, 0.f, 0.f, 0.f}, 0, 0, 0);
#pragma unroll
      for (int j = 0; j < 4; j++) {
        float e = __expf(-2.0f * fmaxf(s4[j], 0.0f));
        At[smt * 16 + lq + j][c0 + lr] = (_Float16)((1.0f - e) / (1.0f + e));
      }
    }
    __syncthreads();
    // P-phase: B-frag = contiguous b128 from transposed Xq
    {
      int nn = pnt * 16 + lr;
#pragma unroll
      for (int kc = 0; kc < 2; kc++) {
        half8 af = *reinterpret_cast<const half8*>(&At[pmt * 16 + lr][kc * 32 + lk]);
        half8 bf = *reinterpret_cast<const half8*>(&XqT[cur][nn][kc * 32 + lk]);
        pacc = __builtin_amdgcn_mfma_f32_16x16x32_f16(af, bf, pacc, 0, 0, 0);
      }
    }
    if (hv) {
      *reinterpret_cast<half8*>(&Xm[nb][sr][sk]) = vm;
#pragma unroll
      for (int e = 0; e < 8; e++) XqT[nb][sk + e][sr] = vq[e];
    }
    __syncthreads();
  }

#pragma unroll
  for (int j = 0; j < 4; j++) Pm[pmt * 16 + lq + j][pnt * 16 + lr] = pacc[j];
  __syncthreads();
  int r = tid & 31, fgr = tid >> 5;
  int f0 = fgr * 4;
  float o[4];
#pragma unroll
  for (int j = 0; j < 4; j++) o[j] = bs[f0 + j];
#pragma unroll
  for (int k = 0; k < 32; k++) {
    float mv = Pm[r][k];
    float4 wv = *reinterpret_cast<const float4*>(&Ws[k][f0]);
    o[0] = fmaf(mv, wv.x, o[0]);
    o[1] = fmaf(mv, wv.y, o[1]);
    o[2] = fmaf(mv, wv.z, o[2]);
    o[3] = fmaf(mv, wv.w, o[3]);
  }
  int grr = r0 + r;
  if (grr < 2096) {
    _Float16* dst = Xout + ((size_t)b * 2096 + grr) * 32 + f0;
#pragma unroll
    for (int j = 0; j < 4; j++) {
      float v = o[j];
      dst[j] = (_Float16)(v > 0.0f ? v : (__expf(v) - 1.0f));
    }
  }
}

// ---------------- Kernel 7: fused persistent kernel (GRU + rs + final combine) ----------------
__global__ __launch_bounds__(1024) void k_trgru(
    const _Float16* __restrict__ X, const float* __restrict__ wih,
    const float* __restrict__ bih, float* __restrict__ gi,
    const float* __restrict__ whh, const float* __restrict__ bhh,
    unsigned char* __restrict__ hA, unsigned char* __restrict__ hB,
    float* __restrict__ rt, int* __restrict__ seq,
    const float* __restrict__ frW1, const float* __restrict__ frb1,
    const float* __restrict__ frW2, const float* __restrict__ frb2,
    float* __restrict__ rs, const float* __restrict__ outW,
    const float* __restrict__ outb, float* __restrict__ out) {
  __shared__ __align__(16) unsigned char SM[122880];
  int tid = threadIdx.x;
  int blk = blockIdx.x;

  if (blk >= NBLK) {
    // ================= rs path (spare blocks) =================
    float* W1s = (float*)(SM);            // 32*96
    float* W2s = (float*)(SM + 12288);    // 96*100
    float* b1s = (float*)(SM + 50688);
    float* b2s = (float*)(SM + 51072);
    float* Xt  = (float*)(SM + 51456);    // 32*33
    float* Hl  = (float*)(SM + 55680);    // 32*100
    for (int i = tid; i < 32 * 96; i += 1024) W1s[i] = frW1[i];
    for (int i = tid; i < 96 * 96; i += 1024) W2s[(i / 96) * 100 + (i % 96)] = frW2[i];
    if (tid < 96) { b1s[tid] = frb1[tid]; b2s[tid] = frb2[tid]; }
    __syncthreads();
    for (int ti = blk - NBLK; ti < 504; ti += NBLK) {
      int b = ti / 63, n0 = (ti % 63) * 32;
      {
        int r = tid >> 5, k = tid & 31;
        Xt[r * 33 + k] =
            (n0 + r < 2000) ? (float)X[((size_t)b * 2096 + n0 + r) * 32 + k] : 0.0f;
      }
      __syncthreads();
#pragma unroll
      for (int q = 0; q < 3; q++) {
        int idx = q * 1024 + tid;
        int r = idx / 96, c = idx % 96;
        float a = b1s[c];
#pragma unroll 8
        for (int k = 0; k < 32; k++) a = fmaf(Xt[r * 33 + k], W1s[k * 96 + c], a);
        Hl[r * 100 + c] = a > 0.0f ? a : (__expf(a) - 1.0f);
      }
      __syncthreads();
#pragma unroll
      for (int q = 0; q < 3; q++) {
        int idx = q * 1024 + tid;
        int r = idx / 96, c = idx % 96;
        float o = b2s[c];
#pragma unroll 8
        for (int k = 0; k < 96; k++) o = fmaf(Hl[r * 100 + k], W2s[k * 100 + c], o);
        if (n0 + r < 2000) {
          __hip_atomic_store(&rs[((size_t)b * 2000 + n0 + r) * 96 + c], o,
                             __ATOMIC_RELAXED, __HIP_MEMORY_SCOPE_AGENT);
        }
      }
      __syncthreads();
    }
    // flag done (rs stores drained by the syncthreads above)
    if (tid == 0) {
      __hip_atomic_store(&seq[blk * 32], 96, __ATOMIC_RELAXED,
                         __HIP_MEMORY_SCOPE_AGENT);
    }
  } else {
    // ================= GRU path =================
    unsigned char* wf = SM;               // 3*32768
    float* pt = (float*)(SM + 98304);     // 6144 f32
    int l = tid & 63, w = tid >> 6;

    for (int i = tid; i < 12288; i += 1024) ((unsigned long long*)wf)[i] = 0ull;

    // gi prologue: this block's own 48 gate-rows
    if (tid < 768) {
      int t = tid >> 3, b = tid & 7;
      float xr[32];
      const _Float16* xp = X + ((size_t)b * 2096 + 2000 + t) * 32;
#pragma unroll
      for (int k = 0; k < 32; k++) xr[k] = (float)xp[k];
      float* gp = gi + ((size_t)b * 96 + t) * 6000;
      for (int g = 0; g < 3; g++) {
#pragma unroll
        for (int j = 0; j < 16; j++) {
          int row = g * 2000 + blk * 16 + j;
          const float* wr = wih + (size_t)row * 32;
          float a = bih[row];
#pragma unroll 8
          for (int k = 0; k < 32; k++) a = fmaf(xr[k], wr[k], a);
          gp[row] = a;
        }
      }
    }

    // one-time weight fill: f32 -> fp8 e4m3 fragments
    for (int i = tid; i < 3 * 64 * 64; i += 1024) {
      int g = i >> 12;
      int c = (i >> 6) & 63;
      int l2 = i & 63;
      int j = l2 & 15;
      int k0 = c * 32 + ((l2 >> 4) << 3);
      if (k0 <= 1992) {
        const float* src = whh + ((size_t)(g * 2000 + blk * 16 + j)) * 2000 + k0;
        float4 v0 = *reinterpret_cast<const float4*>(src);
        float4 v1 = *reinterpret_cast<const float4*>(src + 4);
        unsigned int lo = __builtin_amdgcn_cvt_pk_fp8_f32(v0.x, v0.y, 0, false);
        lo = __builtin_amdgcn_cvt_pk_fp8_f32(v0.z, v0.w, lo, true);
        unsigned int hi = __builtin_amdgcn_cvt_pk_fp8_f32(v1.x, v1.y, 0, false);
        hi = __builtin_amdgcn_cvt_pk_fp8_f32(v1.z, v1.w, hi, true);
        unsigned long long q = ((unsigned long long)hi << 32) | (unsigned long long)lo;
        *reinterpret_cast<unsigned long long*>(wf + (size_t)g * 32768 + c * 512 + l2 * 8) = q;
      }
    }

    int cj = tid >> 3, cb = tid & 7;
    int jg = blk * 16 + cj;
    float hold = 0.0f, bR = 0.f, bZ = 0.f, bN = 0.f;
    if (tid < 128) {
      bR = bhh[jg]; bZ = bhh[2000 + jg]; bN = bhh[4000 + jg];
    }
    int bb = l & 7, kblk = (l >> 4) * 8;   // direct-load mapping (matches old bslot)
    __syncthreads();

    for (int t = 0; t < 96; t++) {
      const unsigned char* hc = (t & 1) ? hB : hA;
      unsigned char* hn = (t & 1) ? hA : hB;
      float gir = 0.f, giz = 0.f, gin = 0.f;
      if (tid < 128) {
        const float* gp = gi + ((size_t)cb * 96 + t) * 6000;
        gir = gp[jg]; giz = gp[2000 + jg]; gin = gp[4000 + jg];
      }
      // MFMA: direct global B-fragment loads (no LDS staging)
      f32x4 a0 = {0.f, 0.f, 0.f, 0.f}, a1 = {0.f, 0.f, 0.f, 0.f}, a2 = {0.f, 0.f, 0.f, 0.f};
#pragma unroll
      for (int i = 0; i < 4; i++) {
        int c = w * 4 + i;
        int k0 = c * 32 + kblk;
        long long bv = 0;
        if (k0 <= 1992)
          bv = *reinterpret_cast<const long long*>(hc + bb * 2000 + k0);
        long long w0 = *reinterpret_cast<const long long*>(wf + 0 * 32768 + c * 512 + l * 8);
        long long w1 = *reinterpret_cast<const long long*>(wf + 1 * 32768 + c * 512 + l * 8);
        long long w2 = *reinterpret_cast<const long long*>(wf + 2 * 32768 + c * 512 + l * 8);
        a0 = __builtin_amdgcn_mfma_f32_16x16x32_fp8_fp8(w0, bv, a0, 0, 0, 0);
        a1 = __builtin_amdgcn_mfma_f32_16x16x32_fp8_fp8(w1, bv, a1, 0, 0, 0);
        a2 = __builtin_amdgcn_mfma_f32_16x16x32_fp8_fp8(w2, bv, a2, 0, 0, 0);
      }
      {
        int bcol = l & 15;
        if (bcol < 8) {
          int lb = l >> 4;
          *reinterpret_cast<f32x4*>(pt + w * 384 + 0 * 128 + lb * 32 + bcol * 4) = a0;
          *reinterpret_cast<f32x4*>(pt + w * 384 + 1 * 128 + lb * 32 + bcol * 4) = a1;
          *reinterpret_cast<f32x4*>(pt + w * 384 + 2 * 128 + lb * 32 + bcol * 4) = a2;
        }
      }
      __syncthreads();
      if (tid < 128) {
        float s[3];
#pragma unroll
        for (int g = 0; g < 3; g++) {
          int base = g * 128 + (cj >> 2) * 32 + cb * 4 + (cj & 3);
          float acc = 0.f;
#pragma unroll
          for (int w2 = 0; w2 < 16; w2++) acc += pt[w2 * 384 + base];
          s[g] = acc;
        }
        float r_ = 1.0f / (1.0f + __expf(-(gir + s[0] + bR)));
        float z_ = 1.0f / (1.0f + __expf(-(giz + s[1] + bZ)));
        float n_ = tanhf(gin + r_ * (s[2] + bN));
        hold = (1.0f - z_) * n_ + z_ * hold;
        {
          unsigned int p = __builtin_amdgcn_cvt_pk_fp8_f32(hold, 0.0f, 0, false);
          __hip_atomic_store(hn + cb * 2000 + jg, (unsigned char)(p & 0xFF),
                             __ATOMIC_RELAXED, __HIP_MEMORY_SCOPE_AGENT);
        }
        __hip_atomic_store(&rt[((size_t)cb * 96 + t) * 2000 + jg], hold,
                           __ATOMIC_RELAXED, __HIP_MEMORY_SCOPE_AGENT);
      }
      __syncthreads();  // drains h/rt stores before flag
      if (tid == 0) {
        __hip_atomic_store(&seq[blk * 32], t + 1, __ATOMIC_RELAXED,
                           __HIP_MEMORY_SCOPE_AGENT);
      }
      if ((tid >> 6) == 2) {
        int lane = tid & 63;
        const int* s1 = &seq[lane * 32];
        const int* s2 = &seq[((lane + 64) < NBLK ? (lane + 64) : lane) * 32];
        while (true) {
          int v1 = __hip_atomic_load(s1, __ATOMIC_RELAXED, __HIP_MEMORY_SCOPE_AGENT);
          int v2 = __hip_atomic_load(s2, __ATOMIC_RELAXED, __HIP_MEMORY_SCOPE_AGENT);
          if (__all(v1 > t && v2 > t)) break;
          __builtin_amdgcn_s_sleep(1);
        }
        if (lane == 0) {
          (void)__hip_atomic_load(s1, __ATOMIC_ACQUIRE, __HIP_MEMORY_SCOPE_AGENT);
        }
      }
      __syncthreads();
    }
  }

  // ================= shared epilogue: final barrier + out matmul =================
  {
    float* wsm = (float*)SM;  // 97 floats (safe: wf/pt dead, spare LDS dead)
    __syncthreads();
    if (tid >= 128 && tid < 224) wsm[tid - 128] = outW[tid - 128];
    if (tid == 224) wsm[96] = outb[0];
    if (tid < 64) {
      const int* p0 = &seq[tid * 32];
      const int* p1 = &seq[(tid + 64) * 32];
      const int* p2 = &seq[(tid + 128) * 32];
      int i3 = tid + 192; if (i3 >= TOTBLK) i3 = tid;
      const int* p3 = &seq[i3 * 32];
      while (true) {
        int v0 = __hip_atomic_load(p0, __ATOMIC_RELAXED, __HIP_MEMORY_SCOPE_AGENT);
        int v1 = __hip_atomic_load(p1, __ATOMIC_RELAXED, __HIP_MEMORY_SCOPE_AGENT);
        int v2 = __hip_atomic_load(p2, __ATOMIC_RELAXED, __HIP_MEMORY_SCOPE_AGENT);
        int v3 = __hip_atomic_load(p3, __ATOMIC_RELAXED, __HIP_MEMORY_SCOPE_AGENT);
        if (__all(v0 >= 96 && v1 >= 96 && v2 >= 96 && v3 >= 96)) break;
        __builtin_amdgcn_s_sleep(2);
      }
      if (tid == 0) {
        (void)__hip_atomic_load(p0, __ATOMIC_ACQUIRE, __HIP_MEMORY_SCOPE_AGENT);
      }
    }
    __syncthreads();
    if (tid < 64) {
      int idx = blk * 64 + tid;
      int b = idx / 2000, n = idx % 2000;
      const float* rsp = rs + (size_t)idx * 96;
      float acc = wsm[96];
      for (int t4 = 0; t4 < 24; t4++) {
        float4 rv = *reinterpret_cast<const float4*>(rsp + t4 * 4);
        int t = t4 * 4;
        acc = fmaf(rv.x + rt[((size_t)b * 96 + t + 0) * 2000 + n], wsm[t + 0], acc);
        acc = fmaf(rv.y + rt[((size_t)b * 96 + t + 1) * 2000 + n], wsm[t + 1], acc);
        acc = fmaf(rv.z + rt[((size_t)b * 96 + t + 2) * 2000 + n], wsm[t + 2], acc);
        acc = fmaf(rv.w + rt[((size_t)b * 96 + t + 3) * 2000 + n], wsm[t + 3], acc);
      }
      out[idx] = acc;
    }
  }
}

extern "C" void kernel_launch(void* const* d_in, const int* in_sizes, int n_in,
                              void* d_out, int out_size, void* d_ws, size_t ws_size,
                              hipStream_t stream) {
  const float* x      = (const float*)d_in[0];
  const float* x_mark = (const float*)d_in[1];
  const float* sp_emb = (const float*)d_in[2];
  const float* sp_W1  = (const float*)d_in[3];
  const float* sp_b1  = (const float*)d_in[4];
  const float* sp_W2  = (const float*)d_in[5];
  const float* sp_b2  = (const float*)d_in[6];
  const float* t_emb  = (const float*)d_in[7];
  const float* t_Wih  = (const float*)d_in[8];
  const float* t_Whh  = (const float*)d_in[9];
  const float* t_bih  = (const float*)d_in[10];
  const float* t_bhh  = (const float*)d_in[11];
  const float* gcn_W  = (const float*)d_in[12];
  const float* gcn_b  = (const float*)d_in[13];
  const float* fr_W1  = (const float*)d_in[14];
  const float* fr_b1  = (const float*)d_in[15];
  const float* fr_W2  = (const float*)d_in[16];
  const float* fr_b2  = (const float*)d_in[17];
  const float* tr_Wih = (const float*)d_in[18];
  const float* tr_Whh = (const float*)d_in[19];
  const float* tr_bih = (const float*)d_in[20];
  const float* tr_bhh = (const float*)d_in[21];
  const float* out_W  = (const float*)d_in[22];
  const float* out_b  = (const float*)d_in[23];
  (void)in_sizes; (void)n_in; (void)out_size; (void)ws_size;

  float* ws = (float*)d_ws;
  float* X0   = ws;                    // slots sized for f32; f16 uses half
  float* X1   = X0 + 536576;
  float* X2   = X1 + 536576;
  float* tgi  = X2 + 536576;           // 768*96
  float* trgi = tgi + 73728;           // 8*96*6000
  float* hsl  = trgi + 4608000;        // hA/hB (fp8, 16000 B each)
  float* rt   = hsl + 16000;           // 8*96*2000
  float* rs   = rt + 1536000;          // 8*2000*96
  float* barf = rs + 1536000;          // BAR_INTS ints (seq)

  _Float16* X0h = (_Float16*)X0;
  _Float16* X1h = (_Float16*)X1;
  _Float16* X2h = (_Float16*)X2;
  unsigned char* hA = (unsigned char*)hsl;
  unsigned char* hB = hA + 16000;
  int* seq = (int*)barf;

  k_pre<<<159, 256, 0, stream>>>(x, x_mark, sp_emb, sp_W1, sp_b1, sp_W2, sp_b2,
                                 t_emb, t_Wih, t_bih, X0h, tgi, seq, hA);
  k_tgru<<<1, 768, 0, stream>>>(tgi, t_Whh, t_bhh, X0h);

  dim3 gg(66, 8);
  k_gnn<<<gg, 256, 0, stream>>>(X0h, X0h, X1h, gcn_W + 0 * 1024, gcn_b + 0 * 32);
  k_gnn<<<gg, 256, 0, stream>>>(X0h, X1h, X2h, gcn_W + 1 * 1024, gcn_b + 1 * 32);
  k_gnn<<<gg, 256, 0, stream>>>(X2h, X2h, X0h, gcn_W + 2 * 1024, gcn_b + 2 * 32);
  k_gnn<<<gg, 256, 0, stream>>>(X2h, X0h, X1h, gcn_W + 3 * 1024, gcn_b + 3 * 32);

  {
    const _Float16* a0 = X1h;
    const float* a1 = tr_Wih;
    const float* a2 = tr_bih;
    float* a3 = trgi;
    const float* a4 = tr_Whh;
    const float* a5 = tr_bhh;
    unsigned char* a6 = hA;
    unsigned char* a7 = hB;
    float* a8 = rt;
    int* a9 = seq;
    const float* a10 = fr_W1;
    const float* a11 = fr_b1;
    const float* a12 = fr_W2;
    const float* a13 = fr_b2;
    float* a14 = rs;
    const float* a15 = out_W;
    const float* a16 = out_b;
    float* a17 = (float*)d_out;
    void* cargs[] = {&a0, &a1, &a2, &a3, &a4, &a5, &a6, &a7, &a8, &a9,
                     &a10, &a11, &a12, &a13, &a14, &a15, &a16, &a17};
    hipLaunchCooperativeKernel((const void*)k_trgru, dim3(TOTBLK), dim3(1024), cargs, 0, stream);
  }
}